// Round 3
// baseline (963.031 us; speedup 1.0000x reference)
//
#include <hip/hip_runtime.h>
#include <hip/hip_bf16.h>
#include <math.h>

#define N_NODES 50000
#define N_EDGES 800000
#define HID 128
#define LAT 64
#define IN_NODE 11
#define K_EDGE 261    // 2*HID + 1 + 4
#define KP1 288       // K_EDGE padded to multiple of 32
#define KN 256        // node MLP folded K (h + agg)
#define AST 296       // edge feature LDS row stride (bf16 elems), 288+8 pad
#define NST 264       // node feature LDS row stride, 256+8 pad
#define TST 136       // t1 LDS row stride, 128+8 pad
#define MST 132       // msg LDS row stride (floats), 128+4 pad
#define NTPB 20       // edge tiles per block (grid 1250, ~5 launched/CU, 4 resident)
#define NTN 2         // node tiles per block (grid 782 ~ 3/CU)
#define NSCAN 196     // scan blocks: 196*256 = 50176 >= N_NODES
// prep_all block partition
#define EB 3125       // edge count+tail blocks
#define EMB_B 25000   // embedding blocks (2 nodes each)
#define WPB 32        // weight prep blocks
#define ZB 100        // agg zero blocks

typedef __attribute__((ext_vector_type(8))) short short8;
typedef __attribute__((ext_vector_type(4))) short short4v;
typedef __attribute__((ext_vector_type(4))) float floatx4;

__device__ __forceinline__ float elu_f(float v) { return v > 0.0f ? v : __expf(v) - 1.0f; }

__device__ __forceinline__ short f2bf(float f) {
    unsigned int u = __builtin_bit_cast(unsigned int, f);
    u += 0x7fffu + ((u >> 16) & 1u);   // round-to-nearest-even
    return (short)(u >> 16);
}

__device__ __forceinline__ short2 f2bf2(float a, float b) {
    float2 p; p.x = a; p.y = b;
    __hip_bfloat162 h = __float22bfloat162_rn(p);   // v_cvt_pk_bf16_f32
    short2 r;
    __builtin_memcpy(&r, &h, sizeof(r));
    return r;
}

__device__ __forceinline__ float bf2f(short s) {
    unsigned int u = ((unsigned int)(unsigned short)s) << 16;
    return __builtin_bit_cast(float, u);
}

// ---------------- fused prep: edge count+tail | emb | weight prep | agg zero ----------------
__global__ void prep_all(const int* __restrict__ edges, const float* __restrict__ x,
                         const float* __restrict__ edge_attr, const float* __restrict__ h0,
                         const float* __restrict__ emb_w, const float* __restrict__ emb_b,
                         const float* __restrict__ ew1, const float* __restrict__ ew2,
                         const float* __restrict__ nw1, const float* __restrict__ nw2,
                         int* __restrict__ cnt, short* __restrict__ tail_u,
                         short* __restrict__ h_bf,
                         short* __restrict__ ew1T, short* __restrict__ ew2T,
                         short* __restrict__ nw1T, short* __restrict__ nw2T,
                         float* __restrict__ agg) {
    int b = blockIdx.x, t = threadIdx.x;
    if (b < EB) {
        // ---- edge: count + radial + bf16 tail pack ----
        int e = b * 256 + t;
        if (e >= N_EDGES) return;
        int r = edges[e], c = edges[N_EDGES + e];
        atomicAdd(&cnt[r], 1);
        float dx = x[r*3+0] - x[c*3+0];
        float dy = x[r*3+1] - x[c*3+1];
        float dz = x[r*3+2] - x[c*3+2];
        float radial = dx*dx + dy*dy + dz*dz;
        float4 ea = *(const float4*)(edge_attr + (size_t)e * 4);
        short8 s = { f2bf(radial), f2bf(ea.x), f2bf(ea.y), f2bf(ea.z), f2bf(ea.w), 0, 0, 0 };
        *(short8*)(tail_u + (size_t)e * 8) = s;
    } else if (b < EB + EMB_B) {
        // ---- embedding: h_bf = bf16(h0 @ emb_w + emb_b) ----
        int bb = b - EB;
        int n = bb * 2 + (t >> 7);
        int c = t & 127;
        if (n >= N_NODES) return;
        float acc = emb_b[c];
        #pragma unroll
        for (int k = 0; k < IN_NODE; ++k) acc += h0[n*IN_NODE + k] * emb_w[k*HID + c];
        h_bf[(size_t)n*HID + c] = f2bf(acc);
    } else if (b < EB + EMB_B + WPB) {
        // ---- weight prep: transpose + bf16 + pad/fold ----
        int idx = (b - EB - EMB_B) * 256 + t;
        int stride = WPB * 256;
        for (int i = idx; i < 2*128*KP1; i += stride) {
            int l = i / (128*KP1); int r = i % (128*KP1);
            int c = r / KP1; int k = r % KP1;
            float v = (k < K_EDGE) ? ew1[(size_t)l*K_EDGE*128 + (size_t)k*128 + c] : 0.0f;
            ew1T[i] = f2bf(v);
        }
        for (int i = idx; i < 2*128*128; i += stride) {
            int l = i / (128*128); int r = i % (128*128);
            int c = r / 128; int k = r % 128;
            ew2T[i] = f2bf(ew2[(size_t)l*128*128 + (size_t)k*128 + c]);
        }
        for (int i = idx; i < 2*128*KN; i += stride) {
            int l = i / (128*KN); int r = i % (128*KN);
            int c = r / KN; int k = r % KN;
            const float* base = nw1 + (size_t)l*384*128;
            float v = (k < 128) ? (base[(size_t)k*128 + c] + base[(size_t)(256+k)*128 + c])
                                : base[(size_t)k*128 + c];
            nw1T[i] = f2bf(v);
        }
        for (int i = idx; i < 2*128*128; i += stride) {
            int l = i / (128*128); int r = i % (128*128);
            int c = r / 128; int k = r % 128;
            nw2T[i] = f2bf(nw2[(size_t)l*128*128 + (size_t)k*128 + c]);
        }
    } else {
        // ---- agg zero ----
        int idx = (b - EB - EMB_B - WPB) * 256 + t;
        int stride = ZB * 256;
        float4 z = {0,0,0,0};
        float4* a4 = (float4*)agg;
        for (int i = idx; i < N_NODES*HID/4; i += stride) a4[i] = z;
    }
}

// ---------------- CSR pass 2a: per-block exclusive scan (256 rows/block) ----------------
__global__ void scan_a(const int* __restrict__ cnt, int* __restrict__ cursor,
                       int* __restrict__ blk) {
    __shared__ int s[256];
    int b = blockIdx.x, t = threadIdx.x;
    int row = b * 256 + t;
    int v = (row < N_NODES) ? cnt[row] : 0;
    s[t] = v;
    __syncthreads();
    #pragma unroll
    for (int off = 1; off < 256; off <<= 1) {
        int add = (t >= off) ? s[t - off] : 0;
        __syncthreads();
        s[t] += add;
        __syncthreads();
    }
    if (row < N_NODES) cursor[row] = s[t] - v;     // exclusive within block
    if (t == 255) blk[b] = s[255];                 // block total
}

// ---------------- CSR pass 2b: exclusivize the 196 block totals ----------------
__global__ void scan_b(int* __restrict__ blk) {
    __shared__ int s[256];
    int t = threadIdx.x;
    int v = (t < NSCAN) ? blk[t] : 0;
    s[t] = v;
    __syncthreads();
    #pragma unroll
    for (int off = 1; off < 256; off <<= 1) {
        int add = (t >= off) ? s[t - off] : 0;
        __syncthreads();
        s[t] += add;
        __syncthreads();
    }
    if (t < NSCAN) blk[t] = s[t] - v;              // exclusive block offset
}

// ---------------- CSR pass 3: place srow/scol/tail in sorted order ----------------
__global__ void csr_place(const int* __restrict__ edges, const short* __restrict__ tail_u,
                          int* __restrict__ cursor, const int* __restrict__ blk,
                          int* __restrict__ srow, int* __restrict__ scol,
                          short* __restrict__ tail_s) {
    int e = blockIdx.x * 256 + threadIdx.x;
    if (e >= N_EDGES) return;
    int r = edges[e], c = edges[N_EDGES + e];
    short8 s = *(const short8*)(tail_u + (size_t)e * 8);
    int pos = atomicAdd(&cursor[r], 1) + blk[r >> 8];
    srow[pos] = r; scol[pos] = c;
    *(short8*)(tail_s + (size_t)pos * 8) = s;
}

// ---------------- MFMA edge MLP: NTPB tiles/block, msg overlaid, 4 blocks/CU ----------------
// Occupancy experiment: compiler uses ~84 VGPR (weights rematerialized from L2 per
// tile), so min-4-waves/EU fits without spills; LDS 28 KB * 4 = 112 KB <= 160 KB.
__global__ __launch_bounds__(256, 4) void edge_mfma_kernel(
    const short* __restrict__ h_bf, const short* __restrict__ tail_s,
    const int* __restrict__ srow, const int* __restrict__ scol,
    const short* __restrict__ w1T, const float* __restrict__ b1,
    const short* __restrict__ w2T, const float* __restrict__ b2,
    float* __restrict__ agg)
{
    __shared__ __align__(16) short featA[32 * AST];   // 18944 B; msg overlays here
    __shared__ __align__(16) short t1[32 * TST];      // 8704 B
    __shared__ int srowS[32];
    float* msgF = (float*)featA;                      // 32 x MST floats = 16896 B <= featA
    int t = threadIdx.x;
    int lane = t & 63;
    int wv = t >> 6;          // wave: channel block [wv*32, wv*32+32)
    int l15 = lane & 15;
    int quad = lane >> 4;
    int el = t >> 3, j = t & 7;

    // ---- preload this wave's weight fragments into registers (once) ----
    // (compiler rematerializes these as per-tile L2-hit loads at 84 VGPR — fine)
    short8 aw1[2][9], aw2[2][4];
    float4 b1v[2], b2v[2];
    #pragma unroll
    for (int mi = 0; mi < 2; ++mi) {
        #pragma unroll
        for (int ks = 0; ks < 9; ++ks)
            aw1[mi][ks] = *(const short8*)&w1T[(size_t)(wv*32 + mi*16 + l15)*KP1 + ks*32 + quad*8];
        #pragma unroll
        for (int ks = 0; ks < 4; ++ks)
            aw2[mi][ks] = *(const short8*)&w2T[(size_t)(wv*32 + mi*16 + l15)*128 + ks*32 + quad*8];
        b1v[mi] = *(const float4*)&b1[wv*32 + mi*16 + quad*4];
        b2v[mi] = *(const float4*)&b2[wv*32 + mi*16 + quad*4];
    }

    for (int it = 0; it < NTPB; ++it) {
        int e0 = (blockIdx.x * NTPB + it) * 32;
        __syncthreads();   // prior iteration's msg reads done before featA overwrite

        // ---- stage 32 edges' gathered bf16 features ----
        {
            int e = e0 + el;
            int r = srow[e], c = scol[e];
            if (j == 0) srowS[el] = r;
            const short8* hr = (const short8*)(h_bf + (size_t)r * HID + j*16);
            const short8* hc = (const short8*)(h_bf + (size_t)c * HID + j*16);
            short8 s0 = hr[0], s1 = hr[1];
            short8 s2 = hc[0], s3 = hc[1];
            *(short8*)&featA[el*AST + j*16]       = s0;
            *(short8*)&featA[el*AST + j*16 + 8]   = s1;
            *(short8*)&featA[el*AST + 128 + j*16]     = s2;
            *(short8*)&featA[el*AST + 128 + j*16 + 8] = s3;
        }
        if (t < 32) {
            int e = e0 + t;
            short8 s = *(const short8*)(tail_s + (size_t)e * 8);
            short8 z = {0,0,0,0,0,0,0,0};
            *(short8*)&featA[t*AST + 256] = s;
            *(short8*)&featA[t*AST + 264] = z;
            *(short8*)&featA[t*AST + 272] = z;
            *(short8*)&featA[t*AST + 280] = z;
        }
        __syncthreads();

        // ---- layer 1: K = 288, A resident ----
        floatx4 acc[2][2] = {{{0,0,0,0},{0,0,0,0}},{{0,0,0,0},{0,0,0,0}}};
        #pragma unroll
        for (int ks = 0; ks < 9; ++ks) {
            int koff = ks*32 + quad*8;
            short8 bb0 = *(const short8*)&featA[l15*AST + koff];
            short8 bb1 = *(const short8*)&featA[(16 + l15)*AST + koff];
            acc[0][0] = __builtin_amdgcn_mfma_f32_16x16x32_bf16(aw1[0][ks], bb0, acc[0][0], 0, 0, 0);
            acc[0][1] = __builtin_amdgcn_mfma_f32_16x16x32_bf16(aw1[0][ks], bb1, acc[0][1], 0, 0, 0);
            acc[1][0] = __builtin_amdgcn_mfma_f32_16x16x32_bf16(aw1[1][ks], bb0, acc[1][0], 0, 0, 0);
            acc[1][1] = __builtin_amdgcn_mfma_f32_16x16x32_bf16(aw1[1][ks], bb1, acc[1][1], 0, 0, 0);
        }

        // ---- epilogue 1: bias + elu -> bf16 t1[e][c] (packed cvt) ----
        #pragma unroll
        for (int mi = 0; mi < 2; ++mi) {
            int cb = wv*32 + mi*16 + quad*4;
            #pragma unroll
            for (int ni = 0; ni < 2; ++ni) {
                short2 q0 = f2bf2(elu_f(acc[mi][ni][0] + b1v[mi].x),
                                  elu_f(acc[mi][ni][1] + b1v[mi].y));
                short2 q1 = f2bf2(elu_f(acc[mi][ni][2] + b1v[mi].z),
                                  elu_f(acc[mi][ni][3] + b1v[mi].w));
                short4v s = { q0.x, q0.y, q1.x, q1.y };
                *(short4v*)&t1[(ni*16 + l15)*TST + cb] = s;
            }
        }
        __syncthreads();   // featA reads done (L1 K-loop) -> msg overlay safe after here

        // ---- layer 2: K = 128, A resident ----
        floatx4 acc2[2][2] = {{{0,0,0,0},{0,0,0,0}},{{0,0,0,0},{0,0,0,0}}};
        #pragma unroll
        for (int ks = 0; ks < 4; ++ks) {
            int koff = ks*32 + quad*8;
            short8 bb0 = *(const short8*)&t1[l15*TST + koff];
            short8 bb1 = *(const short8*)&t1[(16 + l15)*TST + koff];
            acc2[0][0] = __builtin_amdgcn_mfma_f32_16x16x32_bf16(aw2[0][ks], bb0, acc2[0][0], 0, 0, 0);
            acc2[0][1] = __builtin_amdgcn_mfma_f32_16x16x32_bf16(aw2[0][ks], bb1, acc2[0][1], 0, 0, 0);
            acc2[1][0] = __builtin_amdgcn_mfma_f32_16x16x32_bf16(aw2[1][ks], bb0, acc2[1][0], 0, 0, 0);
            acc2[1][1] = __builtin_amdgcn_mfma_f32_16x16x32_bf16(aw2[1][ks], bb1, acc2[1][1], 0, 0, 0);
        }

        // ---- epilogue 2: bias + elu -> f32 msg tile (overlaid on featA) ----
        #pragma unroll
        for (int mi = 0; mi < 2; ++mi) {
            int cb = wv*32 + mi*16 + quad*4;
            #pragma unroll
            for (int ni = 0; ni < 2; ++ni) {
                float4 v = { elu_f(acc2[mi][ni][0] + b2v[mi].x), elu_f(acc2[mi][ni][1] + b2v[mi].y),
                             elu_f(acc2[mi][ni][2] + b2v[mi].z), elu_f(acc2[mi][ni][3] + b2v[mi].w) };
                *(float4*)&msgF[(ni*16 + l15)*MST + cb] = v;
            }
        }
        __syncthreads();

        // ---- segmented reduce: thread (ch, half) walks 16 sorted edges, flush per run ----
        {
            int ch = t & 127, half = t >> 7;
            int base = half * 16;
            int prow = srowS[base];
            float run = 0.0f;
            #pragma unroll
            for (int i = 0; i < 16; ++i) {
                int rr = srowS[base + i];
                if (rr != prow) {
                    unsafeAtomicAdd(&agg[(size_t)prow * HID + ch], run);
                    run = 0.0f; prow = rr;
                }
                run += msgF[(base + i)*MST + ch];
            }
            unsafeAtomicAdd(&agg[(size_t)prow * HID + ch], run);
        }
    }
}

// ---------------- MFMA node MLP: register weights, NTN tiles/block, optional agg re-zero ----------------
__global__ __launch_bounds__(256, 3) void node_mfma_kernel(
    const short* __restrict__ h_bf, float* __restrict__ agg,
    const short* __restrict__ w1T, const float* __restrict__ b1,
    const short* __restrict__ w2T, const float* __restrict__ b2,
    short* __restrict__ hout_bf, int zero_agg)
{
    __shared__ short featN[32 * NST];   // 16896 B
    __shared__ short t1[32 * TST];      // 8704 B
    int t = threadIdx.x;
    int lane = t & 63;
    int wv = t >> 6;
    int l15 = lane & 15;
    int quad = lane >> 4;
    int nl = t >> 3, j = t & 7;

    // ---- preload this wave's weight fragments (once) ----
    short8 aw1[2][8], aw2[2][4];
    float4 b1v[2], b2v[2];
    #pragma unroll
    for (int mi = 0; mi < 2; ++mi) {
        #pragma unroll
        for (int ks = 0; ks < 8; ++ks)
            aw1[mi][ks] = *(const short8*)&w1T[(size_t)(wv*32 + mi*16 + l15)*KN + ks*32 + quad*8];
        #pragma unroll
        for (int ks = 0; ks < 4; ++ks)
            aw2[mi][ks] = *(const short8*)&w2T[(size_t)(wv*32 + mi*16 + l15)*128 + ks*32 + quad*8];
        b1v[mi] = *(const float4*)&b1[wv*32 + mi*16 + quad*4];
        b2v[mi] = *(const float4*)&b2[wv*32 + mi*16 + quad*4];
    }

    for (int it = 0; it < NTN; ++it) {
        int n0 = (blockIdx.x * NTN + it) * 32;
        if (n0 >= N_NODES) break;          // block-uniform
        __syncthreads();

        int n = n0 + nl;
        int idx = n < N_NODES ? n : N_NODES - 1;
        {
            const short8* hp = (const short8*)(h_bf + (size_t)idx * HID + j*16);
            short8 s0 = hp[0], s1 = hp[1];
            const float4* ap = (const float4*)(agg + (size_t)idx * HID) + j*4;
            float4 u0 = ap[0], u1 = ap[1], u2 = ap[2], u3 = ap[3];
            short2 p0 = f2bf2(u0.x, u0.y), p1 = f2bf2(u0.z, u0.w);
            short2 p2 = f2bf2(u1.x, u1.y), p3 = f2bf2(u1.z, u1.w);
            short2 p4 = f2bf2(u2.x, u2.y), p5 = f2bf2(u2.z, u2.w);
            short2 p6 = f2bf2(u3.x, u3.y), p7 = f2bf2(u3.z, u3.w);
            short8 s2 = { p0.x, p0.y, p1.x, p1.y, p2.x, p2.y, p3.x, p3.y };
            short8 s3 = { p4.x, p4.y, p5.x, p5.y, p6.x, p6.y, p7.x, p7.y };
            *(short8*)&featN[nl*NST + j*16]       = s0;
            *(short8*)&featN[nl*NST + j*16 + 8]   = s1;
            *(short8*)&featN[nl*NST + 128 + j*16]     = s2;
            *(short8*)&featN[nl*NST + 128 + j*16 + 8] = s3;
        }
        __syncthreads();

        // ---- re-zero consumed agg rows for the next layer (block owns these rows) ----
        if (zero_agg && n < N_NODES) {
            float4 z = {0,0,0,0};
            float4* ap = (float4*)(agg + (size_t)n * HID) + j*4;
            ap[0] = z; ap[1] = z; ap[2] = z; ap[3] = z;
        }

        floatx4 acc[2][2] = {{{0,0,0,0},{0,0,0,0}},{{0,0,0,0},{0,0,0,0}}};
        #pragma unroll
        for (int ks = 0; ks < 8; ++ks) {
            int koff = ks*32 + quad*8;
            short8 bb0 = *(const short8*)&featN[l15*NST + koff];
            short8 bb1 = *(const short8*)&featN[(16 + l15)*NST + koff];
            acc[0][0] = __builtin_amdgcn_mfma_f32_16x16x32_bf16(aw1[0][ks], bb0, acc[0][0], 0, 0, 0);
            acc[0][1] = __builtin_amdgcn_mfma_f32_16x16x32_bf16(aw1[0][ks], bb1, acc[0][1], 0, 0, 0);
            acc[1][0] = __builtin_amdgcn_mfma_f32_16x16x32_bf16(aw1[1][ks], bb0, acc[1][0], 0, 0, 0);
            acc[1][1] = __builtin_amdgcn_mfma_f32_16x16x32_bf16(aw1[1][ks], bb1, acc[1][1], 0, 0, 0);
        }

        #pragma unroll
        for (int mi = 0; mi < 2; ++mi) {
            int cb = wv*32 + mi*16 + quad*4;
            #pragma unroll
            for (int ni = 0; ni < 2; ++ni) {
                short2 p0 = f2bf2(elu_f(acc[mi][ni][0] + b1v[mi].x),
                                  elu_f(acc[mi][ni][1] + b1v[mi].y));
                short2 p1 = f2bf2(elu_f(acc[mi][ni][2] + b1v[mi].z),
                                  elu_f(acc[mi][ni][3] + b1v[mi].w));
                short4v s = { p0.x, p0.y, p1.x, p1.y };
                *(short4v*)&t1[(ni*16 + l15)*TST + cb] = s;
            }
        }
        __syncthreads();

        floatx4 acc2[2][2] = {{{0,0,0,0},{0,0,0,0}},{{0,0,0,0},{0,0,0,0}}};
        #pragma unroll
        for (int ks = 0; ks < 4; ++ks) {
            int koff = ks*32 + quad*8;
            short8 bb0 = *(const short8*)&t1[l15*TST + koff];
            short8 bb1 = *(const short8*)&t1[(16 + l15)*TST + koff];
            acc2[0][0] = __builtin_amdgcn_mfma_f32_16x16x32_bf16(aw2[0][ks], bb0, acc2[0][0], 0, 0, 0);
            acc2[0][1] = __builtin_amdgcn_mfma_f32_16x16x32_bf16(aw2[0][ks], bb1, acc2[0][1], 0, 0, 0);
            acc2[1][0] = __builtin_amdgcn_mfma_f32_16x16x32_bf16(aw2[1][ks], bb0, acc2[1][0], 0, 0, 0);
            acc2[1][1] = __builtin_amdgcn_mfma_f32_16x16x32_bf16(aw2[1][ks], bb1, acc2[1][1], 0, 0, 0);
        }

        #pragma unroll
        for (int mi = 0; mi < 2; ++mi) {
            int cb = wv*32 + mi*16 + quad*4;
            #pragma unroll
            for (int ni = 0; ni < 2; ++ni) {
                int nn = n0 + ni*16 + l15;
                if (nn < N_NODES) {
                    short2 p0 = f2bf2(acc2[mi][ni][0] + b2v[mi].x, acc2[mi][ni][1] + b2v[mi].y);
                    short2 p1 = f2bf2(acc2[mi][ni][2] + b2v[mi].z, acc2[mi][ni][3] + b2v[mi].w);
                    short4v s = { p0.x, p0.y, p1.x, p1.y };
                    *(short4v*)&hout_bf[(size_t)nn*HID + cb] = s;
                }
            }
        }
    }
}

// ---------------- output head: z = mu + 0.01*eps*exp(0.5*logvar), bf16 h (vectorized) ----------------
__global__ void out_kernel(const short* __restrict__ h_bf, const float* __restrict__ label,
                           const float* __restrict__ eps,
                           const float* __restrict__ mu_w, const float* __restrict__ mu_b,
                           const float* __restrict__ var_w, const float* __restrict__ var_b,
                           float* __restrict__ z)
{
    int t = threadIdx.x;
    int n = blockIdx.x * 4 + (t >> 6);
    int c = t & 63;
    if (n >= N_NODES) return;
    float am = mu_b[c], av = var_b[c];
    const short8* hp = (const short8*)(h_bf + (size_t)n * HID);
    #pragma unroll 4
    for (int k8 = 0; k8 < HID / 8; ++k8) {
        short8 hv = hp[k8];
        #pragma unroll
        for (int jj = 0; jj < 8; ++jj) {
            float h = bf2f(hv[jj]);
            am += h * mu_w[(k8*8 + jj)*LAT + c];
            av += h * var_w[(k8*8 + jj)*LAT + c];
        }
    }
    #pragma unroll
    for (int k = 0; k < 7; ++k) {
        float lv = label[(size_t)n*7 + k];
        am += lv * mu_w[(HID+k)*LAT + c];
        av += lv * var_w[(HID+k)*LAT + c];
    }
    float sd = expf(av * 0.5f);
    z[(size_t)n*LAT + c] = am + 0.01f * eps[(size_t)n*LAT + c] * sd;
}

extern "C" void kernel_launch(void* const* d_in, const int* in_sizes, int n_in,
                              void* d_out, int out_size, void* d_ws, size_t ws_size,
                              hipStream_t stream) {
    const float* h0        = (const float*)d_in[0];
    const float* label     = (const float*)d_in[1];
    const float* x         = (const float*)d_in[2];
    const float* edge_attr = (const float*)d_in[3];
    const float* eps       = (const float*)d_in[4];
    const float* emb_w     = (const float*)d_in[5];
    const float* emb_b     = (const float*)d_in[6];
    const float* edge_w1   = (const float*)d_in[7];
    const float* edge_b1   = (const float*)d_in[8];
    const float* edge_w2   = (const float*)d_in[9];
    const float* edge_b2   = (const float*)d_in[10];
    const float* node_w1   = (const float*)d_in[11];
    const float* node_b1   = (const float*)d_in[12];
    const float* node_w2   = (const float*)d_in[13];
    const float* node_b2   = (const float*)d_in[14];
    const float* mu_w      = (const float*)d_in[15];
    const float* mu_b      = (const float*)d_in[16];
    const float* var_w     = (const float*)d_in[17];
    const float* var_b     = (const float*)d_in[18];
    const int*   edges     = (const int*)d_in[19];
    float* out = (float*)d_out;

    float* agg      = (float*)d_ws;                     // N*128 f32
    short* h_bf     = (short*)(agg + (size_t)N_NODES * HID);  // N*128 bf16
    short* tail_u   = h_bf + (size_t)N_NODES * HID;     // E*8 bf16 (unsorted)
    short* tail_s   = tail_u + (size_t)N_EDGES * 8;     // E*8 bf16 (sorted)
    int*   cnt      = (int*)(tail_s + (size_t)N_EDGES * 8);   // N int
    int*   cursor   = cnt + N_NODES;                    // N int
    int*   blk      = cursor + N_NODES;                 // 256 int
    int*   srow     = blk + 256;                        // E int
    int*   scol     = srow + N_EDGES;                   // E int
    short* ew1T     = (short*)(scol + N_EDGES);         // 2*128*288
    short* ew2T     = ew1T + 2*128*KP1;                 // 2*128*128
    short* nw1T     = ew2T + 2*128*128;                 // 2*128*256
    short* nw2T     = nw1T + 2*128*KN;                  // 2*128*128

    hipMemsetAsync(cnt, 0, N_NODES * sizeof(int), stream);
    prep_all<<<EB + EMB_B + WPB + ZB, 256, 0, stream>>>(
        edges, x, edge_attr, h0, emb_w, emb_b,
        edge_w1, edge_w2, node_w1, node_w2,
        cnt, tail_u, h_bf, ew1T, ew2T, nw1T, nw2T, agg);
    scan_a<<<NSCAN, 256, 0, stream>>>(cnt, cursor, blk);
    scan_b<<<1, 256, 0, stream>>>(blk);
    csr_place<<<(N_EDGES + 255) / 256, 256, 0, stream>>>(edges, tail_u, cursor, blk,
                                                         srow, scol, tail_s);

    for (int l = 0; l < 2; ++l) {
        edge_mfma_kernel<<<N_EDGES / 32 / NTPB, 256, 0, stream>>>(
            h_bf, tail_s, srow, scol,
            ew1T + (size_t)l * 128 * KP1, edge_b1 + l * HID,
            ew2T + (size_t)l * 128 * 128, edge_b2 + l * HID, agg);
        node_mfma_kernel<<<(N_NODES/32 + NTN) / NTN, 256, 0, stream>>>(
            h_bf, agg,
            nw1T + (size_t)l * 128 * KN, node_b1 + l * HID,
            nw2T + (size_t)l * 128 * 128, node_b2 + l * HID, h_bf,
            (l == 0) ? 1 : 0);
    }

    out_kernel<<<N_NODES / 4, 256, 0, stream>>>(h_bf, label, eps, mu_w, mu_b,
                                                var_w, var_b, out);
}

// Round 4
// 767.092 us; speedup vs baseline: 1.2554x; 1.2554x over previous
//
#include <hip/hip_runtime.h>
#include <hip/hip_bf16.h>
#include <math.h>

#define N_NODES 50000
#define N_EDGES 800000
#define HID 128
#define LAT 64
#define IN_NODE 11
#define K_EDGE 261    // 2*HID + 1 + 4
#define KP1 288       // K_EDGE padded to multiple of 32
#define KN 256        // node MLP folded K (h + agg)
#define AST 296       // edge feature LDS row stride (bf16 elems), 288+8 pad
#define NST 264       // node feature LDS row stride, 256+8 pad
#define TST 136       // t1 LDS row stride, 128+8 pad
#define MST 132       // msg LDS row stride (floats), 128+4 pad
#define TE 64         // edges per tile (doubled: amortize barriers + weight reloads)
#define NTPB 10       // edge tiles per block (grid 1250, 2 blocks/CU resident)
#define NTN 2         // node tiles per block (grid 782 ~ 3/CU)
#define NSCAN 196     // scan blocks: 196*256 = 50176 >= N_NODES
// prep_all block partition
#define EB 3125       // edge count+tail blocks
#define EMB_B 25000   // embedding blocks (2 nodes each)
#define WPB 32        // weight prep blocks
#define ZB 100        // agg zero blocks

typedef __attribute__((ext_vector_type(8))) short short8;
typedef __attribute__((ext_vector_type(4))) short short4v;
typedef __attribute__((ext_vector_type(4))) float floatx4;

__device__ __forceinline__ float elu_f(float v) { return v > 0.0f ? v : __expf(v) - 1.0f; }

__device__ __forceinline__ short f2bf(float f) {
    unsigned int u = __builtin_bit_cast(unsigned int, f);
    u += 0x7fffu + ((u >> 16) & 1u);   // round-to-nearest-even
    return (short)(u >> 16);
}

__device__ __forceinline__ short2 f2bf2(float a, float b) {
    float2 p; p.x = a; p.y = b;
    __hip_bfloat162 h = __float22bfloat162_rn(p);   // v_cvt_pk_bf16_f32
    short2 r;
    __builtin_memcpy(&r, &h, sizeof(r));
    return r;
}

__device__ __forceinline__ float bf2f(short s) {
    unsigned int u = ((unsigned int)(unsigned short)s) << 16;
    return __builtin_bit_cast(float, u);
}

// ---------------- fused prep: edge count+tail | emb | weight prep | agg zero ----------------
__global__ void prep_all(const int* __restrict__ edges, const float* __restrict__ x,
                         const float* __restrict__ edge_attr, const float* __restrict__ h0,
                         const float* __restrict__ emb_w, const float* __restrict__ emb_b,
                         const float* __restrict__ ew1, const float* __restrict__ ew2,
                         const float* __restrict__ nw1, const float* __restrict__ nw2,
                         int* __restrict__ cnt, short* __restrict__ tail_u,
                         short* __restrict__ h_bf,
                         short* __restrict__ ew1T, short* __restrict__ ew2T,
                         short* __restrict__ nw1T, short* __restrict__ nw2T,
                         float* __restrict__ agg) {
    int b = blockIdx.x, t = threadIdx.x;
    if (b < EB) {
        // ---- edge: count + radial + bf16 tail pack ----
        int e = b * 256 + t;
        if (e >= N_EDGES) return;
        int r = edges[e], c = edges[N_EDGES + e];
        atomicAdd(&cnt[r], 1);
        float dx = x[r*3+0] - x[c*3+0];
        float dy = x[r*3+1] - x[c*3+1];
        float dz = x[r*3+2] - x[c*3+2];
        float radial = dx*dx + dy*dy + dz*dz;
        float4 ea = *(const float4*)(edge_attr + (size_t)e * 4);
        short8 s = { f2bf(radial), f2bf(ea.x), f2bf(ea.y), f2bf(ea.z), f2bf(ea.w), 0, 0, 0 };
        *(short8*)(tail_u + (size_t)e * 8) = s;
    } else if (b < EB + EMB_B) {
        // ---- embedding: h_bf = bf16(h0 @ emb_w + emb_b) ----
        int bb = b - EB;
        int n = bb * 2 + (t >> 7);
        int c = t & 127;
        if (n >= N_NODES) return;
        float acc = emb_b[c];
        #pragma unroll
        for (int k = 0; k < IN_NODE; ++k) acc += h0[n*IN_NODE + k] * emb_w[k*HID + c];
        h_bf[(size_t)n*HID + c] = f2bf(acc);
    } else if (b < EB + EMB_B + WPB) {
        // ---- weight prep: transpose + bf16 + pad/fold ----
        int idx = (b - EB - EMB_B) * 256 + t;
        int stride = WPB * 256;
        for (int i = idx; i < 2*128*KP1; i += stride) {
            int l = i / (128*KP1); int r = i % (128*KP1);
            int c = r / KP1; int k = r % KP1;
            float v = (k < K_EDGE) ? ew1[(size_t)l*K_EDGE*128 + (size_t)k*128 + c] : 0.0f;
            ew1T[i] = f2bf(v);
        }
        for (int i = idx; i < 2*128*128; i += stride) {
            int l = i / (128*128); int r = i % (128*128);
            int c = r / 128; int k = r % 128;
            ew2T[i] = f2bf(ew2[(size_t)l*128*128 + (size_t)k*128 + c]);
        }
        for (int i = idx; i < 2*128*KN; i += stride) {
            int l = i / (128*KN); int r = i % (128*KN);
            int c = r / KN; int k = r % KN;
            const float* base = nw1 + (size_t)l*384*128;
            float v = (k < 128) ? (base[(size_t)k*128 + c] + base[(size_t)(256+k)*128 + c])
                                : base[(size_t)k*128 + c];
            nw1T[i] = f2bf(v);
        }
        for (int i = idx; i < 2*128*128; i += stride) {
            int l = i / (128*128); int r = i % (128*128);
            int c = r / 128; int k = r % 128;
            nw2T[i] = f2bf(nw2[(size_t)l*128*128 + (size_t)k*128 + c]);
        }
    } else {
        // ---- agg zero ----
        int idx = (b - EB - EMB_B - WPB) * 256 + t;
        int stride = ZB * 256;
        float4 z = {0,0,0,0};
        float4* a4 = (float4*)agg;
        for (int i = idx; i < N_NODES*HID/4; i += stride) a4[i] = z;
    }
}

// ---------------- CSR pass 2a: per-block exclusive scan (256 rows/block) ----------------
__global__ void scan_a(const int* __restrict__ cnt, int* __restrict__ cursor,
                       int* __restrict__ blk) {
    __shared__ int s[256];
    int b = blockIdx.x, t = threadIdx.x;
    int row = b * 256 + t;
    int v = (row < N_NODES) ? cnt[row] : 0;
    s[t] = v;
    __syncthreads();
    #pragma unroll
    for (int off = 1; off < 256; off <<= 1) {
        int add = (t >= off) ? s[t - off] : 0;
        __syncthreads();
        s[t] += add;
        __syncthreads();
    }
    if (row < N_NODES) cursor[row] = s[t] - v;     // exclusive within block
    if (t == 255) blk[b] = s[255];                 // block total
}

// ---------------- CSR pass 2b: exclusivize the 196 block totals ----------------
__global__ void scan_b(int* __restrict__ blk) {
    __shared__ int s[256];
    int t = threadIdx.x;
    int v = (t < NSCAN) ? blk[t] : 0;
    s[t] = v;
    __syncthreads();
    #pragma unroll
    for (int off = 1; off < 256; off <<= 1) {
        int add = (t >= off) ? s[t - off] : 0;
        __syncthreads();
        s[t] += add;
        __syncthreads();
    }
    if (t < NSCAN) blk[t] = s[t] - v;              // exclusive block offset
}

// ---------------- CSR pass 3: place srow/scol/tail in sorted order ----------------
__global__ void csr_place(const int* __restrict__ edges, const short* __restrict__ tail_u,
                          int* __restrict__ cursor, const int* __restrict__ blk,
                          int* __restrict__ srow, int* __restrict__ scol,
                          short* __restrict__ tail_s) {
    int e = blockIdx.x * 256 + threadIdx.x;
    if (e >= N_EDGES) return;
    int r = edges[e], c = edges[N_EDGES + e];
    short8 s = *(const short8*)(tail_u + (size_t)e * 8);
    int pos = atomicAdd(&cursor[r], 1) + blk[r >> 8];
    srow[pos] = r; scol[pos] = c;
    *(short8*)(tail_s + (size_t)pos * 8) = s;
}

// ---------------- MFMA edge MLP: 64-edge tiles, msg overlaid, 2 blocks/CU ----------------
// TE=64 halves per-edge barrier count and per-edge weight-reload traffic vs TE=32.
// LDS ~55.5 KB/block -> exactly 2 blocks/CU (matches measured residency).
// bounds=2: VGPR cap 256; compiler needs ~84-140 -> no spill (r3 lesson: bounds=4
// forced 64 VGPR -> scratch spill -> FETCH 5.4x, dur 1.7x. Never cap below ~128 here.)
__global__ __launch_bounds__(256, 2) void edge_mfma_kernel(
    const short* __restrict__ h_bf, const short* __restrict__ tail_s,
    const int* __restrict__ srow, const int* __restrict__ scol,
    const short* __restrict__ w1T, const float* __restrict__ b1,
    const short* __restrict__ w2T, const float* __restrict__ b2,
    float* __restrict__ agg)
{
    __shared__ __align__(16) short featA[TE * AST];   // 37888 B; msg overlays here
    __shared__ __align__(16) short t1[TE * TST];      // 17408 B
    __shared__ int srowS[TE];
    float* msgF = (float*)featA;                      // TE x MST floats = 33792 B <= featA
    int t = threadIdx.x;
    int lane = t & 63;
    int wv = t >> 6;          // wave: channel block [wv*32, wv*32+32)
    int l15 = lane & 15;
    int quad = lane >> 4;
    int el = t >> 2, j = t & 3;   // staging: 4 threads/edge, 32 elems (4 short8) each side

    // ---- weight fragments (source-hoisted; compiler rematerializes per tile from L1/L2) ----
    short8 aw1[2][9], aw2[2][4];
    float4 b1v[2], b2v[2];
    #pragma unroll
    for (int mi = 0; mi < 2; ++mi) {
        #pragma unroll
        for (int ks = 0; ks < 9; ++ks)
            aw1[mi][ks] = *(const short8*)&w1T[(size_t)(wv*32 + mi*16 + l15)*KP1 + ks*32 + quad*8];
        #pragma unroll
        for (int ks = 0; ks < 4; ++ks)
            aw2[mi][ks] = *(const short8*)&w2T[(size_t)(wv*32 + mi*16 + l15)*128 + ks*32 + quad*8];
        b1v[mi] = *(const float4*)&b1[wv*32 + mi*16 + quad*4];
        b2v[mi] = *(const float4*)&b2[wv*32 + mi*16 + quad*4];
    }

    for (int it = 0; it < NTPB; ++it) {
        int e0 = (blockIdx.x * NTPB + it) * TE;
        __syncthreads();   // prior iteration's msg reads done before featA overwrite

        // ---- stage TE edges' gathered bf16 features ----
        {
            int e = e0 + el;
            int r = srow[e], c = scol[e];
            if (j == 0) srowS[el] = r;
            const short8* hr = (const short8*)(h_bf + (size_t)r * HID) + j*4;
            const short8* hc = (const short8*)(h_bf + (size_t)c * HID) + j*4;
            short8 s0 = hr[0], s1 = hr[1], s2 = hr[2], s3 = hr[3];
            short8 u0 = hc[0], u1 = hc[1], u2 = hc[2], u3 = hc[3];
            short* d = &featA[el*AST + j*32];
            *(short8*)(d)      = s0;
            *(short8*)(d + 8)  = s1;
            *(short8*)(d + 16) = s2;
            *(short8*)(d + 24) = s3;
            short* d2 = &featA[el*AST + 128 + j*32];
            *(short8*)(d2)      = u0;
            *(short8*)(d2 + 8)  = u1;
            *(short8*)(d2 + 16) = u2;
            *(short8*)(d2 + 24) = u3;
        }
        if (t < TE) {
            int e = e0 + t;
            short8 s = *(const short8*)(tail_s + (size_t)e * 8);
            short8 z = {0,0,0,0,0,0,0,0};
            *(short8*)&featA[t*AST + 256] = s;
            *(short8*)&featA[t*AST + 264] = z;
            *(short8*)&featA[t*AST + 272] = z;
            *(short8*)&featA[t*AST + 280] = z;
        }
        __syncthreads();

        // ---- layer 1: K = 288, 72 MFMA/wave ----
        floatx4 acc[2][4] = {{{0,0,0,0},{0,0,0,0},{0,0,0,0},{0,0,0,0}},
                             {{0,0,0,0},{0,0,0,0},{0,0,0,0},{0,0,0,0}}};
        #pragma unroll
        for (int ks = 0; ks < 9; ++ks) {
            int koff = ks*32 + quad*8;
            short8 bb0 = *(const short8*)&featA[l15*AST + koff];
            short8 bb1 = *(const short8*)&featA[(16 + l15)*AST + koff];
            short8 bb2 = *(const short8*)&featA[(32 + l15)*AST + koff];
            short8 bb3 = *(const short8*)&featA[(48 + l15)*AST + koff];
            acc[0][0] = __builtin_amdgcn_mfma_f32_16x16x32_bf16(aw1[0][ks], bb0, acc[0][0], 0, 0, 0);
            acc[0][1] = __builtin_amdgcn_mfma_f32_16x16x32_bf16(aw1[0][ks], bb1, acc[0][1], 0, 0, 0);
            acc[0][2] = __builtin_amdgcn_mfma_f32_16x16x32_bf16(aw1[0][ks], bb2, acc[0][2], 0, 0, 0);
            acc[0][3] = __builtin_amdgcn_mfma_f32_16x16x32_bf16(aw1[0][ks], bb3, acc[0][3], 0, 0, 0);
            acc[1][0] = __builtin_amdgcn_mfma_f32_16x16x32_bf16(aw1[1][ks], bb0, acc[1][0], 0, 0, 0);
            acc[1][1] = __builtin_amdgcn_mfma_f32_16x16x32_bf16(aw1[1][ks], bb1, acc[1][1], 0, 0, 0);
            acc[1][2] = __builtin_amdgcn_mfma_f32_16x16x32_bf16(aw1[1][ks], bb2, acc[1][2], 0, 0, 0);
            acc[1][3] = __builtin_amdgcn_mfma_f32_16x16x32_bf16(aw1[1][ks], bb3, acc[1][3], 0, 0, 0);
        }

        // ---- epilogue 1: bias + elu -> bf16 t1[e][c] (packed cvt) ----
        #pragma unroll
        for (int mi = 0; mi < 2; ++mi) {
            int cb = wv*32 + mi*16 + quad*4;
            #pragma unroll
            for (int ni = 0; ni < 4; ++ni) {
                short2 q0 = f2bf2(elu_f(acc[mi][ni][0] + b1v[mi].x),
                                  elu_f(acc[mi][ni][1] + b1v[mi].y));
                short2 q1 = f2bf2(elu_f(acc[mi][ni][2] + b1v[mi].z),
                                  elu_f(acc[mi][ni][3] + b1v[mi].w));
                short4v s = { q0.x, q0.y, q1.x, q1.y };
                *(short4v*)&t1[(ni*16 + l15)*TST + cb] = s;
            }
        }
        __syncthreads();   // featA reads done (L1 K-loop) -> msg overlay safe after here

        // ---- layer 2: K = 128, 32 MFMA/wave ----
        floatx4 acc2[2][4] = {{{0,0,0,0},{0,0,0,0},{0,0,0,0},{0,0,0,0}},
                              {{0,0,0,0},{0,0,0,0},{0,0,0,0},{0,0,0,0}}};
        #pragma unroll
        for (int ks = 0; ks < 4; ++ks) {
            int koff = ks*32 + quad*8;
            short8 bb0 = *(const short8*)&t1[l15*TST + koff];
            short8 bb1 = *(const short8*)&t1[(16 + l15)*TST + koff];
            short8 bb2 = *(const short8*)&t1[(32 + l15)*TST + koff];
            short8 bb3 = *(const short8*)&t1[(48 + l15)*TST + koff];
            acc2[0][0] = __builtin_amdgcn_mfma_f32_16x16x32_bf16(aw2[0][ks], bb0, acc2[0][0], 0, 0, 0);
            acc2[0][1] = __builtin_amdgcn_mfma_f32_16x16x32_bf16(aw2[0][ks], bb1, acc2[0][1], 0, 0, 0);
            acc2[0][2] = __builtin_amdgcn_mfma_f32_16x16x32_bf16(aw2[0][ks], bb2, acc2[0][2], 0, 0, 0);
            acc2[0][3] = __builtin_amdgcn_mfma_f32_16x16x32_bf16(aw2[0][ks], bb3, acc2[0][3], 0, 0, 0);
            acc2[1][0] = __builtin_amdgcn_mfma_f32_16x16x32_bf16(aw2[1][ks], bb0, acc2[1][0], 0, 0, 0);
            acc2[1][1] = __builtin_amdgcn_mfma_f32_16x16x32_bf16(aw2[1][ks], bb1, acc2[1][1], 0, 0, 0);
            acc2[1][2] = __builtin_amdgcn_mfma_f32_16x16x32_bf16(aw2[1][ks], bb2, acc2[1][2], 0, 0, 0);
            acc2[1][3] = __builtin_amdgcn_mfma_f32_16x16x32_bf16(aw2[1][ks], bb3, acc2[1][3], 0, 0, 0);
        }

        // ---- epilogue 2: bias + elu -> f32 msg tile (overlaid on featA) ----
        #pragma unroll
        for (int mi = 0; mi < 2; ++mi) {
            int cb = wv*32 + mi*16 + quad*4;
            #pragma unroll
            for (int ni = 0; ni < 4; ++ni) {
                float4 v = { elu_f(acc2[mi][ni][0] + b2v[mi].x), elu_f(acc2[mi][ni][1] + b2v[mi].y),
                             elu_f(acc2[mi][ni][2] + b2v[mi].z), elu_f(acc2[mi][ni][3] + b2v[mi].w) };
                *(float4*)&msgF[(ni*16 + l15)*MST + cb] = v;
            }
        }
        __syncthreads();

        // ---- segmented reduce: thread (ch, seg) walks 32 sorted edges, flush per run ----
        {
            int ch = t & 127, seg = t >> 7;
            int base = seg * 32;
            int prow = srowS[base];
            float run = 0.0f;
            #pragma unroll
            for (int i = 0; i < 32; ++i) {
                int rr = srowS[base + i];
                if (rr != prow) {
                    unsafeAtomicAdd(&agg[(size_t)prow * HID + ch], run);
                    run = 0.0f; prow = rr;
                }
                run += msgF[(base + i)*MST + ch];
            }
            unsafeAtomicAdd(&agg[(size_t)prow * HID + ch], run);
        }
    }
}

// ---------------- MFMA node MLP: register weights, NTN tiles/block, optional agg re-zero ----------------
__global__ __launch_bounds__(256, 3) void node_mfma_kernel(
    const short* __restrict__ h_bf, float* __restrict__ agg,
    const short* __restrict__ w1T, const float* __restrict__ b1,
    const short* __restrict__ w2T, const float* __restrict__ b2,
    short* __restrict__ hout_bf, int zero_agg)
{
    __shared__ short featN[32 * NST];   // 16896 B
    __shared__ short t1[32 * TST];      // 8704 B
    int t = threadIdx.x;
    int lane = t & 63;
    int wv = t >> 6;
    int l15 = lane & 15;
    int quad = lane >> 4;
    int nl = t >> 3, j = t & 7;

    // ---- preload this wave's weight fragments (once) ----
    short8 aw1[2][8], aw2[2][4];
    float4 b1v[2], b2v[2];
    #pragma unroll
    for (int mi = 0; mi < 2; ++mi) {
        #pragma unroll
        for (int ks = 0; ks < 8; ++ks)
            aw1[mi][ks] = *(const short8*)&w1T[(size_t)(wv*32 + mi*16 + l15)*KN + ks*32 + quad*8];
        #pragma unroll
        for (int ks = 0; ks < 4; ++ks)
            aw2[mi][ks] = *(const short8*)&w2T[(size_t)(wv*32 + mi*16 + l15)*128 + ks*32 + quad*8];
        b1v[mi] = *(const float4*)&b1[wv*32 + mi*16 + quad*4];
        b2v[mi] = *(const float4*)&b2[wv*32 + mi*16 + quad*4];
    }

    for (int it = 0; it < NTN; ++it) {
        int n0 = (blockIdx.x * NTN + it) * 32;
        if (n0 >= N_NODES) break;          // block-uniform
        __syncthreads();

        int n = n0 + nl;
        int idx = n < N_NODES ? n : N_NODES - 1;
        {
            const short8* hp = (const short8*)(h_bf + (size_t)idx * HID + j*16);
            short8 s0 = hp[0], s1 = hp[1];
            const float4* ap = (const float4*)(agg + (size_t)idx * HID) + j*4;
            float4 u0 = ap[0], u1 = ap[1], u2 = ap[2], u3 = ap[3];
            short2 p0 = f2bf2(u0.x, u0.y), p1 = f2bf2(u0.z, u0.w);
            short2 p2 = f2bf2(u1.x, u1.y), p3 = f2bf2(u1.z, u1.w);
            short2 p4 = f2bf2(u2.x, u2.y), p5 = f2bf2(u2.z, u2.w);
            short2 p6 = f2bf2(u3.x, u3.y), p7 = f2bf2(u3.z, u3.w);
            short8 s2 = { p0.x, p0.y, p1.x, p1.y, p2.x, p2.y, p3.x, p3.y };
            short8 s3 = { p4.x, p4.y, p5.x, p5.y, p6.x, p6.y, p7.x, p7.y };
            *(short8*)&featN[nl*NST + j*16]       = s0;
            *(short8*)&featN[nl*NST + j*16 + 8]   = s1;
            *(short8*)&featN[nl*NST + 128 + j*16]     = s2;
            *(short8*)&featN[nl*NST + 128 + j*16 + 8] = s3;
        }
        __syncthreads();

        // ---- re-zero consumed agg rows for the next layer (block owns these rows) ----
        if (zero_agg && n < N_NODES) {
            float4 z = {0,0,0,0};
            float4* ap = (float4*)(agg + (size_t)n * HID) + j*4;
            ap[0] = z; ap[1] = z; ap[2] = z; ap[3] = z;
        }

        floatx4 acc[2][2] = {{{0,0,0,0},{0,0,0,0}},{{0,0,0,0},{0,0,0,0}}};
        #pragma unroll
        for (int ks = 0; ks < 8; ++ks) {
            int koff = ks*32 + quad*8;
            short8 bb0 = *(const short8*)&featN[l15*NST + koff];
            short8 bb1 = *(const short8*)&featN[(16 + l15)*NST + koff];
            acc[0][0] = __builtin_amdgcn_mfma_f32_16x16x32_bf16(aw1[0][ks], bb0, acc[0][0], 0, 0, 0);
            acc[0][1] = __builtin_amdgcn_mfma_f32_16x16x32_bf16(aw1[0][ks], bb1, acc[0][1], 0, 0, 0);
            acc[1][0] = __builtin_amdgcn_mfma_f32_16x16x32_bf16(aw1[1][ks], bb0, acc[1][0], 0, 0, 0);
            acc[1][1] = __builtin_amdgcn_mfma_f32_16x16x32_bf16(aw1[1][ks], bb1, acc[1][1], 0, 0, 0);
        }

        #pragma unroll
        for (int mi = 0; mi < 2; ++mi) {
            int cb = wv*32 + mi*16 + quad*4;
            #pragma unroll
            for (int ni = 0; ni < 2; ++ni) {
                short2 p0 = f2bf2(elu_f(acc[mi][ni][0] + b1v[mi].x),
                                  elu_f(acc[mi][ni][1] + b1v[mi].y));
                short2 p1 = f2bf2(elu_f(acc[mi][ni][2] + b1v[mi].z),
                                  elu_f(acc[mi][ni][3] + b1v[mi].w));
                short4v s = { p0.x, p0.y, p1.x, p1.y };
                *(short4v*)&t1[(ni*16 + l15)*TST + cb] = s;
            }
        }
        __syncthreads();

        floatx4 acc2[2][2] = {{{0,0,0,0},{0,0,0,0}},{{0,0,0,0},{0,0,0,0}}};
        #pragma unroll
        for (int ks = 0; ks < 4; ++ks) {
            int koff = ks*32 + quad*8;
            short8 bb0 = *(const short8*)&t1[l15*TST + koff];
            short8 bb1 = *(const short8*)&t1[(16 + l15)*TST + koff];
            acc2[0][0] = __builtin_amdgcn_mfma_f32_16x16x32_bf16(aw2[0][ks], bb0, acc2[0][0], 0, 0, 0);
            acc2[0][1] = __builtin_amdgcn_mfma_f32_16x16x32_bf16(aw2[0][ks], bb1, acc2[0][1], 0, 0, 0);
            acc2[1][0] = __builtin_amdgcn_mfma_f32_16x16x32_bf16(aw2[1][ks], bb0, acc2[1][0], 0, 0, 0);
            acc2[1][1] = __builtin_amdgcn_mfma_f32_16x16x32_bf16(aw2[1][ks], bb1, acc2[1][1], 0, 0, 0);
        }

        #pragma unroll
        for (int mi = 0; mi < 2; ++mi) {
            int cb = wv*32 + mi*16 + quad*4;
            #pragma unroll
            for (int ni = 0; ni < 2; ++ni) {
                int nn = n0 + ni*16 + l15;
                if (nn < N_NODES) {
                    short2 p0 = f2bf2(acc2[mi][ni][0] + b2v[mi].x, acc2[mi][ni][1] + b2v[mi].y);
                    short2 p1 = f2bf2(acc2[mi][ni][2] + b2v[mi].z, acc2[mi][ni][3] + b2v[mi].w);
                    short4v s = { p0.x, p0.y, p1.x, p1.y };
                    *(short4v*)&hout_bf[(size_t)nn*HID + cb] = s;
                }
            }
        }
    }
}

// ---------------- output head: z = mu + 0.01*eps*exp(0.5*logvar), bf16 h (vectorized) ----------------
__global__ void out_kernel(const short* __restrict__ h_bf, const float* __restrict__ label,
                           const float* __restrict__ eps,
                           const float* __restrict__ mu_w, const float* __restrict__ mu_b,
                           const float* __restrict__ var_w, const float* __restrict__ var_b,
                           float* __restrict__ z)
{
    int t = threadIdx.x;
    int n = blockIdx.x * 4 + (t >> 6);
    int c = t & 63;
    if (n >= N_NODES) return;
    float am = mu_b[c], av = var_b[c];
    const short8* hp = (const short8*)(h_bf + (size_t)n * HID);
    #pragma unroll 4
    for (int k8 = 0; k8 < HID / 8; ++k8) {
        short8 hv = hp[k8];
        #pragma unroll
        for (int jj = 0; jj < 8; ++jj) {
            float h = bf2f(hv[jj]);
            am += h * mu_w[(k8*8 + jj)*LAT + c];
            av += h * var_w[(k8*8 + jj)*LAT + c];
        }
    }
    #pragma unroll
    for (int k = 0; k < 7; ++k) {
        float lv = label[(size_t)n*7 + k];
        am += lv * mu_w[(HID+k)*LAT + c];
        av += lv * var_w[(HID+k)*LAT + c];
    }
    float sd = expf(av * 0.5f);
    z[(size_t)n*LAT + c] = am + 0.01f * eps[(size_t)n*LAT + c] * sd;
}

extern "C" void kernel_launch(void* const* d_in, const int* in_sizes, int n_in,
                              void* d_out, int out_size, void* d_ws, size_t ws_size,
                              hipStream_t stream) {
    const float* h0        = (const float*)d_in[0];
    const float* label     = (const float*)d_in[1];
    const float* x         = (const float*)d_in[2];
    const float* edge_attr = (const float*)d_in[3];
    const float* eps       = (const float*)d_in[4];
    const float* emb_w     = (const float*)d_in[5];
    const float* emb_b     = (const float*)d_in[6];
    const float* edge_w1   = (const float*)d_in[7];
    const float* edge_b1   = (const float*)d_in[8];
    const float* edge_w2   = (const float*)d_in[9];
    const float* edge_b2   = (const float*)d_in[10];
    const float* node_w1   = (const float*)d_in[11];
    const float* node_b1   = (const float*)d_in[12];
    const float* node_w2   = (const float*)d_in[13];
    const float* node_b2   = (const float*)d_in[14];
    const float* mu_w      = (const float*)d_in[15];
    const float* mu_b      = (const float*)d_in[16];
    const float* var_w     = (const float*)d_in[17];
    const float* var_b     = (const float*)d_in[18];
    const int*   edges     = (const int*)d_in[19];
    float* out = (float*)d_out;

    float* agg      = (float*)d_ws;                     // N*128 f32
    short* h_bf     = (short*)(agg + (size_t)N_NODES * HID);  // N*128 bf16
    short* tail_u   = h_bf + (size_t)N_NODES * HID;     // E*8 bf16 (unsorted)
    short* tail_s   = tail_u + (size_t)N_EDGES * 8;     // E*8 bf16 (sorted)
    int*   cnt      = (int*)(tail_s + (size_t)N_EDGES * 8);   // N int
    int*   cursor   = cnt + N_NODES;                    // N int
    int*   blk      = cursor + N_NODES;                 // 256 int
    int*   srow     = blk + 256;                        // E int
    int*   scol     = srow + N_EDGES;                   // E int
    short* ew1T     = (short*)(scol + N_EDGES);         // 2*128*288
    short* ew2T     = ew1T + 2*128*KP1;                 // 2*128*128
    short* nw1T     = ew2T + 2*128*128;                 // 2*128*256
    short* nw2T     = nw1T + 2*128*KN;                  // 2*128*128

    hipMemsetAsync(cnt, 0, N_NODES * sizeof(int), stream);
    prep_all<<<EB + EMB_B + WPB + ZB, 256, 0, stream>>>(
        edges, x, edge_attr, h0, emb_w, emb_b,
        edge_w1, edge_w2, node_w1, node_w2,
        cnt, tail_u, h_bf, ew1T, ew2T, nw1T, nw2T, agg);
    scan_a<<<NSCAN, 256, 0, stream>>>(cnt, cursor, blk);
    scan_b<<<1, 256, 0, stream>>>(blk);
    csr_place<<<(N_EDGES + 255) / 256, 256, 0, stream>>>(edges, tail_u, cursor, blk,
                                                         srow, scol, tail_s);

    for (int l = 0; l < 2; ++l) {
        edge_mfma_kernel<<<N_EDGES / TE / NTPB, 256, 0, stream>>>(
            h_bf, tail_s, srow, scol,
            ew1T + (size_t)l * 128 * KP1, edge_b1 + l * HID,
            ew2T + (size_t)l * 128 * 128, edge_b2 + l * HID, agg);
        node_mfma_kernel<<<(N_NODES/32 + NTN) / NTN, 256, 0, stream>>>(
            h_bf, agg,
            nw1T + (size_t)l * 128 * KN, node_b1 + l * HID,
            nw2T + (size_t)l * 128 * 128, node_b2 + l * HID, h_bf,
            (l == 0) ? 1 : 0);
    }

    out_kernel<<<N_NODES / 4, 256, 0, stream>>>(h_bf, label, eps, mu_w, mu_b,
                                                var_w, var_b, out);
}

// Round 5
// 766.382 us; speedup vs baseline: 1.2566x; 1.0009x over previous
//
#include <hip/hip_runtime.h>
#include <hip/hip_bf16.h>
#include <math.h>

#define N_NODES 50000
#define N_EDGES 800000
#define HID 128
#define LAT 64
#define IN_NODE 11
#define K_EDGE 261    // 2*HID + 1 + 4
#define KP1 288       // K_EDGE padded to multiple of 32
#define KN 256        // node MLP folded K (h + agg)
#define AST 296       // edge feature LDS row stride (bf16 elems), 288+8 pad
#define NST 264       // node feature LDS row stride, 256+8 pad
#define TST 136       // t1 LDS row stride, 128+8 pad
#define MST 132       // msg LDS row stride (floats), 128+4 pad
#define TE 32         // edges per tile (r4 lesson: 64 hurt — longer phases, less overlap)
#define NTPB 20       // edge tiles per block (grid 1250)
#define NTN 2         // node tiles per block (grid 782 ~ 3/CU)
#define NSCAN 196     // scan blocks: 196*256 = 50176 >= N_NODES
// prep_all block partition
#define EB 3125       // edge count+tail blocks
#define EMB_B 25000   // embedding blocks (2 nodes each)
#define WPB 32        // weight prep blocks
#define ZB 100        // agg zero blocks

typedef __attribute__((ext_vector_type(8))) short short8;
typedef __attribute__((ext_vector_type(4))) short short4v;
typedef __attribute__((ext_vector_type(4))) float floatx4;

__device__ __forceinline__ float elu_f(float v) { return v > 0.0f ? v : __expf(v) - 1.0f; }

__device__ __forceinline__ short f2bf(float f) {
    unsigned int u = __builtin_bit_cast(unsigned int, f);
    u += 0x7fffu + ((u >> 16) & 1u);   // round-to-nearest-even
    return (short)(u >> 16);
}

__device__ __forceinline__ short2 f2bf2(float a, float b) {
    float2 p; p.x = a; p.y = b;
    __hip_bfloat162 h = __float22bfloat162_rn(p);   // v_cvt_pk_bf16_f32
    short2 r;
    __builtin_memcpy(&r, &h, sizeof(r));
    return r;
}

__device__ __forceinline__ float bf2f(short s) {
    unsigned int u = ((unsigned int)(unsigned short)s) << 16;
    return __builtin_bit_cast(float, u);
}

// ---------------- fused prep: edge count+tail | emb | weight prep | agg zero ----------------
__global__ void prep_all(const int* __restrict__ edges, const float* __restrict__ x,
                         const float* __restrict__ edge_attr, const float* __restrict__ h0,
                         const float* __restrict__ emb_w, const float* __restrict__ emb_b,
                         const float* __restrict__ ew1, const float* __restrict__ ew2,
                         const float* __restrict__ nw1, const float* __restrict__ nw2,
                         int* __restrict__ cnt, short* __restrict__ tail_u,
                         short* __restrict__ h_bf,
                         short* __restrict__ ew1T, short* __restrict__ ew2T,
                         short* __restrict__ nw1T, short* __restrict__ nw2T,
                         float* __restrict__ agg) {
    int b = blockIdx.x, t = threadIdx.x;
    if (b < EB) {
        // ---- edge: count + radial + bf16 tail pack ----
        int e = b * 256 + t;
        if (e >= N_EDGES) return;
        int r = edges[e], c = edges[N_EDGES + e];
        atomicAdd(&cnt[r], 1);
        float dx = x[r*3+0] - x[c*3+0];
        float dy = x[r*3+1] - x[c*3+1];
        float dz = x[r*3+2] - x[c*3+2];
        float radial = dx*dx + dy*dy + dz*dz;
        float4 ea = *(const float4*)(edge_attr + (size_t)e * 4);
        short8 s = { f2bf(radial), f2bf(ea.x), f2bf(ea.y), f2bf(ea.z), f2bf(ea.w), 0, 0, 0 };
        *(short8*)(tail_u + (size_t)e * 8) = s;
    } else if (b < EB + EMB_B) {
        // ---- embedding: h_bf = bf16(h0 @ emb_w + emb_b) ----
        int bb = b - EB;
        int n = bb * 2 + (t >> 7);
        int c = t & 127;
        if (n >= N_NODES) return;
        float acc = emb_b[c];
        #pragma unroll
        for (int k = 0; k < IN_NODE; ++k) acc += h0[n*IN_NODE + k] * emb_w[k*HID + c];
        h_bf[(size_t)n*HID + c] = f2bf(acc);
    } else if (b < EB + EMB_B + WPB) {
        // ---- weight prep: transpose + bf16 + pad/fold ----
        int idx = (b - EB - EMB_B) * 256 + t;
        int stride = WPB * 256;
        for (int i = idx; i < 2*128*KP1; i += stride) {
            int l = i / (128*KP1); int r = i % (128*KP1);
            int c = r / KP1; int k = r % KP1;
            float v = (k < K_EDGE) ? ew1[(size_t)l*K_EDGE*128 + (size_t)k*128 + c] : 0.0f;
            ew1T[i] = f2bf(v);
        }
        for (int i = idx; i < 2*128*128; i += stride) {
            int l = i / (128*128); int r = i % (128*128);
            int c = r / 128; int k = r % 128;
            ew2T[i] = f2bf(ew2[(size_t)l*128*128 + (size_t)k*128 + c]);
        }
        for (int i = idx; i < 2*128*KN; i += stride) {
            int l = i / (128*KN); int r = i % (128*KN);
            int c = r / KN; int k = r % KN;
            const float* base = nw1 + (size_t)l*384*128;
            float v = (k < 128) ? (base[(size_t)k*128 + c] + base[(size_t)(256+k)*128 + c])
                                : base[(size_t)k*128 + c];
            nw1T[i] = f2bf(v);
        }
        for (int i = idx; i < 2*128*128; i += stride) {
            int l = i / (128*128); int r = i % (128*128);
            int c = r / 128; int k = r % 128;
            nw2T[i] = f2bf(nw2[(size_t)l*128*128 + (size_t)k*128 + c]);
        }
    } else {
        // ---- agg zero ----
        int idx = (b - EB - EMB_B - WPB) * 256 + t;
        int stride = ZB * 256;
        float4 z = {0,0,0,0};
        float4* a4 = (float4*)agg;
        for (int i = idx; i < N_NODES*HID/4; i += stride) a4[i] = z;
    }
}

// ---------------- CSR pass 2a: per-block exclusive scan (256 rows/block) ----------------
__global__ void scan_a(const int* __restrict__ cnt, int* __restrict__ cursor,
                       int* __restrict__ blk) {
    __shared__ int s[256];
    int b = blockIdx.x, t = threadIdx.x;
    int row = b * 256 + t;
    int v = (row < N_NODES) ? cnt[row] : 0;
    s[t] = v;
    __syncthreads();
    #pragma unroll
    for (int off = 1; off < 256; off <<= 1) {
        int add = (t >= off) ? s[t - off] : 0;
        __syncthreads();
        s[t] += add;
        __syncthreads();
    }
    if (row < N_NODES) cursor[row] = s[t] - v;     // exclusive within block
    if (t == 255) blk[b] = s[255];                 // block total
}

// ---------------- CSR pass 2b: exclusivize the 196 block totals ----------------
__global__ void scan_b(int* __restrict__ blk) {
    __shared__ int s[256];
    int t = threadIdx.x;
    int v = (t < NSCAN) ? blk[t] : 0;
    s[t] = v;
    __syncthreads();
    #pragma unroll
    for (int off = 1; off < 256; off <<= 1) {
        int add = (t >= off) ? s[t - off] : 0;
        __syncthreads();
        s[t] += add;
        __syncthreads();
    }
    if (t < NSCAN) blk[t] = s[t] - v;              // exclusive block offset
}

// ---------------- CSR pass 3: place srow/scol/tail in sorted order ----------------
__global__ void csr_place(const int* __restrict__ edges, const short* __restrict__ tail_u,
                          int* __restrict__ cursor, const int* __restrict__ blk,
                          int* __restrict__ srow, int* __restrict__ scol,
                          short* __restrict__ tail_s) {
    int e = blockIdx.x * 256 + threadIdx.x;
    if (e >= N_EDGES) return;
    int r = edges[e], c = edges[N_EDGES + e];
    short8 s = *(const short8*)(tail_u + (size_t)e * 8);
    int pos = atomicAdd(&cursor[r], 1) + blk[r >> 8];
    srow[pos] = r; scol[pos] = c;
    *(short8*)(tail_s + (size_t)pos * 8) = s;
}

// ---------------- MFMA edge MLP: 512 threads, 8 waves x 16 channels, resident weights ----------
// 16 channels/wave -> weight frags = 13 short8 = 52 VGPR -> compiler can keep them
// RESIDENT (r0-r4: 32-ch waves needed 104 VGPR of weights -> rematerialized ~26 L2
// loads into EVERY tile's K-loop). Block = 8 waves; 2 blocks/CU = 4 waves/SIMD.
// bounds (512,2): VGPR cap 256 (r3 lesson: tighter caps force spill catastrophe).
__global__ __launch_bounds__(512, 2) void edge_mfma_kernel(
    const short* __restrict__ h_bf, const short* __restrict__ tail_s,
    const int* __restrict__ srow, const int* __restrict__ scol,
    const short* __restrict__ w1T, const float* __restrict__ b1,
    const short* __restrict__ w2T, const float* __restrict__ b2,
    float* __restrict__ agg)
{
    __shared__ __align__(16) short featA[TE * AST];   // 18944 B; msg overlays here
    __shared__ __align__(16) short t1[TE * TST];      // 8704 B
    __shared__ int srowS[TE];
    float* msgF = (float*)featA;                      // TE x MST floats = 16896 B <= featA
    int t = threadIdx.x;
    int lane = t & 63;
    int wv = t >> 6;          // wave: channel block [wv*16, wv*16+16)
    int l15 = lane & 15;
    int quad = lane >> 4;
    int el = t >> 4, j = t & 15;   // staging: 16 threads/edge, one h-side short8 pair each

    // ---- weight fragments: 9+4 short8 = 52 VGPR/lane, held resident across all tiles ----
    short8 aw1[9], aw2[4];
    #pragma unroll
    for (int ks = 0; ks < 9; ++ks)
        aw1[ks] = *(const short8*)&w1T[(size_t)(wv*16 + l15)*KP1 + ks*32 + quad*8];
    #pragma unroll
    for (int ks = 0; ks < 4; ++ks)
        aw2[ks] = *(const short8*)&w2T[(size_t)(wv*16 + l15)*128 + ks*32 + quad*8];
    float4 b1v = *(const float4*)&b1[wv*16 + quad*4];
    float4 b2v = *(const float4*)&b2[wv*16 + quad*4];
    int cb = wv*16 + quad*4;   // output channel base for this lane's C/D rows

    for (int it = 0; it < NTPB; ++it) {
        int e0 = (blockIdx.x * NTPB + it) * TE;
        __syncthreads();   // prior iteration's msg reads done before featA overwrite

        // ---- stage TE edges: thread j<8 -> h[row] parts (j, j+8); j>=8 -> h[col] ----
        {
            int e = e0 + el;
            int nidx = (j < 8) ? srow[e] : scol[e];
            if (j == 0) srowS[el] = nidx;
            int part = j & 7;
            const short8* hp = (const short8*)(h_bf + (size_t)nidx * HID) + part;
            short8 s0 = hp[0], s1 = hp[8];
            short* d = &featA[el*AST + (j < 8 ? 0 : 128) + part*8];
            *(short8*)d        = s0;
            *(short8*)(d + 64) = s1;
        }
        if (t < TE) {
            int e = e0 + t;
            short8 s = *(const short8*)(tail_s + (size_t)e * 8);
            short8 z = {0,0,0,0,0,0,0,0};
            *(short8*)&featA[t*AST + 256] = s;
            *(short8*)&featA[t*AST + 264] = z;
            *(short8*)&featA[t*AST + 272] = z;
            *(short8*)&featA[t*AST + 280] = z;
        }
        __syncthreads();

        // ---- layer 1: K = 288, 18 MFMA/wave, A resident in VGPRs ----
        floatx4 acc[2] = {{0,0,0,0},{0,0,0,0}};
        #pragma unroll
        for (int ks = 0; ks < 9; ++ks) {
            int koff = ks*32 + quad*8;
            short8 bb0 = *(const short8*)&featA[l15*AST + koff];
            short8 bb1 = *(const short8*)&featA[(16 + l15)*AST + koff];
            acc[0] = __builtin_amdgcn_mfma_f32_16x16x32_bf16(aw1[ks], bb0, acc[0], 0, 0, 0);
            acc[1] = __builtin_amdgcn_mfma_f32_16x16x32_bf16(aw1[ks], bb1, acc[1], 0, 0, 0);
        }

        // ---- epilogue 1: bias + elu -> bf16 t1[e][c] (packed cvt) ----
        #pragma unroll
        for (int ni = 0; ni < 2; ++ni) {
            short2 q0 = f2bf2(elu_f(acc[ni][0] + b1v.x), elu_f(acc[ni][1] + b1v.y));
            short2 q1 = f2bf2(elu_f(acc[ni][2] + b1v.z), elu_f(acc[ni][3] + b1v.w));
            short4v s = { q0.x, q0.y, q1.x, q1.y };
            *(short4v*)&t1[(ni*16 + l15)*TST + cb] = s;
        }
        __syncthreads();   // featA reads done (L1 K-loop) -> msg overlay safe after here

        // ---- layer 2: K = 128, 8 MFMA/wave ----
        floatx4 acc2[2] = {{0,0,0,0},{0,0,0,0}};
        #pragma unroll
        for (int ks = 0; ks < 4; ++ks) {
            int koff = ks*32 + quad*8;
            short8 bb0 = *(const short8*)&t1[l15*TST + koff];
            short8 bb1 = *(const short8*)&t1[(16 + l15)*TST + koff];
            acc2[0] = __builtin_amdgcn_mfma_f32_16x16x32_bf16(aw2[ks], bb0, acc2[0], 0, 0, 0);
            acc2[1] = __builtin_amdgcn_mfma_f32_16x16x32_bf16(aw2[ks], bb1, acc2[1], 0, 0, 0);
        }

        // ---- epilogue 2: bias + elu -> f32 msg tile (overlaid on featA) ----
        #pragma unroll
        for (int ni = 0; ni < 2; ++ni) {
            float4 v = { elu_f(acc2[ni][0] + b2v.x), elu_f(acc2[ni][1] + b2v.y),
                         elu_f(acc2[ni][2] + b2v.z), elu_f(acc2[ni][3] + b2v.w) };
            *(float4*)&msgF[(ni*16 + l15)*MST + cb] = v;
        }
        __syncthreads();

        // ---- segmented reduce: thread (ch, seg) walks 8 sorted edges, flush per run ----
        {
            int ch = t & 127, seg = t >> 7;
            int base = seg * 8;
            int prow = srowS[base];
            float run = 0.0f;
            #pragma unroll
            for (int i = 0; i < 8; ++i) {
                int rr = srowS[base + i];
                if (rr != prow) {
                    unsafeAtomicAdd(&agg[(size_t)prow * HID + ch], run);
                    run = 0.0f; prow = rr;
                }
                run += msgF[(base + i)*MST + ch];
            }
            unsafeAtomicAdd(&agg[(size_t)prow * HID + ch], run);
        }
    }
}

// ---------------- MFMA node MLP: register weights, NTN tiles/block, optional agg re-zero ----------------
__global__ __launch_bounds__(256, 3) void node_mfma_kernel(
    const short* __restrict__ h_bf, float* __restrict__ agg,
    const short* __restrict__ w1T, const float* __restrict__ b1,
    const short* __restrict__ w2T, const float* __restrict__ b2,
    short* __restrict__ hout_bf, int zero_agg)
{
    __shared__ short featN[32 * NST];   // 16896 B
    __shared__ short t1[32 * TST];      // 8704 B
    int t = threadIdx.x;
    int lane = t & 63;
    int wv = t >> 6;
    int l15 = lane & 15;
    int quad = lane >> 4;
    int nl = t >> 3, j = t & 7;

    // ---- preload this wave's weight fragments (once) ----
    short8 aw1[2][8], aw2[2][4];
    float4 b1v[2], b2v[2];
    #pragma unroll
    for (int mi = 0; mi < 2; ++mi) {
        #pragma unroll
        for (int ks = 0; ks < 8; ++ks)
            aw1[mi][ks] = *(const short8*)&w1T[(size_t)(wv*32 + mi*16 + l15)*KN + ks*32 + quad*8];
        #pragma unroll
        for (int ks = 0; ks < 4; ++ks)
            aw2[mi][ks] = *(const short8*)&w2T[(size_t)(wv*32 + mi*16 + l15)*128 + ks*32 + quad*8];
        b1v[mi] = *(const float4*)&b1[wv*32 + mi*16 + quad*4];
        b2v[mi] = *(const float4*)&b2[wv*32 + mi*16 + quad*4];
    }

    for (int it = 0; it < NTN; ++it) {
        int n0 = (blockIdx.x * NTN + it) * 32;
        if (n0 >= N_NODES) break;          // block-uniform
        __syncthreads();

        int n = n0 + nl;
        int idx = n < N_NODES ? n : N_NODES - 1;
        {
            const short8* hp = (const short8*)(h_bf + (size_t)idx * HID + j*16);
            short8 s0 = hp[0], s1 = hp[1];
            const float4* ap = (const float4*)(agg + (size_t)idx * HID) + j*4;
            float4 u0 = ap[0], u1 = ap[1], u2 = ap[2], u3 = ap[3];
            short2 p0 = f2bf2(u0.x, u0.y), p1 = f2bf2(u0.z, u0.w);
            short2 p2 = f2bf2(u1.x, u1.y), p3 = f2bf2(u1.z, u1.w);
            short2 p4 = f2bf2(u2.x, u2.y), p5 = f2bf2(u2.z, u2.w);
            short2 p6 = f2bf2(u3.x, u3.y), p7 = f2bf2(u3.z, u3.w);
            short8 s2 = { p0.x, p0.y, p1.x, p1.y, p2.x, p2.y, p3.x, p3.y };
            short8 s3 = { p4.x, p4.y, p5.x, p5.y, p6.x, p6.y, p7.x, p7.y };
            *(short8*)&featN[nl*NST + j*16]       = s0;
            *(short8*)&featN[nl*NST + j*16 + 8]   = s1;
            *(short8*)&featN[nl*NST + 128 + j*16]     = s2;
            *(short8*)&featN[nl*NST + 128 + j*16 + 8] = s3;
        }
        __syncthreads();

        // ---- re-zero consumed agg rows for the next layer (block owns these rows) ----
        if (zero_agg && n < N_NODES) {
            float4 z = {0,0,0,0};
            float4* ap = (float4*)(agg + (size_t)n * HID) + j*4;
            ap[0] = z; ap[1] = z; ap[2] = z; ap[3] = z;
        }

        floatx4 acc[2][2] = {{{0,0,0,0},{0,0,0,0}},{{0,0,0,0},{0,0,0,0}}};
        #pragma unroll
        for (int ks = 0; ks < 8; ++ks) {
            int koff = ks*32 + quad*8;
            short8 bb0 = *(const short8*)&featN[l15*NST + koff];
            short8 bb1 = *(const short8*)&featN[(16 + l15)*NST + koff];
            acc[0][0] = __builtin_amdgcn_mfma_f32_16x16x32_bf16(aw1[0][ks], bb0, acc[0][0], 0, 0, 0);
            acc[0][1] = __builtin_amdgcn_mfma_f32_16x16x32_bf16(aw1[0][ks], bb1, acc[0][1], 0, 0, 0);
            acc[1][0] = __builtin_amdgcn_mfma_f32_16x16x32_bf16(aw1[1][ks], bb0, acc[1][0], 0, 0, 0);
            acc[1][1] = __builtin_amdgcn_mfma_f32_16x16x32_bf16(aw1[1][ks], bb1, acc[1][1], 0, 0, 0);
        }

        #pragma unroll
        for (int mi = 0; mi < 2; ++mi) {
            int cb = wv*32 + mi*16 + quad*4;
            #pragma unroll
            for (int ni = 0; ni < 2; ++ni) {
                short2 p0 = f2bf2(elu_f(acc[mi][ni][0] + b1v[mi].x),
                                  elu_f(acc[mi][ni][1] + b1v[mi].y));
                short2 p1 = f2bf2(elu_f(acc[mi][ni][2] + b1v[mi].z),
                                  elu_f(acc[mi][ni][3] + b1v[mi].w));
                short4v s = { p0.x, p0.y, p1.x, p1.y };
                *(short4v*)&t1[(ni*16 + l15)*TST + cb] = s;
            }
        }
        __syncthreads();

        floatx4 acc2[2][2] = {{{0,0,0,0},{0,0,0,0}},{{0,0,0,0},{0,0,0,0}}};
        #pragma unroll
        for (int ks = 0; ks < 4; ++ks) {
            int koff = ks*32 + quad*8;
            short8 bb0 = *(const short8*)&t1[l15*TST + koff];
            short8 bb1 = *(const short8*)&t1[(16 + l15)*TST + koff];
            acc2[0][0] = __builtin_amdgcn_mfma_f32_16x16x32_bf16(aw2[0][ks], bb0, acc2[0][0], 0, 0, 0);
            acc2[0][1] = __builtin_amdgcn_mfma_f32_16x16x32_bf16(aw2[0][ks], bb1, acc2[0][1], 0, 0, 0);
            acc2[1][0] = __builtin_amdgcn_mfma_f32_16x16x32_bf16(aw2[1][ks], bb0, acc2[1][0], 0, 0, 0);
            acc2[1][1] = __builtin_amdgcn_mfma_f32_16x16x32_bf16(aw2[1][ks], bb1, acc2[1][1], 0, 0, 0);
        }

        #pragma unroll
        for (int mi = 0; mi < 2; ++mi) {
            int cb = wv*32 + mi*16 + quad*4;
            #pragma unroll
            for (int ni = 0; ni < 2; ++ni) {
                int nn = n0 + ni*16 + l15;
                if (nn < N_NODES) {
                    short2 p0 = f2bf2(acc2[mi][ni][0] + b2v[mi].x, acc2[mi][ni][1] + b2v[mi].y);
                    short2 p1 = f2bf2(acc2[mi][ni][2] + b2v[mi].z, acc2[mi][ni][3] + b2v[mi].w);
                    short4v s = { p0.x, p0.y, p1.x, p1.y };
                    *(short4v*)&hout_bf[(size_t)nn*HID + cb] = s;
                }
            }
        }
    }
}

// ---------------- output head: z = mu + 0.01*eps*exp(0.5*logvar), bf16 h (vectorized) ----------------
__global__ void out_kernel(const short* __restrict__ h_bf, const float* __restrict__ label,
                           const float* __restrict__ eps,
                           const float* __restrict__ mu_w, const float* __restrict__ mu_b,
                           const float* __restrict__ var_w, const float* __restrict__ var_b,
                           float* __restrict__ z)
{
    int t = threadIdx.x;
    int n = blockIdx.x * 4 + (t >> 6);
    int c = t & 63;
    if (n >= N_NODES) return;
    float am = mu_b[c], av = var_b[c];
    const short8* hp = (const short8*)(h_bf + (size_t)n * HID);
    #pragma unroll 4
    for (int k8 = 0; k8 < HID / 8; ++k8) {
        short8 hv = hp[k8];
        #pragma unroll
        for (int jj = 0; jj < 8; ++jj) {
            float h = bf2f(hv[jj]);
            am += h * mu_w[(k8*8 + jj)*LAT + c];
            av += h * var_w[(k8*8 + jj)*LAT + c];
        }
    }
    #pragma unroll
    for (int k = 0; k < 7; ++k) {
        float lv = label[(size_t)n*7 + k];
        am += lv * mu_w[(HID+k)*LAT + c];
        av += lv * var_w[(HID+k)*LAT + c];
    }
    float sd = expf(av * 0.5f);
    z[(size_t)n*LAT + c] = am + 0.01f * eps[(size_t)n*LAT + c] * sd;
}

extern "C" void kernel_launch(void* const* d_in, const int* in_sizes, int n_in,
                              void* d_out, int out_size, void* d_ws, size_t ws_size,
                              hipStream_t stream) {
    const float* h0        = (const float*)d_in[0];
    const float* label     = (const float*)d_in[1];
    const float* x         = (const float*)d_in[2];
    const float* edge_attr = (const float*)d_in[3];
    const float* eps       = (const float*)d_in[4];
    const float* emb_w     = (const float*)d_in[5];
    const float* emb_b     = (const float*)d_in[6];
    const float* edge_w1   = (const float*)d_in[7];
    const float* edge_b1   = (const float*)d_in[8];
    const float* edge_w2   = (const float*)d_in[9];
    const float* edge_b2   = (const float*)d_in[10];
    const float* node_w1   = (const float*)d_in[11];
    const float* node_b1   = (const float*)d_in[12];
    const float* node_w2   = (const float*)d_in[13];
    const float* node_b2   = (const float*)d_in[14];
    const float* mu_w      = (const float*)d_in[15];
    const float* mu_b      = (const float*)d_in[16];
    const float* var_w     = (const float*)d_in[17];
    const float* var_b     = (const float*)d_in[18];
    const int*   edges     = (const int*)d_in[19];
    float* out = (float*)d_out;

    float* agg      = (float*)d_ws;                     // N*128 f32
    short* h_bf     = (short*)(agg + (size_t)N_NODES * HID);  // N*128 bf16
    short* tail_u   = h_bf + (size_t)N_NODES * HID;     // E*8 bf16 (unsorted)
    short* tail_s   = tail_u + (size_t)N_EDGES * 8;     // E*8 bf16 (sorted)
    int*   cnt      = (int*)(tail_s + (size_t)N_EDGES * 8);   // N int
    int*   cursor   = cnt + N_NODES;                    // N int
    int*   blk      = cursor + N_NODES;                 // 256 int
    int*   srow     = blk + 256;                        // E int
    int*   scol     = srow + N_EDGES;                   // E int
    short* ew1T     = (short*)(scol + N_EDGES);         // 2*128*288
    short* ew2T     = ew1T + 2*128*KP1;                 // 2*128*128
    short* nw1T     = ew2T + 2*128*128;                 // 2*128*256
    short* nw2T     = nw1T + 2*128*KN;                  // 2*128*128

    hipMemsetAsync(cnt, 0, N_NODES * sizeof(int), stream);
    prep_all<<<EB + EMB_B + WPB + ZB, 256, 0, stream>>>(
        edges, x, edge_attr, h0, emb_w, emb_b,
        edge_w1, edge_w2, node_w1, node_w2,
        cnt, tail_u, h_bf, ew1T, ew2T, nw1T, nw2T, agg);
    scan_a<<<NSCAN, 256, 0, stream>>>(cnt, cursor, blk);
    scan_b<<<1, 256, 0, stream>>>(blk);
    csr_place<<<(N_EDGES + 255) / 256, 256, 0, stream>>>(edges, tail_u, cursor, blk,
                                                         srow, scol, tail_s);

    for (int l = 0; l < 2; ++l) {
        edge_mfma_kernel<<<N_EDGES / TE / NTPB, 512, 0, stream>>>(
            h_bf, tail_s, srow, scol,
            ew1T + (size_t)l * 128 * KP1, edge_b1 + l * HID,
            ew2T + (size_t)l * 128 * 128, edge_b2 + l * HID, agg);
        node_mfma_kernel<<<(N_NODES/32 + NTN) / NTN, 256, 0, stream>>>(
            h_bf, agg,
            nw1T + (size_t)l * 128 * KN, node_b1 + l * HID,
            nw2T + (size_t)l * 128 * 128, node_b2 + l * HID, h_bf,
            (l == 0) ? 1 : 0);
    }

    out_kernel<<<N_NODES / 4, 256, 0, stream>>>(h_bf, label, eps, mu_w, mu_b,
                                                var_w, var_b, out);
}

// Round 6
// 737.200 us; speedup vs baseline: 1.3063x; 1.0396x over previous
//
#include <hip/hip_runtime.h>
#include <hip/hip_bf16.h>
#include <math.h>

#define N_NODES 50000
#define N_EDGES 800000
#define HID 128
#define LAT 64
#define IN_NODE 11
#define K_EDGE 261    // 2*HID + 1 + 4
#define KP1 288       // K_EDGE padded to multiple of 32
#define KN 256        // node MLP folded K (h + agg)
#define AST 296       // edge feature LDS row stride (bf16 elems), 288+8 pad
#define NST 264       // node feature LDS row stride, 256+8 pad
#define TST 136       // t1 LDS row stride, 128+8 pad
#define MST 132       // msg LDS row stride (floats), 128+4 pad
#define TE 32         // edges per tile (r4: 64 hurt; r5: 16-ch waves hurt — keep r0 shape)
#define NTPB 20       // edge tiles per block (grid 1250)
#define NTN 2         // node tiles per block (grid 782 ~ 3/CU)
#define NSCAN 196     // scan blocks: 196*256 = 50176 >= N_NODES
// prep_all block partition
#define EB 3125       // edge count+tail blocks
#define EMB_B 25000   // embedding blocks (2 nodes each)
#define WPB 32        // weight prep blocks
#define ZB 100        // agg zero blocks

typedef __attribute__((ext_vector_type(8))) short short8;
typedef __attribute__((ext_vector_type(4))) short short4v;
typedef __attribute__((ext_vector_type(4))) float floatx4;

__device__ __forceinline__ float elu_f(float v) { return v > 0.0f ? v : __expf(v) - 1.0f; }

__device__ __forceinline__ short f2bf(float f) {
    unsigned int u = __builtin_bit_cast(unsigned int, f);
    u += 0x7fffu + ((u >> 16) & 1u);   // round-to-nearest-even
    return (short)(u >> 16);
}

__device__ __forceinline__ short2 f2bf2(float a, float b) {
    float2 p; p.x = a; p.y = b;
    __hip_bfloat162 h = __float22bfloat162_rn(p);   // v_cvt_pk_bf16_f32
    short2 r;
    __builtin_memcpy(&r, &h, sizeof(r));
    return r;
}

__device__ __forceinline__ float bf2f(short s) {
    unsigned int u = ((unsigned int)(unsigned short)s) << 16;
    return __builtin_bit_cast(float, u);
}

// ---------------- fused prep: edge count+tail | emb | weight prep | agg zero ----------------
__global__ void prep_all(const int* __restrict__ edges, const float* __restrict__ x,
                         const float* __restrict__ edge_attr, const float* __restrict__ h0,
                         const float* __restrict__ emb_w, const float* __restrict__ emb_b,
                         const float* __restrict__ ew1, const float* __restrict__ ew2,
                         const float* __restrict__ nw1, const float* __restrict__ nw2,
                         int* __restrict__ cnt, short* __restrict__ tail_u,
                         short* __restrict__ h_bf,
                         short* __restrict__ ew1T, short* __restrict__ ew2T,
                         short* __restrict__ nw1T, short* __restrict__ nw2T,
                         float* __restrict__ agg) {
    int b = blockIdx.x, t = threadIdx.x;
    if (b < EB) {
        // ---- edge: count + radial + bf16 tail pack ----
        int e = b * 256 + t;
        if (e >= N_EDGES) return;
        int r = edges[e], c = edges[N_EDGES + e];
        atomicAdd(&cnt[r], 1);
        float dx = x[r*3+0] - x[c*3+0];
        float dy = x[r*3+1] - x[c*3+1];
        float dz = x[r*3+2] - x[c*3+2];
        float radial = dx*dx + dy*dy + dz*dz;
        float4 ea = *(const float4*)(edge_attr + (size_t)e * 4);
        short8 s = { f2bf(radial), f2bf(ea.x), f2bf(ea.y), f2bf(ea.z), f2bf(ea.w), 0, 0, 0 };
        *(short8*)(tail_u + (size_t)e * 8) = s;
    } else if (b < EB + EMB_B) {
        // ---- embedding: h_bf = bf16(h0 @ emb_w + emb_b) ----
        int bb = b - EB;
        int n = bb * 2 + (t >> 7);
        int c = t & 127;
        if (n >= N_NODES) return;
        float acc = emb_b[c];
        #pragma unroll
        for (int k = 0; k < IN_NODE; ++k) acc += h0[n*IN_NODE + k] * emb_w[k*HID + c];
        h_bf[(size_t)n*HID + c] = f2bf(acc);
    } else if (b < EB + EMB_B + WPB) {
        // ---- weight prep: transpose + bf16 + pad/fold ----
        int idx = (b - EB - EMB_B) * 256 + t;
        int stride = WPB * 256;
        for (int i = idx; i < 2*128*KP1; i += stride) {
            int l = i / (128*KP1); int r = i % (128*KP1);
            int c = r / KP1; int k = r % KP1;
            float v = (k < K_EDGE) ? ew1[(size_t)l*K_EDGE*128 + (size_t)k*128 + c] : 0.0f;
            ew1T[i] = f2bf(v);
        }
        for (int i = idx; i < 2*128*128; i += stride) {
            int l = i / (128*128); int r = i % (128*128);
            int c = r / 128; int k = r % 128;
            ew2T[i] = f2bf(ew2[(size_t)l*128*128 + (size_t)k*128 + c]);
        }
        for (int i = idx; i < 2*128*KN; i += stride) {
            int l = i / (128*KN); int r = i % (128*KN);
            int c = r / KN; int k = r % KN;
            const float* base = nw1 + (size_t)l*384*128;
            float v = (k < 128) ? (base[(size_t)k*128 + c] + base[(size_t)(256+k)*128 + c])
                                : base[(size_t)k*128 + c];
            nw1T[i] = f2bf(v);
        }
        for (int i = idx; i < 2*128*128; i += stride) {
            int l = i / (128*128); int r = i % (128*128);
            int c = r / 128; int k = r % 128;
            nw2T[i] = f2bf(nw2[(size_t)l*128*128 + (size_t)k*128 + c]);
        }
    } else {
        // ---- agg zero ----
        int idx = (b - EB - EMB_B - WPB) * 256 + t;
        int stride = ZB * 256;
        float4 z = {0,0,0,0};
        float4* a4 = (float4*)agg;
        for (int i = idx; i < N_NODES*HID/4; i += stride) a4[i] = z;
    }
}

// ---------------- CSR pass 2a: per-block exclusive scan (256 rows/block) ----------------
__global__ void scan_a(const int* __restrict__ cnt, int* __restrict__ cursor,
                       int* __restrict__ blk) {
    __shared__ int s[256];
    int b = blockIdx.x, t = threadIdx.x;
    int row = b * 256 + t;
    int v = (row < N_NODES) ? cnt[row] : 0;
    s[t] = v;
    __syncthreads();
    #pragma unroll
    for (int off = 1; off < 256; off <<= 1) {
        int add = (t >= off) ? s[t - off] : 0;
        __syncthreads();
        s[t] += add;
        __syncthreads();
    }
    if (row < N_NODES) cursor[row] = s[t] - v;     // exclusive within block
    if (t == 255) blk[b] = s[255];                 // block total
}

// ---------------- CSR pass 2b: exclusivize the 196 block totals ----------------
__global__ void scan_b(int* __restrict__ blk) {
    __shared__ int s[256];
    int t = threadIdx.x;
    int v = (t < NSCAN) ? blk[t] : 0;
    s[t] = v;
    __syncthreads();
    #pragma unroll
    for (int off = 1; off < 256; off <<= 1) {
        int add = (t >= off) ? s[t - off] : 0;
        __syncthreads();
        s[t] += add;
        __syncthreads();
    }
    if (t < NSCAN) blk[t] = s[t] - v;              // exclusive block offset
}

// ---------------- CSR pass 3: place srow/scol/tail in sorted order ----------------
__global__ void csr_place(const int* __restrict__ edges, const short* __restrict__ tail_u,
                          int* __restrict__ cursor, const int* __restrict__ blk,
                          int* __restrict__ srow, int* __restrict__ scol,
                          short* __restrict__ tail_s) {
    int e = blockIdx.x * 256 + threadIdx.x;
    if (e >= N_EDGES) return;
    int r = edges[e], c = edges[N_EDGES + e];
    short8 s = *(const short8*)(tail_u + (size_t)e * 8);
    int pos = atomicAdd(&cursor[r], 1) + blk[r >> 8];
    srow[pos] = r; scol[pos] = c;
    *(short8*)(tail_s + (size_t)pos * 8) = s;
}

// ---------------- MFMA edge MLP: r0 structure + asm-PINNED resident weights ----------------
// r0-r5 evidence: compiler REMATERIALIZES weight fragments from L2 inside every tile
// (VGPR 60-100 measured vs 160+ if resident) -> every K-step gated by ~200cy L2 latency.
// Fix: empty inline-asm def per fragment = opaque value, cannot be recomputed -> must
// stay in VGPRs across the tile loop. Peak ~180-200 VGPR < 256 cap of (256,2); >=129
// VGPR still gives 8 waves/CU = measured residency, so occupancy unchanged by design.
__global__ __launch_bounds__(256, 2) void edge_mfma_kernel(
    const short* __restrict__ h_bf, const short* __restrict__ tail_s,
    const int* __restrict__ srow, const int* __restrict__ scol,
    const short* __restrict__ w1T, const float* __restrict__ b1,
    const short* __restrict__ w2T, const float* __restrict__ b2,
    float* __restrict__ agg)
{
    __shared__ __align__(16) short featA[TE * AST];   // 18944 B; msg overlays here
    __shared__ __align__(16) short t1[TE * TST];      // 8704 B
    __shared__ int srowS[TE];
    float* msgF = (float*)featA;                      // TE x MST floats = 16896 B <= featA
    int t = threadIdx.x;
    int lane = t & 63;
    int wv = t >> 6;          // wave: channel block [wv*32, wv*32+32)
    int l15 = lane & 15;
    int quad = lane >> 4;
    int el = t >> 3, j = t & 7;

    // ---- weight fragments: loaded once, PINNED resident via opaque asm defs ----
    short8 aw1[2][9], aw2[2][4];
    floatx4 b1v[2], b2v[2];
    #pragma unroll
    for (int mi = 0; mi < 2; ++mi) {
        #pragma unroll
        for (int ks = 0; ks < 9; ++ks) {
            aw1[mi][ks] = *(const short8*)&w1T[(size_t)(wv*32 + mi*16 + l15)*KP1 + ks*32 + quad*8];
            asm volatile("" : "+v"(aw1[mi][ks]));
        }
        #pragma unroll
        for (int ks = 0; ks < 4; ++ks) {
            aw2[mi][ks] = *(const short8*)&w2T[(size_t)(wv*32 + mi*16 + l15)*128 + ks*32 + quad*8];
            asm volatile("" : "+v"(aw2[mi][ks]));
        }
        b1v[mi] = *(const floatx4*)&b1[wv*32 + mi*16 + quad*4];
        asm volatile("" : "+v"(b1v[mi]));
        b2v[mi] = *(const floatx4*)&b2[wv*32 + mi*16 + quad*4];
        asm volatile("" : "+v"(b2v[mi]));
    }

    for (int it = 0; it < NTPB; ++it) {
        int e0 = (blockIdx.x * NTPB + it) * TE;
        __syncthreads();   // prior iteration's msg reads done before featA overwrite

        // ---- stage TE edges' gathered bf16 features ----
        {
            int e = e0 + el;
            int r = srow[e], c = scol[e];
            if (j == 0) srowS[el] = r;
            const short8* hr = (const short8*)(h_bf + (size_t)r * HID + j*16);
            const short8* hc = (const short8*)(h_bf + (size_t)c * HID + j*16);
            short8 s0 = hr[0], s1 = hr[1];
            short8 s2 = hc[0], s3 = hc[1];
            *(short8*)&featA[el*AST + j*16]       = s0;
            *(short8*)&featA[el*AST + j*16 + 8]   = s1;
            *(short8*)&featA[el*AST + 128 + j*16]     = s2;
            *(short8*)&featA[el*AST + 128 + j*16 + 8] = s3;
        }
        if (t < TE) {
            int e = e0 + t;
            short8 s = *(const short8*)(tail_s + (size_t)e * 8);
            short8 z = {0,0,0,0,0,0,0,0};
            *(short8*)&featA[t*AST + 256] = s;
            *(short8*)&featA[t*AST + 264] = z;
            *(short8*)&featA[t*AST + 272] = z;
            *(short8*)&featA[t*AST + 280] = z;
        }
        __syncthreads();

        // ---- layer 1: K = 288, weights in VGPRs ----
        floatx4 acc[2][2] = {{{0,0,0,0},{0,0,0,0}},{{0,0,0,0},{0,0,0,0}}};
        #pragma unroll
        for (int ks = 0; ks < 9; ++ks) {
            int koff = ks*32 + quad*8;
            short8 bb0 = *(const short8*)&featA[l15*AST + koff];
            short8 bb1 = *(const short8*)&featA[(16 + l15)*AST + koff];
            acc[0][0] = __builtin_amdgcn_mfma_f32_16x16x32_bf16(aw1[0][ks], bb0, acc[0][0], 0, 0, 0);
            acc[0][1] = __builtin_amdgcn_mfma_f32_16x16x32_bf16(aw1[0][ks], bb1, acc[0][1], 0, 0, 0);
            acc[1][0] = __builtin_amdgcn_mfma_f32_16x16x32_bf16(aw1[1][ks], bb0, acc[1][0], 0, 0, 0);
            acc[1][1] = __builtin_amdgcn_mfma_f32_16x16x32_bf16(aw1[1][ks], bb1, acc[1][1], 0, 0, 0);
        }

        // ---- epilogue 1: bias + elu -> bf16 t1[e][c] (packed cvt) ----
        #pragma unroll
        for (int mi = 0; mi < 2; ++mi) {
            int cb = wv*32 + mi*16 + quad*4;
            #pragma unroll
            for (int ni = 0; ni < 2; ++ni) {
                short2 q0 = f2bf2(elu_f(acc[mi][ni][0] + b1v[mi][0]),
                                  elu_f(acc[mi][ni][1] + b1v[mi][1]));
                short2 q1 = f2bf2(elu_f(acc[mi][ni][2] + b1v[mi][2]),
                                  elu_f(acc[mi][ni][3] + b1v[mi][3]));
                short4v s = { q0.x, q0.y, q1.x, q1.y };
                *(short4v*)&t1[(ni*16 + l15)*TST + cb] = s;
            }
        }
        __syncthreads();   // featA reads done (L1 K-loop) -> msg overlay safe after here

        // ---- layer 2: K = 128, weights in VGPRs ----
        floatx4 acc2[2][2] = {{{0,0,0,0},{0,0,0,0}},{{0,0,0,0},{0,0,0,0}}};
        #pragma unroll
        for (int ks = 0; ks < 4; ++ks) {
            int koff = ks*32 + quad*8;
            short8 bb0 = *(const short8*)&t1[l15*TST + koff];
            short8 bb1 = *(const short8*)&t1[(16 + l15)*TST + koff];
            acc2[0][0] = __builtin_amdgcn_mfma_f32_16x16x32_bf16(aw2[0][ks], bb0, acc2[0][0], 0, 0, 0);
            acc2[0][1] = __builtin_amdgcn_mfma_f32_16x16x32_bf16(aw2[0][ks], bb1, acc2[0][1], 0, 0, 0);
            acc2[1][0] = __builtin_amdgcn_mfma_f32_16x16x32_bf16(aw2[1][ks], bb0, acc2[1][0], 0, 0, 0);
            acc2[1][1] = __builtin_amdgcn_mfma_f32_16x16x32_bf16(aw2[1][ks], bb1, acc2[1][1], 0, 0, 0);
        }

        // ---- epilogue 2: bias + elu -> f32 msg tile (overlaid on featA) ----
        #pragma unroll
        for (int mi = 0; mi < 2; ++mi) {
            int cb = wv*32 + mi*16 + quad*4;
            #pragma unroll
            for (int ni = 0; ni < 2; ++ni) {
                float4 v = { elu_f(acc2[mi][ni][0] + b2v[mi][0]), elu_f(acc2[mi][ni][1] + b2v[mi][1]),
                             elu_f(acc2[mi][ni][2] + b2v[mi][2]), elu_f(acc2[mi][ni][3] + b2v[mi][3]) };
                *(float4*)&msgF[(ni*16 + l15)*MST + cb] = v;
            }
        }
        __syncthreads();

        // ---- segmented reduce: thread (ch, half) walks 16 sorted edges, flush per run ----
        {
            int ch = t & 127, half = t >> 7;
            int base = half * 16;
            int prow = srowS[base];
            float run = 0.0f;
            #pragma unroll
            for (int i = 0; i < 16; ++i) {
                int rr = srowS[base + i];
                if (rr != prow) {
                    unsafeAtomicAdd(&agg[(size_t)prow * HID + ch], run);
                    run = 0.0f; prow = rr;
                }
                run += msgF[(base + i)*MST + ch];
            }
            unsafeAtomicAdd(&agg[(size_t)prow * HID + ch], run);
        }
    }
}

// ---------------- MFMA node MLP: register weights, NTN tiles/block, optional agg re-zero ----------------
__global__ __launch_bounds__(256, 3) void node_mfma_kernel(
    const short* __restrict__ h_bf, float* __restrict__ agg,
    const short* __restrict__ w1T, const float* __restrict__ b1,
    const short* __restrict__ w2T, const float* __restrict__ b2,
    short* __restrict__ hout_bf, int zero_agg)
{
    __shared__ short featN[32 * NST];   // 16896 B
    __shared__ short t1[32 * TST];      // 8704 B
    int t = threadIdx.x;
    int lane = t & 63;
    int wv = t >> 6;
    int l15 = lane & 15;
    int quad = lane >> 4;
    int nl = t >> 3, j = t & 7;

    // ---- preload this wave's weight fragments (once) ----
    short8 aw1[2][8], aw2[2][4];
    float4 b1v[2], b2v[2];
    #pragma unroll
    for (int mi = 0; mi < 2; ++mi) {
        #pragma unroll
        for (int ks = 0; ks < 8; ++ks)
            aw1[mi][ks] = *(const short8*)&w1T[(size_t)(wv*32 + mi*16 + l15)*KN + ks*32 + quad*8];
        #pragma unroll
        for (int ks = 0; ks < 4; ++ks)
            aw2[mi][ks] = *(const short8*)&w2T[(size_t)(wv*32 + mi*16 + l15)*128 + ks*32 + quad*8];
        b1v[mi] = *(const float4*)&b1[wv*32 + mi*16 + quad*4];
        b2v[mi] = *(const float4*)&b2[wv*32 + mi*16 + quad*4];
    }

    for (int it = 0; it < NTN; ++it) {
        int n0 = (blockIdx.x * NTN + it) * 32;
        if (n0 >= N_NODES) break;          // block-uniform
        __syncthreads();

        int n = n0 + nl;
        int idx = n < N_NODES ? n : N_NODES - 1;
        {
            const short8* hp = (const short8*)(h_bf + (size_t)idx * HID + j*16);
            short8 s0 = hp[0], s1 = hp[1];
            const float4* ap = (const float4*)(agg + (size_t)idx * HID) + j*4;
            float4 u0 = ap[0], u1 = ap[1], u2 = ap[2], u3 = ap[3];
            short2 p0 = f2bf2(u0.x, u0.y), p1 = f2bf2(u0.z, u0.w);
            short2 p2 = f2bf2(u1.x, u1.y), p3 = f2bf2(u1.z, u1.w);
            short2 p4 = f2bf2(u2.x, u2.y), p5 = f2bf2(u2.z, u2.w);
            short2 p6 = f2bf2(u3.x, u3.y), p7 = f2bf2(u3.z, u3.w);
            short8 s2 = { p0.x, p0.y, p1.x, p1.y, p2.x, p2.y, p3.x, p3.y };
            short8 s3 = { p4.x, p4.y, p5.x, p5.y, p6.x, p6.y, p7.x, p7.y };
            *(short8*)&featN[nl*NST + j*16]       = s0;
            *(short8*)&featN[nl*NST + j*16 + 8]   = s1;
            *(short8*)&featN[nl*NST + 128 + j*16]     = s2;
            *(short8*)&featN[nl*NST + 128 + j*16 + 8] = s3;
        }
        __syncthreads();

        // ---- re-zero consumed agg rows for the next layer (block owns these rows) ----
        if (zero_agg && n < N_NODES) {
            float4 z = {0,0,0,0};
            float4* ap = (float4*)(agg + (size_t)n * HID) + j*4;
            ap[0] = z; ap[1] = z; ap[2] = z; ap[3] = z;
        }

        floatx4 acc[2][2] = {{{0,0,0,0},{0,0,0,0}},{{0,0,0,0},{0,0,0,0}}};
        #pragma unroll
        for (int ks = 0; ks < 8; ++ks) {
            int koff = ks*32 + quad*8;
            short8 bb0 = *(const short8*)&featN[l15*NST + koff];
            short8 bb1 = *(const short8*)&featN[(16 + l15)*NST + koff];
            acc[0][0] = __builtin_amdgcn_mfma_f32_16x16x32_bf16(aw1[0][ks], bb0, acc[0][0], 0, 0, 0);
            acc[0][1] = __builtin_amdgcn_mfma_f32_16x16x32_bf16(aw1[0][ks], bb1, acc[0][1], 0, 0, 0);
            acc[1][0] = __builtin_amdgcn_mfma_f32_16x16x32_bf16(aw1[1][ks], bb0, acc[1][0], 0, 0, 0);
            acc[1][1] = __builtin_amdgcn_mfma_f32_16x16x32_bf16(aw1[1][ks], bb1, acc[1][1], 0, 0, 0);
        }

        #pragma unroll
        for (int mi = 0; mi < 2; ++mi) {
            int cb = wv*32 + mi*16 + quad*4;
            #pragma unroll
            for (int ni = 0; ni < 2; ++ni) {
                short2 p0 = f2bf2(elu_f(acc[mi][ni][0] + b1v[mi].x),
                                  elu_f(acc[mi][ni][1] + b1v[mi].y));
                short2 p1 = f2bf2(elu_f(acc[mi][ni][2] + b1v[mi].z),
                                  elu_f(acc[mi][ni][3] + b1v[mi].w));
                short4v s = { p0.x, p0.y, p1.x, p1.y };
                *(short4v*)&t1[(ni*16 + l15)*TST + cb] = s;
            }
        }
        __syncthreads();

        floatx4 acc2[2][2] = {{{0,0,0,0},{0,0,0,0}},{{0,0,0,0},{0,0,0,0}}};
        #pragma unroll
        for (int ks = 0; ks < 4; ++ks) {
            int koff = ks*32 + quad*8;
            short8 bb0 = *(const short8*)&t1[l15*TST + koff];
            short8 bb1 = *(const short8*)&t1[(16 + l15)*TST + koff];
            acc2[0][0] = __builtin_amdgcn_mfma_f32_16x16x32_bf16(aw2[0][ks], bb0, acc2[0][0], 0, 0, 0);
            acc2[0][1] = __builtin_amdgcn_mfma_f32_16x16x32_bf16(aw2[0][ks], bb1, acc2[0][1], 0, 0, 0);
            acc2[1][0] = __builtin_amdgcn_mfma_f32_16x16x32_bf16(aw2[1][ks], bb0, acc2[1][0], 0, 0, 0);
            acc2[1][1] = __builtin_amdgcn_mfma_f32_16x16x32_bf16(aw2[1][ks], bb1, acc2[1][1], 0, 0, 0);
        }

        #pragma unroll
        for (int mi = 0; mi < 2; ++mi) {
            int cb = wv*32 + mi*16 + quad*4;
            #pragma unroll
            for (int ni = 0; ni < 2; ++ni) {
                int nn = n0 + ni*16 + l15;
                if (nn < N_NODES) {
                    short2 p0 = f2bf2(acc2[mi][ni][0] + b2v[mi].x, acc2[mi][ni][1] + b2v[mi].y);
                    short2 p1 = f2bf2(acc2[mi][ni][2] + b2v[mi].z, acc2[mi][ni][3] + b2v[mi].w);
                    short4v s = { p0.x, p0.y, p1.x, p1.y };
                    *(short4v*)&hout_bf[(size_t)nn*HID + cb] = s;
                }
            }
        }
    }
}

// ---------------- output head: z = mu + 0.01*eps*exp(0.5*logvar), bf16 h (vectorized) ----------------
__global__ void out_kernel(const short* __restrict__ h_bf, const float* __restrict__ label,
                           const float* __restrict__ eps,
                           const float* __restrict__ mu_w, const float* __restrict__ mu_b,
                           const float* __restrict__ var_w, const float* __restrict__ var_b,
                           float* __restrict__ z)
{
    int t = threadIdx.x;
    int n = blockIdx.x * 4 + (t >> 6);
    int c = t & 63;
    if (n >= N_NODES) return;
    float am = mu_b[c], av = var_b[c];
    const short8* hp = (const short8*)(h_bf + (size_t)n * HID);
    #pragma unroll 4
    for (int k8 = 0; k8 < HID / 8; ++k8) {
        short8 hv = hp[k8];
        #pragma unroll
        for (int jj = 0; jj < 8; ++jj) {
            float h = bf2f(hv[jj]);
            am += h * mu_w[(k8*8 + jj)*LAT + c];
            av += h * var_w[(k8*8 + jj)*LAT + c];
        }
    }
    #pragma unroll
    for (int k = 0; k < 7; ++k) {
        float lv = label[(size_t)n*7 + k];
        am += lv * mu_w[(HID+k)*LAT + c];
        av += lv * var_w[(HID+k)*LAT + c];
    }
    float sd = expf(av * 0.5f);
    z[(size_t)n*LAT + c] = am + 0.01f * eps[(size_t)n*LAT + c] * sd;
}

extern "C" void kernel_launch(void* const* d_in, const int* in_sizes, int n_in,
                              void* d_out, int out_size, void* d_ws, size_t ws_size,
                              hipStream_t stream) {
    const float* h0        = (const float*)d_in[0];
    const float* label     = (const float*)d_in[1];
    const float* x         = (const float*)d_in[2];
    const float* edge_attr = (const float*)d_in[3];
    const float* eps       = (const float*)d_in[4];
    const float* emb_w     = (const float*)d_in[5];
    const float* emb_b     = (const float*)d_in[6];
    const float* edge_w1   = (const float*)d_in[7];
    const float* edge_b1   = (const float*)d_in[8];
    const float* edge_w2   = (const float*)d_in[9];
    const float* edge_b2   = (const float*)d_in[10];
    const float* node_w1   = (const float*)d_in[11];
    const float* node_b1   = (const float*)d_in[12];
    const float* node_w2   = (const float*)d_in[13];
    const float* node_b2   = (const float*)d_in[14];
    const float* mu_w      = (const float*)d_in[15];
    const float* mu_b      = (const float*)d_in[16];
    const float* var_w     = (const float*)d_in[17];
    const float* var_b     = (const float*)d_in[18];
    const int*   edges     = (const int*)d_in[19];
    float* out = (float*)d_out;

    float* agg      = (float*)d_ws;                     // N*128 f32
    short* h_bf     = (short*)(agg + (size_t)N_NODES * HID);  // N*128 bf16
    short* tail_u   = h_bf + (size_t)N_NODES * HID;     // E*8 bf16 (unsorted)
    short* tail_s   = tail_u + (size_t)N_EDGES * 8;     // E*8 bf16 (sorted)
    int*   cnt      = (int*)(tail_s + (size_t)N_EDGES * 8);   // N int
    int*   cursor   = cnt + N_NODES;                    // N int
    int*   blk      = cursor + N_NODES;                 // 256 int
    int*   srow     = blk + 256;                        // E int
    int*   scol     = srow + N_EDGES;                   // E int
    short* ew1T     = (short*)(scol + N_EDGES);         // 2*128*288
    short* ew2T     = ew1T + 2*128*KP1;                 // 2*128*128
    short* nw1T     = ew2T + 2*128*128;                 // 2*128*256
    short* nw2T     = nw1T + 2*128*KN;                  // 2*128*128

    hipMemsetAsync(cnt, 0, N_NODES * sizeof(int), stream);
    prep_all<<<EB + EMB_B + WPB + ZB, 256, 0, stream>>>(
        edges, x, edge_attr, h0, emb_w, emb_b,
        edge_w1, edge_w2, node_w1, node_w2,
        cnt, tail_u, h_bf, ew1T, ew2T, nw1T, nw2T, agg);
    scan_a<<<NSCAN, 256, 0, stream>>>(cnt, cursor, blk);
    scan_b<<<1, 256, 0, stream>>>(blk);
    csr_place<<<(N_EDGES + 255) / 256, 256, 0, stream>>>(edges, tail_u, cursor, blk,
                                                         srow, scol, tail_s);

    for (int l = 0; l < 2; ++l) {
        edge_mfma_kernel<<<N_EDGES / TE / NTPB, 256, 0, stream>>>(
            h_bf, tail_s, srow, scol,
            ew1T + (size_t)l * 128 * KP1, edge_b1 + l * HID,
            ew2T + (size_t)l * 128 * 128, edge_b2 + l * HID, agg);
        node_mfma_kernel<<<(N_NODES/32 + NTN) / NTN, 256, 0, stream>>>(
            h_bf, agg,
            nw1T + (size_t)l * 128 * KN, node_b1 + l * HID,
            nw2T + (size_t)l * 128 * 128, node_b2 + l * HID, h_bf,
            (l == 0) ? 1 : 0);
    }

    out_kernel<<<N_NODES / 4, 256, 0, stream>>>(h_bf, label, eps, mu_w, mu_b,
                                                var_w, var_b, out);
}

// Round 7
// 612.678 us; speedup vs baseline: 1.5718x; 1.2032x over previous
//
#include <hip/hip_runtime.h>
#include <hip/hip_bf16.h>
#include <math.h>

#define N_NODES 50000
#define N_EDGES 800000
#define HID 128
#define LAT 64
#define IN_NODE 11
#define K_EDGE 261    // 2*HID + 1 + 4
#define KP1 288       // K_EDGE padded to multiple of 32
#define KN 256        // node MLP folded K (h + agg)
#define KO 160        // fused out head K: 128 h + 7 label + 1 bias + 24 pad
#define AST 296       // edge feature LDS row stride (bf16 elems), 288+8 pad
#define NST 264       // node feature LDS row stride, 256+8 pad
#define TST 136       // t1 LDS row stride, 128+8 pad
#define MST 132       // msg LDS row stride (floats), 128+4 pad
#define HLST 168      // fused-out hl row stride (160+8 pad)
#define OST 132       // fused-out result row stride (floats)
#define TE 32         // edges per tile (r4: 64 hurt)
#define NTPB 20       // edge tiles per block (grid 1250)
#define NTN 2         // node tiles per block (grid 782)
#define NSCAN 196     // scan blocks: 196*256 = 50176 >= N_NODES
// prep_all block partition
#define EB 3125       // edge count blocks
#define EMB_B 25000   // embedding blocks (2 nodes each)
#define WPB 32        // weight prep blocks
#define ZB 100        // agg zero blocks

typedef __attribute__((ext_vector_type(8))) short short8;
typedef __attribute__((ext_vector_type(4))) short short4v;
typedef __attribute__((ext_vector_type(4))) float floatx4;

__device__ __forceinline__ float elu_f(float v) { return v > 0.0f ? v : __expf(v) - 1.0f; }

__device__ __forceinline__ short f2bf(float f) {
    unsigned int u = __builtin_bit_cast(unsigned int, f);
    u += 0x7fffu + ((u >> 16) & 1u);   // round-to-nearest-even
    return (short)(u >> 16);
}

__device__ __forceinline__ short2 f2bf2(float a, float b) {
    float2 p; p.x = a; p.y = b;
    __hip_bfloat162 h = __float22bfloat162_rn(p);   // v_cvt_pk_bf16_f32
    short2 r;
    __builtin_memcpy(&r, &h, sizeof(r));
    return r;
}

__device__ __forceinline__ float bf2f(short s) {
    unsigned int u = ((unsigned int)(unsigned short)s) << 16;
    return __builtin_bit_cast(float, u);
}

// ---------------- fused prep: edge count | emb | weight prep (+out head) | agg zero ----------------
__global__ void prep_all(const int* __restrict__ edges, const float* __restrict__ h0,
                         const float* __restrict__ emb_w, const float* __restrict__ emb_b,
                         const float* __restrict__ ew1, const float* __restrict__ ew2,
                         const float* __restrict__ nw1, const float* __restrict__ nw2,
                         const float* __restrict__ mu_w, const float* __restrict__ mu_b,
                         const float* __restrict__ var_w, const float* __restrict__ var_b,
                         int* __restrict__ cnt,
                         short* __restrict__ h_bf,
                         short* __restrict__ ew1T, short* __restrict__ ew2T,
                         short* __restrict__ nw1T, short* __restrict__ nw2T,
                         short* __restrict__ owT,
                         float* __restrict__ agg) {
    int b = blockIdx.x, t = threadIdx.x;
    if (b < EB) {
        // ---- edge: pure degree count ----
        int e = b * 256 + t;
        if (e >= N_EDGES) return;
        atomicAdd(&cnt[edges[e]], 1);
    } else if (b < EB + EMB_B) {
        // ---- embedding: h_bf = bf16(h0 @ emb_w + emb_b) ----
        int bb = b - EB;
        int n = bb * 2 + (t >> 7);
        int c = t & 127;
        if (n >= N_NODES) return;
        float acc = emb_b[c];
        #pragma unroll
        for (int k = 0; k < IN_NODE; ++k) acc += h0[n*IN_NODE + k] * emb_w[k*HID + c];
        h_bf[(size_t)n*HID + c] = f2bf(acc);
    } else if (b < EB + EMB_B + WPB) {
        // ---- weight prep: transpose + bf16 + pad/fold ----
        int idx = (b - EB - EMB_B) * 256 + t;
        int stride = WPB * 256;
        for (int i = idx; i < 2*128*KP1; i += stride) {
            int l = i / (128*KP1); int r = i % (128*KP1);
            int c = r / KP1; int k = r % KP1;
            float v = (k < K_EDGE) ? ew1[(size_t)l*K_EDGE*128 + (size_t)k*128 + c] : 0.0f;
            ew1T[i] = f2bf(v);
        }
        for (int i = idx; i < 2*128*128; i += stride) {
            int l = i / (128*128); int r = i % (128*128);
            int c = r / 128; int k = r % 128;
            ew2T[i] = f2bf(ew2[(size_t)l*128*128 + (size_t)k*128 + c]);
        }
        for (int i = idx; i < 2*128*KN; i += stride) {
            int l = i / (128*KN); int r = i % (128*KN);
            int c = r / KN; int k = r % KN;
            const float* base = nw1 + (size_t)l*384*128;
            float v = (k < 128) ? (base[(size_t)k*128 + c] + base[(size_t)(256+k)*128 + c])
                                : base[(size_t)k*128 + c];
            nw1T[i] = f2bf(v);
        }
        for (int i = idx; i < 2*128*128; i += stride) {
            int l = i / (128*128); int r = i % (128*128);
            int c = r / 128; int k = r % 128;
            nw2T[i] = f2bf(nw2[(size_t)l*128*128 + (size_t)k*128 + c]);
        }
        // ---- out head weights: owT[c][k], c<64 mu / c>=64 var; k<135 weights, k=135 bias ----
        for (int i = idx; i < 128*KO; i += stride) {
            int c = i / KO; int k = i % KO;
            float v = 0.0f;
            if (c < 64) {
                if (k < 135) v = mu_w[(size_t)k*LAT + c];
                else if (k == 135) v = mu_b[c];
            } else {
                int cc = c - 64;
                if (k < 135) v = var_w[(size_t)k*LAT + cc];
                else if (k == 135) v = var_b[cc];
            }
            owT[i] = f2bf(v);
        }
    } else {
        // ---- agg zero ----
        int idx = (b - EB - EMB_B - WPB) * 256 + t;
        int stride = ZB * 256;
        float4 z = {0,0,0,0};
        float4* a4 = (float4*)agg;
        for (int i = idx; i < N_NODES*HID/4; i += stride) a4[i] = z;
    }
}

// ---------------- CSR pass 2a: per-block exclusive scan (256 rows/block) ----------------
__global__ void scan_a(const int* __restrict__ cnt, int* __restrict__ cursor,
                       int* __restrict__ blk) {
    __shared__ int s[256];
    int b = blockIdx.x, t = threadIdx.x;
    int row = b * 256 + t;
    int v = (row < N_NODES) ? cnt[row] : 0;
    s[t] = v;
    __syncthreads();
    #pragma unroll
    for (int off = 1; off < 256; off <<= 1) {
        int add = (t >= off) ? s[t - off] : 0;
        __syncthreads();
        s[t] += add;
        __syncthreads();
    }
    if (row < N_NODES) cursor[row] = s[t] - v;     // exclusive within block
    if (t == 255) blk[b] = s[255];                 // block total
}

// ---------------- CSR pass 2b: exclusivize the 196 block totals ----------------
__global__ void scan_b(int* __restrict__ blk) {
    __shared__ int s[256];
    int t = threadIdx.x;
    int v = (t < NSCAN) ? blk[t] : 0;
    s[t] = v;
    __syncthreads();
    #pragma unroll
    for (int off = 1; off < 256; off <<= 1) {
        int add = (t >= off) ? s[t - off] : 0;
        __syncthreads();
        s[t] += add;
        __syncthreads();
    }
    if (t < NSCAN) blk[t] = s[t] - v;              // exclusive block offset
}

// ---------------- CSR pass 3: radial+tail inline, place srow/scol/tail sorted ----------------
__global__ void csr_place(const int* __restrict__ edges, const float* __restrict__ x,
                          const float* __restrict__ edge_attr,
                          int* __restrict__ cursor, const int* __restrict__ blk,
                          int* __restrict__ srow, int* __restrict__ scol,
                          short* __restrict__ tail_s) {
    int e = blockIdx.x * 256 + threadIdx.x;
    if (e >= N_EDGES) return;
    int r = edges[e], c = edges[N_EDGES + e];
    float dx = x[r*3+0] - x[c*3+0];
    float dy = x[r*3+1] - x[c*3+1];
    float dz = x[r*3+2] - x[c*3+2];
    float radial = dx*dx + dy*dy + dz*dz;
    float4 ea = *(const float4*)(edge_attr + (size_t)e * 4);
    short8 s = { f2bf(radial), f2bf(ea.x), f2bf(ea.y), f2bf(ea.z), f2bf(ea.w), 0, 0, 0 };
    int pos = atomicAdd(&cursor[r], 1) + blk[r >> 8];
    srow[pos] = r; scol[pos] = c;
    *(short8*)(tail_s + (size_t)pos * 8) = s;
}

// ---------------- MFMA edge MLP: r0/r1-exact structure (plateau-best 177 us) ----------------
// r0-r6 plateau: DMA pipeline / occupancy x2 / TE=64 / 16-ch waves / asm pin all
// landed 177-200 us. This 4-phase tile loop's ceiling is ~177; do not re-gamble here.
__global__ __launch_bounds__(256, 2) void edge_mfma_kernel(
    const short* __restrict__ h_bf, const short* __restrict__ tail_s,
    const int* __restrict__ srow, const int* __restrict__ scol,
    const short* __restrict__ w1T, const float* __restrict__ b1,
    const short* __restrict__ w2T, const float* __restrict__ b2,
    float* __restrict__ agg)
{
    __shared__ __align__(16) short featA[TE * AST];   // 18944 B; msg overlays here
    __shared__ __align__(16) short t1[TE * TST];      // 8704 B
    __shared__ int srowS[TE];
    float* msgF = (float*)featA;                      // TE x MST floats = 16896 B <= featA
    int t = threadIdx.x;
    int lane = t & 63;
    int wv = t >> 6;          // wave: channel block [wv*32, wv*32+32)
    int l15 = lane & 15;
    int quad = lane >> 4;
    int el = t >> 3, j = t & 7;

    short8 aw1[2][9], aw2[2][4];
    float4 b1v[2], b2v[2];
    #pragma unroll
    for (int mi = 0; mi < 2; ++mi) {
        #pragma unroll
        for (int ks = 0; ks < 9; ++ks)
            aw1[mi][ks] = *(const short8*)&w1T[(size_t)(wv*32 + mi*16 + l15)*KP1 + ks*32 + quad*8];
        #pragma unroll
        for (int ks = 0; ks < 4; ++ks)
            aw2[mi][ks] = *(const short8*)&w2T[(size_t)(wv*32 + mi*16 + l15)*128 + ks*32 + quad*8];
        b1v[mi] = *(const float4*)&b1[wv*32 + mi*16 + quad*4];
        b2v[mi] = *(const float4*)&b2[wv*32 + mi*16 + quad*4];
    }

    for (int it = 0; it < NTPB; ++it) {
        int e0 = (blockIdx.x * NTPB + it) * TE;
        __syncthreads();   // prior iteration's msg reads done before featA overwrite

        // ---- stage TE edges' gathered bf16 features ----
        {
            int e = e0 + el;
            int r = srow[e], c = scol[e];
            if (j == 0) srowS[el] = r;
            const short8* hr = (const short8*)(h_bf + (size_t)r * HID + j*16);
            const short8* hc = (const short8*)(h_bf + (size_t)c * HID + j*16);
            short8 s0 = hr[0], s1 = hr[1];
            short8 s2 = hc[0], s3 = hc[1];
            *(short8*)&featA[el*AST + j*16]       = s0;
            *(short8*)&featA[el*AST + j*16 + 8]   = s1;
            *(short8*)&featA[el*AST + 128 + j*16]     = s2;
            *(short8*)&featA[el*AST + 128 + j*16 + 8] = s3;
        }
        if (t < TE) {
            int e = e0 + t;
            short8 s = *(const short8*)(tail_s + (size_t)e * 8);
            short8 z = {0,0,0,0,0,0,0,0};
            *(short8*)&featA[t*AST + 256] = s;
            *(short8*)&featA[t*AST + 264] = z;
            *(short8*)&featA[t*AST + 272] = z;
            *(short8*)&featA[t*AST + 280] = z;
        }
        __syncthreads();

        // ---- layer 1: K = 288 ----
        floatx4 acc[2][2] = {{{0,0,0,0},{0,0,0,0}},{{0,0,0,0},{0,0,0,0}}};
        #pragma unroll
        for (int ks = 0; ks < 9; ++ks) {
            int koff = ks*32 + quad*8;
            short8 bb0 = *(const short8*)&featA[l15*AST + koff];
            short8 bb1 = *(const short8*)&featA[(16 + l15)*AST + koff];
            acc[0][0] = __builtin_amdgcn_mfma_f32_16x16x32_bf16(aw1[0][ks], bb0, acc[0][0], 0, 0, 0);
            acc[0][1] = __builtin_amdgcn_mfma_f32_16x16x32_bf16(aw1[0][ks], bb1, acc[0][1], 0, 0, 0);
            acc[1][0] = __builtin_amdgcn_mfma_f32_16x16x32_bf16(aw1[1][ks], bb0, acc[1][0], 0, 0, 0);
            acc[1][1] = __builtin_amdgcn_mfma_f32_16x16x32_bf16(aw1[1][ks], bb1, acc[1][1], 0, 0, 0);
        }

        // ---- epilogue 1: bias + elu -> bf16 t1[e][c] ----
        #pragma unroll
        for (int mi = 0; mi < 2; ++mi) {
            int cb = wv*32 + mi*16 + quad*4;
            #pragma unroll
            for (int ni = 0; ni < 2; ++ni) {
                short2 q0 = f2bf2(elu_f(acc[mi][ni][0] + b1v[mi].x),
                                  elu_f(acc[mi][ni][1] + b1v[mi].y));
                short2 q1 = f2bf2(elu_f(acc[mi][ni][2] + b1v[mi].z),
                                  elu_f(acc[mi][ni][3] + b1v[mi].w));
                short4v s = { q0.x, q0.y, q1.x, q1.y };
                *(short4v*)&t1[(ni*16 + l15)*TST + cb] = s;
            }
        }
        __syncthreads();   // featA reads done -> msg overlay safe after here

        // ---- layer 2: K = 128 ----
        floatx4 acc2[2][2] = {{{0,0,0,0},{0,0,0,0}},{{0,0,0,0},{0,0,0,0}}};
        #pragma unroll
        for (int ks = 0; ks < 4; ++ks) {
            int koff = ks*32 + quad*8;
            short8 bb0 = *(const short8*)&t1[l15*TST + koff];
            short8 bb1 = *(const short8*)&t1[(16 + l15)*TST + koff];
            acc2[0][0] = __builtin_amdgcn_mfma_f32_16x16x32_bf16(aw2[0][ks], bb0, acc2[0][0], 0, 0, 0);
            acc2[0][1] = __builtin_amdgcn_mfma_f32_16x16x32_bf16(aw2[0][ks], bb1, acc2[0][1], 0, 0, 0);
            acc2[1][0] = __builtin_amdgcn_mfma_f32_16x16x32_bf16(aw2[1][ks], bb0, acc2[1][0], 0, 0, 0);
            acc2[1][1] = __builtin_amdgcn_mfma_f32_16x16x32_bf16(aw2[1][ks], bb1, acc2[1][1], 0, 0, 0);
        }

        // ---- epilogue 2: bias + elu -> f32 msg tile (overlaid on featA) ----
        #pragma unroll
        for (int mi = 0; mi < 2; ++mi) {
            int cb = wv*32 + mi*16 + quad*4;
            #pragma unroll
            for (int ni = 0; ni < 2; ++ni) {
                float4 v = { elu_f(acc2[mi][ni][0] + b2v[mi].x), elu_f(acc2[mi][ni][1] + b2v[mi].y),
                             elu_f(acc2[mi][ni][2] + b2v[mi].z), elu_f(acc2[mi][ni][3] + b2v[mi].w) };
                *(float4*)&msgF[(ni*16 + l15)*MST + cb] = v;
            }
        }
        __syncthreads();

        // ---- segmented reduce: thread (ch, half) walks 16 sorted edges, flush per run ----
        {
            int ch = t & 127, half = t >> 7;
            int base = half * 16;
            int prow = srowS[base];
            float run = 0.0f;
            #pragma unroll
            for (int i = 0; i < 16; ++i) {
                int rr = srowS[base + i];
                if (rr != prow) {
                    unsafeAtomicAdd(&agg[(size_t)prow * HID + ch], run);
                    run = 0.0f; prow = rr;
                }
                run += msgF[(base + i)*MST + ch];
            }
            unsafeAtomicAdd(&agg[(size_t)prow * HID + ch], run);
        }
    }
}

// ---------------- MFMA node MLP + (l==1) fused output head ----------------
// do_out: after layer 2, stage hl=[h,label,1] bf16 K=160, one more MFMA vs owT
// ([mu;var] weights, bias folded at k=135), then z = mu + 0.01*eps*exp(0.5*var).
// bounds (256,2): register CAP only (out-weight frags add ~40 VGPR); occupancy
// still LDS-governed (36.4 KB -> up to 4 blocks/CU).
__global__ __launch_bounds__(256, 2) void node_mfma_kernel(
    const short* __restrict__ h_bf, float* __restrict__ agg,
    const short* __restrict__ w1T, const float* __restrict__ b1,
    const short* __restrict__ w2T, const float* __restrict__ b2,
    const short* __restrict__ owT, const float* __restrict__ label,
    const float* __restrict__ eps, float* __restrict__ zout,
    short* __restrict__ hout_bf, int zero_agg, int do_out)
{
    __shared__ __align__(16) short featN[32 * NST];   // 16896 B; outB overlays here
    __shared__ __align__(16) short t1[32 * TST];      // 8704 B
    __shared__ __align__(16) short hlB[32 * HLST];    // 10752 B (fused out operand)
    float* outB = (float*)featN;                      // 32 x OST floats = 16896 B
    int t = threadIdx.x;
    int lane = t & 63;
    int wv = t >> 6;
    int l15 = lane & 15;
    int quad = lane >> 4;
    int nl = t >> 3, j = t & 7;

    short8 aw1[2][8], aw2[2][4];
    float4 b1v[2], b2v[2];
    #pragma unroll
    for (int mi = 0; mi < 2; ++mi) {
        #pragma unroll
        for (int ks = 0; ks < 8; ++ks)
            aw1[mi][ks] = *(const short8*)&w1T[(size_t)(wv*32 + mi*16 + l15)*KN + ks*32 + quad*8];
        #pragma unroll
        for (int ks = 0; ks < 4; ++ks)
            aw2[mi][ks] = *(const short8*)&w2T[(size_t)(wv*32 + mi*16 + l15)*128 + ks*32 + quad*8];
        b1v[mi] = *(const float4*)&b1[wv*32 + mi*16 + quad*4];
        b2v[mi] = *(const float4*)&b2[wv*32 + mi*16 + quad*4];
    }

    for (int it = 0; it < NTN; ++it) {
        int n0 = (blockIdx.x * NTN + it) * 32;
        if (n0 >= N_NODES) break;          // block-uniform
        __syncthreads();

        int n = n0 + nl;
        int idx = n < N_NODES ? n : N_NODES - 1;
        {
            const short8* hp = (const short8*)(h_bf + (size_t)idx * HID + j*16);
            short8 s0 = hp[0], s1 = hp[1];
            const float4* ap = (const float4*)(agg + (size_t)idx * HID) + j*4;
            float4 u0 = ap[0], u1 = ap[1], u2 = ap[2], u3 = ap[3];
            short2 p0 = f2bf2(u0.x, u0.y), p1 = f2bf2(u0.z, u0.w);
            short2 p2 = f2bf2(u1.x, u1.y), p3 = f2bf2(u1.z, u1.w);
            short2 p4 = f2bf2(u2.x, u2.y), p5 = f2bf2(u2.z, u2.w);
            short2 p6 = f2bf2(u3.x, u3.y), p7 = f2bf2(u3.z, u3.w);
            short8 s2 = { p0.x, p0.y, p1.x, p1.y, p2.x, p2.y, p3.x, p3.y };
            short8 s3 = { p4.x, p4.y, p5.x, p5.y, p6.x, p6.y, p7.x, p7.y };
            *(short8*)&featN[nl*NST + j*16]       = s0;
            *(short8*)&featN[nl*NST + j*16 + 8]   = s1;
            *(short8*)&featN[nl*NST + 128 + j*16]     = s2;
            *(short8*)&featN[nl*NST + 128 + j*16 + 8] = s3;
        }
        __syncthreads();

        // ---- re-zero consumed agg rows for the next layer ----
        if (zero_agg && n < N_NODES) {
            float4 z = {0,0,0,0};
            float4* ap = (float4*)(agg + (size_t)n * HID) + j*4;
            ap[0] = z; ap[1] = z; ap[2] = z; ap[3] = z;
        }

        floatx4 acc[2][2] = {{{0,0,0,0},{0,0,0,0}},{{0,0,0,0},{0,0,0,0}}};
        #pragma unroll
        for (int ks = 0; ks < 8; ++ks) {
            int koff = ks*32 + quad*8;
            short8 bb0 = *(const short8*)&featN[l15*NST + koff];
            short8 bb1 = *(const short8*)&featN[(16 + l15)*NST + koff];
            acc[0][0] = __builtin_amdgcn_mfma_f32_16x16x32_bf16(aw1[0][ks], bb0, acc[0][0], 0, 0, 0);
            acc[0][1] = __builtin_amdgcn_mfma_f32_16x16x32_bf16(aw1[0][ks], bb1, acc[0][1], 0, 0, 0);
            acc[1][0] = __builtin_amdgcn_mfma_f32_16x16x32_bf16(aw1[1][ks], bb0, acc[1][0], 0, 0, 0);
            acc[1][1] = __builtin_amdgcn_mfma_f32_16x16x32_bf16(aw1[1][ks], bb1, acc[1][1], 0, 0, 0);
        }

        #pragma unroll
        for (int mi = 0; mi < 2; ++mi) {
            int cb = wv*32 + mi*16 + quad*4;
            #pragma unroll
            for (int ni = 0; ni < 2; ++ni) {
                short2 p0 = f2bf2(elu_f(acc[mi][ni][0] + b1v[mi].x),
                                  elu_f(acc[mi][ni][1] + b1v[mi].y));
                short2 p1 = f2bf2(elu_f(acc[mi][ni][2] + b1v[mi].z),
                                  elu_f(acc[mi][ni][3] + b1v[mi].w));
                short4v s = { p0.x, p0.y, p1.x, p1.y };
                *(short4v*)&t1[(ni*16 + l15)*TST + cb] = s;
            }
        }
        __syncthreads();

        floatx4 acc2[2][2] = {{{0,0,0,0},{0,0,0,0}},{{0,0,0,0},{0,0,0,0}}};
        #pragma unroll
        for (int ks = 0; ks < 4; ++ks) {
            int koff = ks*32 + quad*8;
            short8 bb0 = *(const short8*)&t1[l15*TST + koff];
            short8 bb1 = *(const short8*)&t1[(16 + l15)*TST + koff];
            acc2[0][0] = __builtin_amdgcn_mfma_f32_16x16x32_bf16(aw2[0][ks], bb0, acc2[0][0], 0, 0, 0);
            acc2[0][1] = __builtin_amdgcn_mfma_f32_16x16x32_bf16(aw2[0][ks], bb1, acc2[0][1], 0, 0, 0);
            acc2[1][0] = __builtin_amdgcn_mfma_f32_16x16x32_bf16(aw2[1][ks], bb0, acc2[1][0], 0, 0, 0);
            acc2[1][1] = __builtin_amdgcn_mfma_f32_16x16x32_bf16(aw2[1][ks], bb1, acc2[1][1], 0, 0, 0);
        }

        if (!do_out) {
            // ---- layer output h -> global bf16 ----
            #pragma unroll
            for (int mi = 0; mi < 2; ++mi) {
                int cb = wv*32 + mi*16 + quad*4;
                #pragma unroll
                for (int ni = 0; ni < 2; ++ni) {
                    int nn = n0 + ni*16 + l15;
                    if (nn < N_NODES) {
                        short2 p0 = f2bf2(acc2[mi][ni][0] + b2v[mi].x, acc2[mi][ni][1] + b2v[mi].y);
                        short2 p1 = f2bf2(acc2[mi][ni][2] + b2v[mi].z, acc2[mi][ni][3] + b2v[mi].w);
                        short4v s = { p0.x, p0.y, p1.x, p1.y };
                        *(short4v*)&hout_bf[(size_t)nn*HID + cb] = s;
                    }
                }
            }
        } else {
            // ---- fused out head: hl = [h(128), label(7), 1, 0...] bf16 in LDS ----
            #pragma unroll
            for (int mi = 0; mi < 2; ++mi) {
                int cb = wv*32 + mi*16 + quad*4;
                #pragma unroll
                for (int ni = 0; ni < 2; ++ni) {
                    short2 p0 = f2bf2(acc2[mi][ni][0] + b2v[mi].x, acc2[mi][ni][1] + b2v[mi].y);
                    short2 p1 = f2bf2(acc2[mi][ni][2] + b2v[mi].z, acc2[mi][ni][3] + b2v[mi].w);
                    short4v s = { p0.x, p0.y, p1.x, p1.y };
                    *(short4v*)&hlB[(ni*16 + l15)*HLST + cb] = s;
                }
            }
            if (t < 32) {
                int nn = n0 + t;
                int ii = nn < N_NODES ? nn : N_NODES - 1;
                const float* lp = label + (size_t)ii * 7;
                short8 s = { f2bf(lp[0]), f2bf(lp[1]), f2bf(lp[2]), f2bf(lp[3]),
                             f2bf(lp[4]), f2bf(lp[5]), f2bf(lp[6]), f2bf(1.0f) };
                short8 z = {0,0,0,0,0,0,0,0};
                *(short8*)&hlB[t*HLST + 128] = s;
                *(short8*)&hlB[t*HLST + 136] = z;
                *(short8*)&hlB[t*HLST + 144] = z;
                *(short8*)&hlB[t*HLST + 152] = z;
            }
            __syncthreads();

            // ---- out MFMA: K=160; wave ch rows: 0-63 mu, 64-127 var ----
            floatx4 accO[2][2] = {{{0,0,0,0},{0,0,0,0}},{{0,0,0,0},{0,0,0,0}}};
            short8 awO[2][5];
            #pragma unroll
            for (int mi = 0; mi < 2; ++mi)
                #pragma unroll
                for (int ks = 0; ks < 5; ++ks)
                    awO[mi][ks] = *(const short8*)&owT[(size_t)(wv*32 + mi*16 + l15)*KO + ks*32 + quad*8];
            #pragma unroll
            for (int ks = 0; ks < 5; ++ks) {
                int koff = ks*32 + quad*8;
                short8 bb0 = *(const short8*)&hlB[l15*HLST + koff];
                short8 bb1 = *(const short8*)&hlB[(16 + l15)*HLST + koff];
                accO[0][0] = __builtin_amdgcn_mfma_f32_16x16x32_bf16(awO[0][ks], bb0, accO[0][0], 0, 0, 0);
                accO[0][1] = __builtin_amdgcn_mfma_f32_16x16x32_bf16(awO[0][ks], bb1, accO[0][1], 0, 0, 0);
                accO[1][0] = __builtin_amdgcn_mfma_f32_16x16x32_bf16(awO[1][ks], bb0, accO[1][0], 0, 0, 0);
                accO[1][1] = __builtin_amdgcn_mfma_f32_16x16x32_bf16(awO[1][ks], bb1, accO[1][1], 0, 0, 0);
            }
            #pragma unroll
            for (int mi = 0; mi < 2; ++mi) {
                int cg = wv*32 + mi*16 + quad*4;   // 0-63 mu, 64-127 var
                #pragma unroll
                for (int ni = 0; ni < 2; ++ni) {
                    float4 v = { accO[mi][ni][0], accO[mi][ni][1], accO[mi][ni][2], accO[mi][ni][3] };
                    *(float4*)&outB[(ni*16 + l15)*OST + cg] = v;
                }
            }
            __syncthreads();

            // ---- z = mu + 0.01*eps*exp(0.5*var), coalesced ----
            {
                int c = t & 63, g = t >> 6;
                #pragma unroll
                for (int i = 0; i < 8; ++i) {
                    int nloc = g*8 + i;
                    int nn = n0 + nloc;
                    if (nn < N_NODES) {
                        float mu = outB[nloc*OST + c];
                        float va = outB[nloc*OST + 64 + c];
                        zout[(size_t)nn*LAT + c] = mu + 0.01f * eps[(size_t)nn*LAT + c] * __expf(va * 0.5f);
                    }
                }
            }
        }
    }
}

extern "C" void kernel_launch(void* const* d_in, const int* in_sizes, int n_in,
                              void* d_out, int out_size, void* d_ws, size_t ws_size,
                              hipStream_t stream) {
    const float* h0        = (const float*)d_in[0];
    const float* label     = (const float*)d_in[1];
    const float* x         = (const float*)d_in[2];
    const float* edge_attr = (const float*)d_in[3];
    const float* eps       = (const float*)d_in[4];
    const float* emb_w     = (const float*)d_in[5];
    const float* emb_b     = (const float*)d_in[6];
    const float* edge_w1   = (const float*)d_in[7];
    const float* edge_b1   = (const float*)d_in[8];
    const float* edge_w2   = (const float*)d_in[9];
    const float* edge_b2   = (const float*)d_in[10];
    const float* node_w1   = (const float*)d_in[11];
    const float* node_b1   = (const float*)d_in[12];
    const float* node_w2   = (const float*)d_in[13];
    const float* node_b2   = (const float*)d_in[14];
    const float* mu_w      = (const float*)d_in[15];
    const float* mu_b      = (const float*)d_in[16];
    const float* var_w     = (const float*)d_in[17];
    const float* var_b     = (const float*)d_in[18];
    const int*   edges     = (const int*)d_in[19];
    float* out = (float*)d_out;

    float* agg      = (float*)d_ws;                     // N*128 f32
    short* h_bf     = (short*)(agg + (size_t)N_NODES * HID);  // N*128 bf16
    short* tail_s   = h_bf + (size_t)N_NODES * HID;     // E*8 bf16 (sorted)
    int*   cnt      = (int*)(tail_s + (size_t)N_EDGES * 8);   // N int
    int*   cursor   = cnt + N_NODES;                    // N int
    int*   blk      = cursor + N_NODES;                 // 256 int
    int*   srow     = blk + 256;                        // E int
    int*   scol     = srow + N_EDGES;                   // E int
    short* ew1T     = (short*)(scol + N_EDGES);         // 2*128*288
    short* ew2T     = ew1T + 2*128*KP1;                 // 2*128*128
    short* nw1T     = ew2T + 2*128*128;                 // 2*128*256
    short* nw2T     = nw1T + 2*128*KN;                  // 2*128*128
    short* owT      = nw2T + 2*128*128;                 // 128*160

    hipMemsetAsync(cnt, 0, N_NODES * sizeof(int), stream);
    prep_all<<<EB + EMB_B + WPB + ZB, 256, 0, stream>>>(
        edges, h0, emb_w, emb_b,
        edge_w1, edge_w2, node_w1, node_w2,
        mu_w, mu_b, var_w, var_b,
        cnt, h_bf, ew1T, ew2T, nw1T, nw2T, owT, agg);
    scan_a<<<NSCAN, 256, 0, stream>>>(cnt, cursor, blk);
    scan_b<<<1, 256, 0, stream>>>(blk);
    csr_place<<<(N_EDGES + 255) / 256, 256, 0, stream>>>(edges, x, edge_attr, cursor, blk,
                                                         srow, scol, tail_s);

    for (int l = 0; l < 2; ++l) {
        edge_mfma_kernel<<<N_EDGES / TE / NTPB, 256, 0, stream>>>(
            h_bf, tail_s, srow, scol,
            ew1T + (size_t)l * 128 * KP1, edge_b1 + l * HID,
            ew2T + (size_t)l * 128 * 128, edge_b2 + l * HID, agg);
        node_mfma_kernel<<<(N_NODES/32 + NTN) / NTN, 256, 0, stream>>>(
            h_bf, agg,
            nw1T + (size_t)l * 128 * KN, node_b1 + l * HID,
            nw2T + (size_t)l * 128 * 128, node_b2 + l * HID,
            owT, label, eps, out, h_bf,
            (l == 0) ? 1 : 0, (l == 1) ? 1 : 0);
    }
}

// Round 8
// 592.412 us; speedup vs baseline: 1.6256x; 1.0342x over previous
//
#include <hip/hip_runtime.h>
#include <hip/hip_bf16.h>
#include <math.h>

#define N_NODES 50000
#define N_EDGES 800000
#define HID 128
#define LAT 64
#define IN_NODE 11
#define KN 256        // node MLP folded K (h + agg)
#define KO 160        // fused out head K: 128 h + 7 label + 1 bias + 24 pad
#define NST 264       // node feature LDS row stride, 256+8 pad
#define TST 136       // t1 LDS row stride, 128+8 pad
#define MST 132       // msg LDS row stride (floats), 128+4 pad
#define HLST 168      // fused-out hl row stride (160+8 pad)
#define OST 132       // fused-out result row stride (floats)
#define TE 32         // edges per tile
#define NTPB 20       // edge tiles per block (grid 1250)
#define NTN 2         // node tiles per block (grid 782)
#define NSCAN 196     // scan blocks: 196*256 = 50176 >= N_NODES
// prep_all block partition
#define EB 3125       // edge count blocks
#define EMB_B 25000   // embedding blocks (2 nodes each: h + a0)
#define WPB 32        // weight prep blocks
#define ZB 100        // agg zero blocks

typedef __attribute__((ext_vector_type(8))) short short8;
typedef __attribute__((ext_vector_type(4))) short short4v;
typedef __attribute__((ext_vector_type(4))) float floatx4;

__device__ __forceinline__ float elu_f(float v) { return v > 0.0f ? v : __expf(v) - 1.0f; }

__device__ __forceinline__ short f2bf(float f) {
    unsigned int u = __builtin_bit_cast(unsigned int, f);
    u += 0x7fffu + ((u >> 16) & 1u);   // round-to-nearest-even
    return (short)(u >> 16);
}

__device__ __forceinline__ short2 f2bf2(float a, float b) {
    float2 p; p.x = a; p.y = b;
    __hip_bfloat162 h = __float22bfloat162_rn(p);   // v_cvt_pk_bf16_f32
    short2 r;
    __builtin_memcpy(&r, &h, sizeof(r));
    return r;
}

__device__ __forceinline__ float bf2f(short s) {
    unsigned int u = ((unsigned int)(unsigned short)s) << 16;
    return __builtin_bit_cast(float, u);
}

// ---------------- compose: cw[12][256] = [emb_w; emb_b] @ W1(layer0) folded ----------------
// a0[n][mm] = h0[n] . cw[0..10][mm] + cw[11][mm]  reproduces W1a/W1b applied to emb(h0) in f32.
__global__ void compose_k(const float* __restrict__ emb_w, const float* __restrict__ emb_b,
                          const float* __restrict__ ew1, float* __restrict__ cw) {
    int k0 = blockIdx.x;        // 0..11
    int mm = threadIdx.x;       // 0..255
    int m = mm & 127;
    int base = (mm < 128) ? 0 : 128;
    float s = 0.0f;
    for (int k = 0; k < 128; ++k) {
        float w = ew1[(size_t)(base + k) * 128 + m];
        float e = (k0 < 11) ? emb_w[k0 * 128 + k] : emb_b[k];
        s += e * w;
    }
    cw[k0 * 256 + mm] = s;
}

// ---------------- fused prep: edge count | emb+a0 | weight prep | agg zero ----------------
__global__ void prep_all(const int* __restrict__ edges, const float* __restrict__ h0,
                         const float* __restrict__ emb_w, const float* __restrict__ emb_b,
                         const float* __restrict__ ew1, const float* __restrict__ ew2,
                         const float* __restrict__ nw1, const float* __restrict__ nw2,
                         const float* __restrict__ mu_w, const float* __restrict__ mu_b,
                         const float* __restrict__ var_w, const float* __restrict__ var_b,
                         const float* __restrict__ cw,
                         int* __restrict__ cnt,
                         short* __restrict__ h_bf, float* __restrict__ aG,
                         short* __restrict__ ew2T,
                         short* __restrict__ nw1T, short* __restrict__ nw2T,
                         short* __restrict__ owT, short* __restrict__ awaT,
                         float* __restrict__ agg) {
    int b = blockIdx.x, t = threadIdx.x;
    if (b < EB) {
        // ---- edge: pure degree count ----
        int e = b * 256 + t;
        if (e >= N_EDGES) return;
        atomicAdd(&cnt[edges[e]], 1);
    } else if (b < EB + EMB_B) {
        // ---- embedding: h_bf = bf16(emb(h0)); a0 = f32 composed (layer-0 edge operand) ----
        int bb = b - EB;
        int n = bb * 2 + (t >> 7);
        int c = t & 127;
        if (n >= N_NODES) return;
        float h0v[IN_NODE];
        #pragma unroll
        for (int k = 0; k < IN_NODE; ++k) h0v[k] = h0[n*IN_NODE + k];
        float acc = emb_b[c];
        #pragma unroll
        for (int k = 0; k < IN_NODE; ++k) acc += h0v[k] * emb_w[k*HID + c];
        h_bf[(size_t)n*HID + c] = f2bf(acc);
        float s0 = cw[11*256 + c], s1 = cw[11*256 + 128 + c];
        #pragma unroll
        for (int k = 0; k < IN_NODE; ++k) {
            s0 += h0v[k] * cw[k*256 + c];
            s1 += h0v[k] * cw[k*256 + 128 + c];
        }
        aG[(size_t)n*256 + c]       = s0;
        aG[(size_t)n*256 + 128 + c] = s1;
    } else if (b < EB + EMB_B + WPB) {
        // ---- weight prep: transpose + bf16 ----
        int idx = (b - EB - EMB_B) * 256 + t;
        int stride = WPB * 256;
        for (int i = idx; i < 2*128*128; i += stride) {
            int l = i / (128*128); int r = i % (128*128);
            int c = r / 128; int k = r % 128;
            ew2T[i] = f2bf(ew2[(size_t)l*128*128 + (size_t)k*128 + c]);
        }
        for (int i = idx; i < 2*128*KN; i += stride) {
            int l = i / (128*KN); int r = i % (128*KN);
            int c = r / KN; int k = r % KN;
            const float* base = nw1 + (size_t)l*384*128;
            float v = (k < 128) ? (base[(size_t)k*128 + c] + base[(size_t)(256+k)*128 + c])
                                : base[(size_t)k*128 + c];
            nw1T[i] = f2bf(v);
        }
        for (int i = idx; i < 2*128*128; i += stride) {
            int l = i / (128*128); int r = i % (128*128);
            int c = r / 128; int k = r % 128;
            nw2T[i] = f2bf(nw2[(size_t)l*128*128 + (size_t)k*128 + c]);
        }
        // out head weights: owT[c][k], c<64 mu / c>=64 var; k<135 weights, k=135 bias
        for (int i = idx; i < 128*KO; i += stride) {
            int c = i / KO; int k = i % KO;
            float v = 0.0f;
            if (c < 64) {
                if (k < 135) v = mu_w[(size_t)k*LAT + c];
                else if (k == 135) v = mu_b[c];
            } else {
                int cc = c - 64;
                if (k < 135) v = var_w[(size_t)k*LAT + cc];
                else if (k == 135) v = var_b[cc];
            }
            owT[i] = f2bf(v);
        }
        // awaT[l][mm][k]: a-precompute weights (both layers; layer1 used by node l=0 ap)
        for (int i = idx; i < 2*256*128; i += stride) {
            int l = i / (256*128); int r = i % (256*128);
            int mm = r / 128; int k = r % 128;
            int kk = (mm < 128) ? k : 128 + k;
            awaT[i] = f2bf(ew1[(size_t)l*261*128 + (size_t)kk*128 + (mm & 127)]);
        }
    } else {
        // ---- agg zero ----
        int idx = (b - EB - EMB_B - WPB) * 256 + t;
        int stride = ZB * 256;
        float4 z = {0,0,0,0};
        float4* a4 = (float4*)agg;
        for (int i = idx; i < N_NODES*HID/4; i += stride) a4[i] = z;
    }
}

// ---------------- CSR pass 2a: per-block exclusive scan (256 rows/block) ----------------
__global__ void scan_a(const int* __restrict__ cnt, int* __restrict__ cursor,
                       int* __restrict__ blk) {
    __shared__ int s[256];
    int b = blockIdx.x, t = threadIdx.x;
    int row = b * 256 + t;
    int v = (row < N_NODES) ? cnt[row] : 0;
    s[t] = v;
    __syncthreads();
    #pragma unroll
    for (int off = 1; off < 256; off <<= 1) {
        int add = (t >= off) ? s[t - off] : 0;
        __syncthreads();
        s[t] += add;
        __syncthreads();
    }
    if (row < N_NODES) cursor[row] = s[t] - v;     // exclusive within block
    if (t == 255) blk[b] = s[255];                 // block total
}

// ---------------- CSR pass 2b: exclusivize the 196 block totals ----------------
__global__ void scan_b(int* __restrict__ blk) {
    __shared__ int s[256];
    int t = threadIdx.x;
    int v = (t < NSCAN) ? blk[t] : 0;
    s[t] = v;
    __syncthreads();
    #pragma unroll
    for (int off = 1; off < 256; off <<= 1) {
        int add = (t >= off) ? s[t - off] : 0;
        __syncthreads();
        s[t] += add;
        __syncthreads();
    }
    if (t < NSCAN) blk[t] = s[t] - v;              // exclusive block offset
}

// ---------------- CSR pass 3: radial+tail inline, place srow/scol/tail sorted ----------------
__global__ void csr_place(const int* __restrict__ edges, const float* __restrict__ x,
                          const float* __restrict__ edge_attr,
                          int* __restrict__ cursor, const int* __restrict__ blk,
                          int* __restrict__ srow, int* __restrict__ scol,
                          short* __restrict__ tail_s) {
    int e = blockIdx.x * 256 + threadIdx.x;
    if (e >= N_EDGES) return;
    int r = edges[e], c = edges[N_EDGES + e];
    float dx = x[r*3+0] - x[c*3+0];
    float dy = x[r*3+1] - x[c*3+1];
    float dz = x[r*3+2] - x[c*3+2];
    float radial = dx*dx + dy*dy + dz*dz;
    float4 ea = *(const float4*)(edge_attr + (size_t)e * 4);
    short8 s = { f2bf(radial), f2bf(ea.x), f2bf(ea.y), f2bf(ea.z), f2bf(ea.w), 0, 0, 0 };
    int pos = atomicAdd(&cursor[r], 1) + blk[r >> 8];
    srow[pos] = r; scol[pos] = c;
    *(short8*)(tail_s + (size_t)pos * 8) = s;
}

// ---------------- edge kernel: elementwise L1 (a1[row]+a2[col]+W1c.tail) + MFMA L2 -----------
// Layer-1 GEMM replaced by per-node precompute aG (16x less FLOP); tile loop is now
// 2 barriers (srowS double-buffered): [phaseA: gather+elementwise -> t1] bar
// [L2 MFMA -> msg] bar [reduce]. No featA staging at all.
__global__ __launch_bounds__(256, 2) void edge_mfma_kernel(
    const float* __restrict__ aG, const short* __restrict__ tail_s,
    const int* __restrict__ srow, const int* __restrict__ scol,
    const float* __restrict__ w1c, const float* __restrict__ b1,
    const short* __restrict__ w2T, const float* __restrict__ b2,
    float* __restrict__ agg)
{
    __shared__ __align__(16) short t1[TE * TST];      // 8704 B
    __shared__ __align__(16) float msgF[TE * MST];    // 16896 B
    __shared__ int srowS[2][TE];
    int t = threadIdx.x;
    int lane = t & 63;
    int wv = t >> 6;          // wave: channel block [wv*32, wv*32+32)
    int l15 = lane & 15;
    int quad = lane >> 4;
    int cg = t & 15;          // channel group (8 ch) — fixed per thread
    int elb = t >> 4;         // base edge-in-tile (0..15)

    // per-thread tail weights + bias for its 8 channels
    float w1cv[5][8];
    float b1v8[8];
    #pragma unroll
    for (int k = 0; k < 5; ++k)
        #pragma unroll
        for (int j = 0; j < 8; ++j)
            w1cv[k][j] = w1c[k*128 + cg*8 + j];
    #pragma unroll
    for (int j = 0; j < 8; ++j) b1v8[j] = b1[cg*8 + j];

    // L2 weights
    short8 aw2[2][4];
    float4 b2v[2];
    #pragma unroll
    for (int mi = 0; mi < 2; ++mi) {
        #pragma unroll
        for (int ks = 0; ks < 4; ++ks)
            aw2[mi][ks] = *(const short8*)&w2T[(size_t)(wv*32 + mi*16 + l15)*128 + ks*32 + quad*8];
        b2v[mi] = *(const float4*)&b2[wv*32 + mi*16 + quad*4];
    }

    for (int it = 0; it < NTPB; ++it) {
        int e0 = (blockIdx.x * NTPB + it) * TE;
        int pb = it & 1;
        if (t < TE) srowS[pb][t] = srow[e0 + t];

        // ---- phase A: elementwise layer 1 -> t1 ----
        #pragma unroll
        for (int ii = 0; ii < 2; ++ii) {
            int el = elb + ii*16;
            int e = e0 + el;
            int r = srow[e], c = scol[e];
            const float4* p1 = (const float4*)(aG + (size_t)r * 256 + cg*8);
            const float4* p2 = (const float4*)(aG + (size_t)c * 256 + 128 + cg*8);
            float4 x0 = p1[0], x1 = p1[1];
            float4 y0 = p2[0], y1 = p2[1];
            short8 tl = *(const short8*)(tail_s + (size_t)e * 8);
            float t0 = bf2f(tl[0]), t1f = bf2f(tl[1]), t2 = bf2f(tl[2]),
                  t3 = bf2f(tl[3]), t4 = bf2f(tl[4]);
            float s[8] = { x0.x+y0.x, x0.y+y0.y, x0.z+y0.z, x0.w+y0.w,
                           x1.x+y1.x, x1.y+y1.y, x1.z+y1.z, x1.w+y1.w };
            float v[8];
            #pragma unroll
            for (int j = 0; j < 8; ++j) {
                v[j] = elu_f(s[j] + b1v8[j]
                       + t0*w1cv[0][j] + t1f*w1cv[1][j] + t2*w1cv[2][j]
                       + t3*w1cv[3][j] + t4*w1cv[4][j]);
            }
            short2 q0 = f2bf2(v[0], v[1]), q1 = f2bf2(v[2], v[3]);
            short2 q2 = f2bf2(v[4], v[5]), q3 = f2bf2(v[6], v[7]);
            short8 o = { q0.x, q0.y, q1.x, q1.y, q2.x, q2.y, q3.x, q3.y };
            *(short8*)&t1[el*TST + cg*8] = o;
        }
        __syncthreads();

        // ---- layer 2: K = 128 MFMA ----
        floatx4 acc2[2][2] = {{{0,0,0,0},{0,0,0,0}},{{0,0,0,0},{0,0,0,0}}};
        #pragma unroll
        for (int ks = 0; ks < 4; ++ks) {
            int koff = ks*32 + quad*8;
            short8 bb0 = *(const short8*)&t1[l15*TST + koff];
            short8 bb1 = *(const short8*)&t1[(16 + l15)*TST + koff];
            acc2[0][0] = __builtin_amdgcn_mfma_f32_16x16x32_bf16(aw2[0][ks], bb0, acc2[0][0], 0, 0, 0);
            acc2[0][1] = __builtin_amdgcn_mfma_f32_16x16x32_bf16(aw2[0][ks], bb1, acc2[0][1], 0, 0, 0);
            acc2[1][0] = __builtin_amdgcn_mfma_f32_16x16x32_bf16(aw2[1][ks], bb0, acc2[1][0], 0, 0, 0);
            acc2[1][1] = __builtin_amdgcn_mfma_f32_16x16x32_bf16(aw2[1][ks], bb1, acc2[1][1], 0, 0, 0);
        }

        // ---- epilogue 2: bias + elu -> f32 msg tile ----
        #pragma unroll
        for (int mi = 0; mi < 2; ++mi) {
            int cb = wv*32 + mi*16 + quad*4;
            #pragma unroll
            for (int ni = 0; ni < 2; ++ni) {
                float4 v = { elu_f(acc2[mi][ni][0] + b2v[mi].x), elu_f(acc2[mi][ni][1] + b2v[mi].y),
                             elu_f(acc2[mi][ni][2] + b2v[mi].z), elu_f(acc2[mi][ni][3] + b2v[mi].w) };
                *(float4*)&msgF[(ni*16 + l15)*MST + cb] = v;
            }
        }
        __syncthreads();

        // ---- segmented reduce: thread (ch, half) walks 16 sorted edges, flush per run ----
        {
            int ch = t & 127, half = t >> 7;
            int base = half * 16;
            int prow = srowS[pb][base];
            float run = 0.0f;
            #pragma unroll
            for (int i = 0; i < 16; ++i) {
                int rr = srowS[pb][base + i];
                if (rr != prow) {
                    unsafeAtomicAdd(&agg[(size_t)prow * HID + ch], run);
                    run = 0.0f; prow = rr;
                }
                run += msgF[(base + i)*MST + ch];
            }
            unsafeAtomicAdd(&agg[(size_t)prow * HID + ch], run);
        }
        // no trailing barrier: srowS double-buffered; msgF/t1 protected by the two barriers
    }
}

// ---------------- node MLP + (l==0) fused a-precompute + (l==1) fused output head -----------
__global__ __launch_bounds__(256, 2) void node_mfma_kernel(
    const short* __restrict__ h_bf, float* __restrict__ agg,
    const short* __restrict__ w1T, const float* __restrict__ b1,
    const short* __restrict__ w2T, const float* __restrict__ b2,
    const short* __restrict__ owT, const float* __restrict__ label,
    const float* __restrict__ eps, float* __restrict__ zout,
    short* __restrict__ hout_bf, const short* __restrict__ awaT1,
    float* __restrict__ aGout, int zero_agg, int do_out)
{
    __shared__ __align__(16) short featN[32 * NST];   // 16896 B; outB overlays here
    __shared__ __align__(16) short t1[32 * TST];      // 8704 B
    __shared__ __align__(16) short hlB[32 * HLST];    // 10752 B (fused out operand)
    float* outB = (float*)featN;                      // 32 x OST floats = 16896 B
    int t = threadIdx.x;
    int lane = t & 63;
    int wv = t >> 6;
    int l15 = lane & 15;
    int quad = lane >> 4;
    int nl = t >> 3, j = t & 7;

    short8 aw1[2][8], aw2[2][4];
    float4 b1v[2], b2v[2];
    #pragma unroll
    for (int mi = 0; mi < 2; ++mi) {
        #pragma unroll
        for (int ks = 0; ks < 8; ++ks)
            aw1[mi][ks] = *(const short8*)&w1T[(size_t)(wv*32 + mi*16 + l15)*KN + ks*32 + quad*8];
        #pragma unroll
        for (int ks = 0; ks < 4; ++ks)
            aw2[mi][ks] = *(const short8*)&w2T[(size_t)(wv*32 + mi*16 + l15)*128 + ks*32 + quad*8];
        b1v[mi] = *(const float4*)&b1[wv*32 + mi*16 + quad*4];
        b2v[mi] = *(const float4*)&b2[wv*32 + mi*16 + quad*4];
    }

    for (int it = 0; it < NTN; ++it) {
        int n0 = (blockIdx.x * NTN + it) * 32;
        if (n0 >= N_NODES) break;          // block-uniform
        __syncthreads();

        int n = n0 + nl;
        int idx = n < N_NODES ? n : N_NODES - 1;
        {
            const short8* hp = (const short8*)(h_bf + (size_t)idx * HID + j*16);
            short8 s0 = hp[0], s1 = hp[1];
            const float4* ap = (const float4*)(agg + (size_t)idx * HID) + j*4;
            float4 u0 = ap[0], u1 = ap[1], u2 = ap[2], u3 = ap[3];
            short2 p0 = f2bf2(u0.x, u0.y), p1 = f2bf2(u0.z, u0.w);
            short2 p2 = f2bf2(u1.x, u1.y), p3 = f2bf2(u1.z, u1.w);
            short2 p4 = f2bf2(u2.x, u2.y), p5 = f2bf2(u2.z, u2.w);
            short2 p6 = f2bf2(u3.x, u3.y), p7 = f2bf2(u3.z, u3.w);
            short8 s2 = { p0.x, p0.y, p1.x, p1.y, p2.x, p2.y, p3.x, p3.y };
            short8 s3 = { p4.x, p4.y, p5.x, p5.y, p6.x, p6.y, p7.x, p7.y };
            *(short8*)&featN[nl*NST + j*16]       = s0;
            *(short8*)&featN[nl*NST + j*16 + 8]   = s1;
            *(short8*)&featN[nl*NST + 128 + j*16]     = s2;
            *(short8*)&featN[nl*NST + 128 + j*16 + 8] = s3;
        }
        __syncthreads();

        // ---- re-zero consumed agg rows for the next layer ----
        if (zero_agg && n < N_NODES) {
            float4 z = {0,0,0,0};
            float4* ap = (float4*)(agg + (size_t)n * HID) + j*4;
            ap[0] = z; ap[1] = z; ap[2] = z; ap[3] = z;
        }

        floatx4 acc[2][2] = {{{0,0,0,0},{0,0,0,0}},{{0,0,0,0},{0,0,0,0}}};
        #pragma unroll
        for (int ks = 0; ks < 8; ++ks) {
            int koff = ks*32 + quad*8;
            short8 bb0 = *(const short8*)&featN[l15*NST + koff];
            short8 bb1 = *(const short8*)&featN[(16 + l15)*NST + koff];
            acc[0][0] = __builtin_amdgcn_mfma_f32_16x16x32_bf16(aw1[0][ks], bb0, acc[0][0], 0, 0, 0);
            acc[0][1] = __builtin_amdgcn_mfma_f32_16x16x32_bf16(aw1[0][ks], bb1, acc[0][1], 0, 0, 0);
            acc[1][0] = __builtin_amdgcn_mfma_f32_16x16x32_bf16(aw1[1][ks], bb0, acc[1][0], 0, 0, 0);
            acc[1][1] = __builtin_amdgcn_mfma_f32_16x16x32_bf16(aw1[1][ks], bb1, acc[1][1], 0, 0, 0);
        }

        #pragma unroll
        for (int mi = 0; mi < 2; ++mi) {
            int cb = wv*32 + mi*16 + quad*4;
            #pragma unroll
            for (int ni = 0; ni < 2; ++ni) {
                short2 p0 = f2bf2(elu_f(acc[mi][ni][0] + b1v[mi].x),
                                  elu_f(acc[mi][ni][1] + b1v[mi].y));
                short2 p1 = f2bf2(elu_f(acc[mi][ni][2] + b1v[mi].z),
                                  elu_f(acc[mi][ni][3] + b1v[mi].w));
                short4v s = { p0.x, p0.y, p1.x, p1.y };
                *(short4v*)&t1[(ni*16 + l15)*TST + cb] = s;
            }
        }
        __syncthreads();

        floatx4 acc2[2][2] = {{{0,0,0,0},{0,0,0,0}},{{0,0,0,0},{0,0,0,0}}};
        #pragma unroll
        for (int ks = 0; ks < 4; ++ks) {
            int koff = ks*32 + quad*8;
            short8 bb0 = *(const short8*)&t1[l15*TST + koff];
            short8 bb1 = *(const short8*)&t1[(16 + l15)*TST + koff];
            acc2[0][0] = __builtin_amdgcn_mfma_f32_16x16x32_bf16(aw2[0][ks], bb0, acc2[0][0], 0, 0, 0);
            acc2[0][1] = __builtin_amdgcn_mfma_f32_16x16x32_bf16(aw2[0][ks], bb1, acc2[0][1], 0, 0, 0);
            acc2[1][0] = __builtin_amdgcn_mfma_f32_16x16x32_bf16(aw2[1][ks], bb0, acc2[1][0], 0, 0, 0);
            acc2[1][1] = __builtin_amdgcn_mfma_f32_16x16x32_bf16(aw2[1][ks], bb1, acc2[1][1], 0, 0, 0);
        }

        if (!do_out) {
            // ---- write h; stage h into t1; fused a-precompute for layer-1 edges ----
            __syncthreads();   // all L2-MFMA t1 reads done before overwrite
            #pragma unroll
            for (int mi = 0; mi < 2; ++mi) {
                int cb = wv*32 + mi*16 + quad*4;
                #pragma unroll
                for (int ni = 0; ni < 2; ++ni) {
                    int nn = n0 + ni*16 + l15;
                    short2 p0 = f2bf2(acc2[mi][ni][0] + b2v[mi].x, acc2[mi][ni][1] + b2v[mi].y);
                    short2 p1 = f2bf2(acc2[mi][ni][2] + b2v[mi].z, acc2[mi][ni][3] + b2v[mi].w);
                    short4v s = { p0.x, p0.y, p1.x, p1.y };
                    if (nn < N_NODES) *(short4v*)&hout_bf[(size_t)nn*HID + cb] = s;
                    *(short4v*)&t1[(ni*16 + l15)*TST + cb] = s;
                }
            }
            __syncthreads();
            // ap MFMA: 256 outputs over 4 waves (64 ch/wave), K=128
            floatx4 accA[4][2] = {{{0,0,0,0},{0,0,0,0}},{{0,0,0,0},{0,0,0,0}},
                                  {{0,0,0,0},{0,0,0,0}},{{0,0,0,0},{0,0,0,0}}};
            #pragma unroll
            for (int ks = 0; ks < 4; ++ks) {
                int koff = ks*32 + quad*8;
                short8 bb0 = *(const short8*)&t1[l15*TST + koff];
                short8 bb1 = *(const short8*)&t1[(16 + l15)*TST + koff];
                #pragma unroll
                for (int mi = 0; mi < 4; ++mi) {
                    short8 wf = *(const short8*)&awaT1[(size_t)(wv*64 + mi*16 + l15)*128 + ks*32 + quad*8];
                    accA[mi][0] = __builtin_amdgcn_mfma_f32_16x16x32_bf16(wf, bb0, accA[mi][0], 0, 0, 0);
                    accA[mi][1] = __builtin_amdgcn_mfma_f32_16x16x32_bf16(wf, bb1, accA[mi][1], 0, 0, 0);
                }
            }
            #pragma unroll
            for (int mi = 0; mi < 4; ++mi) {
                int mm = wv*64 + mi*16 + quad*4;
                #pragma unroll
                for (int ni = 0; ni < 2; ++ni) {
                    int nn = n0 + ni*16 + l15;
                    if (nn < N_NODES) {
                        float4 v = { accA[mi][ni][0], accA[mi][ni][1], accA[mi][ni][2], accA[mi][ni][3] };
                        *(float4*)&aGout[(size_t)nn*256 + mm] = v;
                    }
                }
            }
        } else {
            // ---- fused out head: hl = [h(128), label(7), 1, 0...] bf16 in LDS ----
            #pragma unroll
            for (int mi = 0; mi < 2; ++mi) {
                int cb = wv*32 + mi*16 + quad*4;
                #pragma unroll
                for (int ni = 0; ni < 2; ++ni) {
                    short2 p0 = f2bf2(acc2[mi][ni][0] + b2v[mi].x, acc2[mi][ni][1] + b2v[mi].y);
                    short2 p1 = f2bf2(acc2[mi][ni][2] + b2v[mi].z, acc2[mi][ni][3] + b2v[mi].w);
                    short4v s = { p0.x, p0.y, p1.x, p1.y };
                    *(short4v*)&hlB[(ni*16 + l15)*HLST + cb] = s;
                }
            }
            if (t < 32) {
                int nn = n0 + t;
                int ii = nn < N_NODES ? nn : N_NODES - 1;
                const float* lp = label + (size_t)ii * 7;
                short8 s = { f2bf(lp[0]), f2bf(lp[1]), f2bf(lp[2]), f2bf(lp[3]),
                             f2bf(lp[4]), f2bf(lp[5]), f2bf(lp[6]), f2bf(1.0f) };
                short8 z = {0,0,0,0,0,0,0,0};
                *(short8*)&hlB[t*HLST + 128] = s;
                *(short8*)&hlB[t*HLST + 136] = z;
                *(short8*)&hlB[t*HLST + 144] = z;
                *(short8*)&hlB[t*HLST + 152] = z;
            }
            __syncthreads();

            // ---- out MFMA: K=160; ch rows: 0-63 mu, 64-127 var ----
            floatx4 accO[2][2] = {{{0,0,0,0},{0,0,0,0}},{{0,0,0,0},{0,0,0,0}}};
            short8 awO[2][5];
            #pragma unroll
            for (int mi = 0; mi < 2; ++mi)
                #pragma unroll
                for (int ks = 0; ks < 5; ++ks)
                    awO[mi][ks] = *(const short8*)&owT[(size_t)(wv*32 + mi*16 + l15)*KO + ks*32 + quad*8];
            #pragma unroll
            for (int ks = 0; ks < 5; ++ks) {
                int koff = ks*32 + quad*8;
                short8 bb0 = *(const short8*)&hlB[l15*HLST + koff];
                short8 bb1 = *(const short8*)&hlB[(16 + l15)*HLST + koff];
                accO[0][0] = __builtin_amdgcn_mfma_f32_16x16x32_bf16(awO[0][ks], bb0, accO[0][0], 0, 0, 0);
                accO[0][1] = __builtin_amdgcn_mfma_f32_16x16x32_bf16(awO[0][ks], bb1, accO[0][1], 0, 0, 0);
                accO[1][0] = __builtin_amdgcn_mfma_f32_16x16x32_bf16(awO[1][ks], bb0, accO[1][0], 0, 0, 0);
                accO[1][1] = __builtin_amdgcn_mfma_f32_16x16x32_bf16(awO[1][ks], bb1, accO[1][1], 0, 0, 0);
            }
            #pragma unroll
            for (int mi = 0; mi < 2; ++mi) {
                int cg2 = wv*32 + mi*16 + quad*4;   // 0-63 mu, 64-127 var
                #pragma unroll
                for (int ni = 0; ni < 2; ++ni) {
                    float4 v = { accO[mi][ni][0], accO[mi][ni][1], accO[mi][ni][2], accO[mi][ni][3] };
                    *(float4*)&outB[(ni*16 + l15)*OST + cg2] = v;
                }
            }
            __syncthreads();

            // ---- z = mu + 0.01*eps*exp(0.5*var), coalesced ----
            {
                int c = t & 63, g = t >> 6;
                #pragma unroll
                for (int i = 0; i < 8; ++i) {
                    int nloc = g*8 + i;
                    int nn = n0 + nloc;
                    if (nn < N_NODES) {
                        float mu = outB[nloc*OST + c];
                        float va = outB[nloc*OST + 64 + c];
                        zout[(size_t)nn*LAT + c] = mu + 0.01f * eps[(size_t)nn*LAT + c] * __expf(va * 0.5f);
                    }
                }
            }
        }
    }
}

extern "C" void kernel_launch(void* const* d_in, const int* in_sizes, int n_in,
                              void* d_out, int out_size, void* d_ws, size_t ws_size,
                              hipStream_t stream) {
    const float* h0        = (const float*)d_in[0];
    const float* label     = (const float*)d_in[1];
    const float* x         = (const float*)d_in[2];
    const float* edge_attr = (const float*)d_in[3];
    const float* eps       = (const float*)d_in[4];
    const float* emb_w     = (const float*)d_in[5];
    const float* emb_b     = (const float*)d_in[6];
    const float* edge_w1   = (const float*)d_in[7];
    const float* edge_b1   = (const float*)d_in[8];
    const float* edge_w2   = (const float*)d_in[9];
    const float* edge_b2   = (const float*)d_in[10];
    const float* node_w1   = (const float*)d_in[11];
    const float* node_b1   = (const float*)d_in[12];
    const float* node_w2   = (const float*)d_in[13];
    const float* node_b2   = (const float*)d_in[14];
    const float* mu_w      = (const float*)d_in[15];
    const float* mu_b      = (const float*)d_in[16];
    const float* var_w     = (const float*)d_in[17];
    const float* var_b     = (const float*)d_in[18];
    const int*   edges     = (const int*)d_in[19];
    float* out = (float*)d_out;

    float* agg      = (float*)d_ws;                         // N*128 f32
    float* aG       = agg + (size_t)N_NODES * HID;          // N*256 f32
    short* h_bf     = (short*)(aG + (size_t)N_NODES * 256); // N*128 bf16
    short* tail_s   = h_bf + (size_t)N_NODES * HID;         // E*8 bf16 (sorted)
    int*   cnt      = (int*)(tail_s + (size_t)N_EDGES * 8); // N int
    int*   cursor   = cnt + N_NODES;                        // N int
    int*   blk      = cursor + N_NODES;                     // 256 int
    int*   srow     = blk + 256;                            // E int
    int*   scol     = srow + N_EDGES;                       // E int
    short* ew2T     = (short*)(scol + N_EDGES);             // 2*128*128
    short* nw1T     = ew2T + 2*128*128;                     // 2*128*256
    short* nw2T     = nw1T + 2*128*KN;                      // 2*128*128
    short* owT      = nw2T + 2*128*128;                     // 128*160
    short* awaT     = owT + 128*KO;                         // 2*256*128
    float* cw       = (float*)(awaT + 2*256*128);           // 12*256

    hipMemsetAsync(cnt, 0, N_NODES * sizeof(int), stream);
    compose_k<<<12, 256, 0, stream>>>(emb_w, emb_b, edge_w1, cw);
    prep_all<<<EB + EMB_B + WPB + ZB, 256, 0, stream>>>(
        edges, h0, emb_w, emb_b,
        edge_w1, edge_w2, node_w1, node_w2,
        mu_w, mu_b, var_w, var_b, cw,
        cnt, h_bf, aG, ew2T, nw1T, nw2T, owT, awaT, agg);
    scan_a<<<NSCAN, 256, 0, stream>>>(cnt, cursor, blk);
    scan_b<<<1, 256, 0, stream>>>(blk);
    csr_place<<<(N_EDGES + 255) / 256, 256, 0, stream>>>(edges, x, edge_attr, cursor, blk,
                                                         srow, scol, tail_s);

    for (int l = 0; l < 2; ++l) {
        edge_mfma_kernel<<<N_EDGES / TE / NTPB, 256, 0, stream>>>(
            aG, tail_s, srow, scol,
            edge_w1 + (size_t)l * 261 * 128 + 256 * 128, edge_b1 + l * HID,
            ew2T + (size_t)l * 128 * 128, edge_b2 + l * HID, agg);
        node_mfma_kernel<<<(N_NODES/32 + NTN) / NTN, 256, 0, stream>>>(
            h_bf, agg,
            nw1T + (size_t)l * 128 * KN, node_b1 + l * HID,
            nw2T + (size_t)l * 128 * 128, node_b2 + l * HID,
            owT, label, eps, out, h_bf,
            awaT + 256 * 128, aG,
            (l == 0) ? 1 : 0, (l == 1) ? 1 : 0);
    }
}

// Round 9
// 571.315 us; speedup vs baseline: 1.6856x; 1.0369x over previous
//
#include <hip/hip_runtime.h>
#include <hip/hip_bf16.h>
#include <math.h>

#define N_NODES 50000
#define N_EDGES 800000
#define HID 128
#define LAT 64
#define IN_NODE 11
#define KN 256        // node MLP folded K (h + agg)
#define KO 160        // fused out head K: 128 h + 7 label + 1 bias + 24 pad
#define NST 264       // node feature LDS row stride, 256+8 pad
#define TST 136       // t1 LDS row stride, 128+8 pad
#define MST 132       // msg LDS row stride (floats), 128+4 pad
#define HLST 168      // fused-out hl row stride (160+8 pad)
#define OST 132       // fused-out result row stride (floats)
#define TE 32         // edges per tile
#define NTPB 20       // edge tiles per block (grid 1250)
#define NTN 2         // node tiles per block (grid 782)
#define NSCAN 196     // scan blocks: 196*256 = 50176 >= N_NODES
// prep_all block partition
#define EB 3125       // edge count blocks
#define EMB_B 25000   // embedding blocks (2 nodes each: h + a0)
#define WPB 32        // weight prep blocks
#define ZB 100        // agg zero blocks

typedef __attribute__((ext_vector_type(8))) short short8;
typedef __attribute__((ext_vector_type(4))) short short4v;
typedef __attribute__((ext_vector_type(4))) float floatx4;

__device__ __forceinline__ float elu_f(float v) { return v > 0.0f ? v : __expf(v) - 1.0f; }

__device__ __forceinline__ short f2bf(float f) {
    unsigned int u = __builtin_bit_cast(unsigned int, f);
    u += 0x7fffu + ((u >> 16) & 1u);   // round-to-nearest-even
    return (short)(u >> 16);
}

__device__ __forceinline__ short2 f2bf2(float a, float b) {
    float2 p; p.x = a; p.y = b;
    __hip_bfloat162 h = __float22bfloat162_rn(p);   // v_cvt_pk_bf16_f32
    short2 r;
    __builtin_memcpy(&r, &h, sizeof(r));
    return r;
}

__device__ __forceinline__ float bf2f(short s) {
    unsigned int u = ((unsigned int)(unsigned short)s) << 16;
    return __builtin_bit_cast(float, u);
}

// lgkm-only barrier: cross-wave data is LDS-only; does NOT drain vmcnt, so
// prefetched global loads stay in flight across it (r1-proven safe).
__device__ __forceinline__ void lds_barrier() {
    asm volatile("s_waitcnt lgkmcnt(0)" ::: "memory");
    __builtin_amdgcn_s_barrier();
    asm volatile("" ::: "memory");
}

// ---------------- compose: cw[12][256] = [emb_w; emb_b] @ W1(layer0) folded ----------------
__global__ void compose_k(const float* __restrict__ emb_w, const float* __restrict__ emb_b,
                          const float* __restrict__ ew1, float* __restrict__ cw) {
    int k0 = blockIdx.x;        // 0..11
    int mm = threadIdx.x;       // 0..255
    int m = mm & 127;
    int base = (mm < 128) ? 0 : 128;
    float s = 0.0f;
    for (int k = 0; k < 128; ++k) {
        float w = ew1[(size_t)(base + k) * 128 + m];
        float e = (k0 < 11) ? emb_w[k0 * 128 + k] : emb_b[k];
        s += e * w;
    }
    cw[k0 * 256 + mm] = s;
}

// ---------------- fused prep: edge count | emb+a0(bf16) | weight prep | agg zero --------------
__global__ void prep_all(const int* __restrict__ edges, const float* __restrict__ h0,
                         const float* __restrict__ emb_w, const float* __restrict__ emb_b,
                         const float* __restrict__ ew1, const float* __restrict__ ew2,
                         const float* __restrict__ nw1, const float* __restrict__ nw2,
                         const float* __restrict__ mu_w, const float* __restrict__ mu_b,
                         const float* __restrict__ var_w, const float* __restrict__ var_b,
                         const float* __restrict__ cw,
                         int* __restrict__ cnt,
                         short* __restrict__ h_bf, short* __restrict__ aGb,
                         short* __restrict__ ew2T,
                         short* __restrict__ nw1T, short* __restrict__ nw2T,
                         short* __restrict__ owT, short* __restrict__ awaT,
                         float* __restrict__ agg) {
    int b = blockIdx.x, t = threadIdx.x;
    if (b < EB) {
        int e = b * 256 + t;
        if (e >= N_EDGES) return;
        atomicAdd(&cnt[edges[e]], 1);
    } else if (b < EB + EMB_B) {
        int bb = b - EB;
        int n = bb * 2 + (t >> 7);
        int c = t & 127;
        if (n >= N_NODES) return;
        float h0v[IN_NODE];
        #pragma unroll
        for (int k = 0; k < IN_NODE; ++k) h0v[k] = h0[n*IN_NODE + k];
        float acc = emb_b[c];
        #pragma unroll
        for (int k = 0; k < IN_NODE; ++k) acc += h0v[k] * emb_w[k*HID + c];
        h_bf[(size_t)n*HID + c] = f2bf(acc);
        float s0 = cw[11*256 + c], s1 = cw[11*256 + 128 + c];
        #pragma unroll
        for (int k = 0; k < IN_NODE; ++k) {
            s0 += h0v[k] * cw[k*256 + c];
            s1 += h0v[k] * cw[k*256 + 128 + c];
        }
        aGb[(size_t)n*256 + c]       = f2bf(s0);
        aGb[(size_t)n*256 + 128 + c] = f2bf(s1);
    } else if (b < EB + EMB_B + WPB) {
        int idx = (b - EB - EMB_B) * 256 + t;
        int stride = WPB * 256;
        for (int i = idx; i < 2*128*128; i += stride) {
            int l = i / (128*128); int r = i % (128*128);
            int c = r / 128; int k = r % 128;
            ew2T[i] = f2bf(ew2[(size_t)l*128*128 + (size_t)k*128 + c]);
        }
        for (int i = idx; i < 2*128*KN; i += stride) {
            int l = i / (128*KN); int r = i % (128*KN);
            int c = r / KN; int k = r % KN;
            const float* base = nw1 + (size_t)l*384*128;
            float v = (k < 128) ? (base[(size_t)k*128 + c] + base[(size_t)(256+k)*128 + c])
                                : base[(size_t)k*128 + c];
            nw1T[i] = f2bf(v);
        }
        for (int i = idx; i < 2*128*128; i += stride) {
            int l = i / (128*128); int r = i % (128*128);
            int c = r / 128; int k = r % 128;
            nw2T[i] = f2bf(nw2[(size_t)l*128*128 + (size_t)k*128 + c]);
        }
        for (int i = idx; i < 128*KO; i += stride) {
            int c = i / KO; int k = i % KO;
            float v = 0.0f;
            if (c < 64) {
                if (k < 135) v = mu_w[(size_t)k*LAT + c];
                else if (k == 135) v = mu_b[c];
            } else {
                int cc = c - 64;
                if (k < 135) v = var_w[(size_t)k*LAT + cc];
                else if (k == 135) v = var_b[cc];
            }
            owT[i] = f2bf(v);
        }
        for (int i = idx; i < 2*256*128; i += stride) {
            int l = i / (256*128); int r = i % (256*128);
            int mm = r / 128; int k = r % 128;
            int kk = (mm < 128) ? k : 128 + k;
            awaT[i] = f2bf(ew1[(size_t)l*261*128 + (size_t)kk*128 + (mm & 127)]);
        }
    } else {
        int idx = (b - EB - EMB_B - WPB) * 256 + t;
        int stride = ZB * 256;
        float4 z = {0,0,0,0};
        float4* a4 = (float4*)agg;
        for (int i = idx; i < N_NODES*HID/4; i += stride) a4[i] = z;
    }
}

// ---------------- CSR pass 2a ----------------
__global__ void scan_a(const int* __restrict__ cnt, int* __restrict__ cursor,
                       int* __restrict__ blk) {
    __shared__ int s[256];
    int b = blockIdx.x, t = threadIdx.x;
    int row = b * 256 + t;
    int v = (row < N_NODES) ? cnt[row] : 0;
    s[t] = v;
    __syncthreads();
    #pragma unroll
    for (int off = 1; off < 256; off <<= 1) {
        int add = (t >= off) ? s[t - off] : 0;
        __syncthreads();
        s[t] += add;
        __syncthreads();
    }
    if (row < N_NODES) cursor[row] = s[t] - v;
    if (t == 255) blk[b] = s[255];
}

// ---------------- CSR pass 2b ----------------
__global__ void scan_b(int* __restrict__ blk) {
    __shared__ int s[256];
    int t = threadIdx.x;
    int v = (t < NSCAN) ? blk[t] : 0;
    s[t] = v;
    __syncthreads();
    #pragma unroll
    for (int off = 1; off < 256; off <<= 1) {
        int add = (t >= off) ? s[t - off] : 0;
        __syncthreads();
        s[t] += add;
        __syncthreads();
    }
    if (t < NSCAN) blk[t] = s[t] - v;
}

// ---------------- CSR pass 3: radial+tail inline, place sorted ----------------
__global__ void csr_place(const int* __restrict__ edges, const float* __restrict__ x,
                          const float* __restrict__ edge_attr,
                          int* __restrict__ cursor, const int* __restrict__ blk,
                          int* __restrict__ srow, int* __restrict__ scol,
                          short* __restrict__ tail_s) {
    int e = blockIdx.x * 256 + threadIdx.x;
    if (e >= N_EDGES) return;
    int r = edges[e], c = edges[N_EDGES + e];
    float dx = x[r*3+0] - x[c*3+0];
    float dy = x[r*3+1] - x[c*3+1];
    float dz = x[r*3+2] - x[c*3+2];
    float radial = dx*dx + dy*dy + dz*dz;
    float4 ea = *(const float4*)(edge_attr + (size_t)e * 4);
    short8 s = { f2bf(radial), f2bf(ea.x), f2bf(ea.y), f2bf(ea.z), f2bf(ea.w), 0, 0, 0 };
    int pos = atomicAdd(&cursor[r], 1) + blk[r >> 8];
    srow[pos] = r; scol[pos] = c;
    *(short8*)(tail_s + (size_t)pos * 8) = s;
}

// ---------------- edge kernel: bf16 aG gather (reg-prefetched) + elementwise L1 + MFMA L2 ----
// r9: (1) aG bf16 halves gather bytes; (2) lgkm-only barriers (no vmcnt drain);
// (3) next tile's a1/a2/tail prefetched into regs right after current consumption —
// loads float across both barriers and a full tile of compute (T14).
__global__ __launch_bounds__(256, 2) void edge_mfma_kernel(
    const short* __restrict__ aGb, const short* __restrict__ tail_s,
    const int* __restrict__ srow, const int* __restrict__ scol,
    const float* __restrict__ w1c, const float* __restrict__ b1,
    const short* __restrict__ w2T, const float* __restrict__ b2,
    float* __restrict__ agg)
{
    __shared__ __align__(16) short t1[TE * TST];      // 8704 B
    __shared__ __align__(16) float msgF[TE * MST];    // 16896 B
    __shared__ int srowS[2][TE];
    int t = threadIdx.x;
    int lane = t & 63;
    int wv = t >> 6;          // wave: channel block [wv*32, wv*32+32)
    int l15 = lane & 15;
    int quad = lane >> 4;
    int cg = t & 15;          // channel group (8 ch) — fixed per thread
    int elb = t >> 4;         // base edge-in-tile (0..15)

    // per-thread tail weights + bias for its 8 channels
    float w1cv[5][8];
    float b1v8[8];
    #pragma unroll
    for (int k = 0; k < 5; ++k)
        #pragma unroll
        for (int j = 0; j < 8; ++j)
            w1cv[k][j] = w1c[k*128 + cg*8 + j];
    #pragma unroll
    for (int j = 0; j < 8; ++j) b1v8[j] = b1[cg*8 + j];

    // L2 weights
    short8 aw2[2][4];
    float4 b2v[2];
    #pragma unroll
    for (int mi = 0; mi < 2; ++mi) {
        #pragma unroll
        for (int ks = 0; ks < 4; ++ks)
            aw2[mi][ks] = *(const short8*)&w2T[(size_t)(wv*32 + mi*16 + l15)*128 + ks*32 + quad*8];
        b2v[mi] = *(const float4*)&b2[wv*32 + mi*16 + quad*4];
    }

    // prefetch registers (next tile's gathered operands)
    short8 pa1[2], pa2[2], ptl[2];
    auto prefetch = [&](int s_) {
        int e0 = (blockIdx.x * NTPB + s_) * TE;
        #pragma unroll
        for (int ii = 0; ii < 2; ++ii) {
            int e = e0 + elb + ii*16;
            e = e < N_EDGES ? e : N_EDGES - 1;        // clamp past-end (last block)
            int r = srow[e], c = scol[e];
            pa1[ii] = *(const short8*)(aGb + (size_t)r * 256 + cg*8);
            pa2[ii] = *(const short8*)(aGb + (size_t)c * 256 + 128 + cg*8);
            ptl[ii] = *(const short8*)(tail_s + (size_t)e * 8);
        }
    };
    prefetch(0);

    for (int it = 0; it < NTPB; ++it) {
        int e0 = (blockIdx.x * NTPB + it) * TE;
        int pb = it & 1;
        if (t < TE) srowS[pb][t] = srow[e0 + t];

        // ---- phase A: elementwise layer 1 from prefetched regs -> t1 ----
        #pragma unroll
        for (int ii = 0; ii < 2; ++ii) {
            int el = elb + ii*16;
            short8 A = pa1[ii], B = pa2[ii], T = ptl[ii];
            float t0 = bf2f(T[0]), t1f = bf2f(T[1]), t2 = bf2f(T[2]),
                  t3 = bf2f(T[3]), t4 = bf2f(T[4]);
            float v[8];
            #pragma unroll
            for (int j = 0; j < 8; ++j) {
                float s = bf2f(A[j]) + bf2f(B[j]);
                v[j] = elu_f(s + b1v8[j]
                       + t0*w1cv[0][j] + t1f*w1cv[1][j] + t2*w1cv[2][j]
                       + t3*w1cv[3][j] + t4*w1cv[4][j]);
            }
            short2 q0 = f2bf2(v[0], v[1]), q1 = f2bf2(v[2], v[3]);
            short2 q2 = f2bf2(v[4], v[5]), q3 = f2bf2(v[6], v[7]);
            short8 o = { q0.x, q0.y, q1.x, q1.y, q2.x, q2.y, q3.x, q3.y };
            *(short8*)&t1[el*TST + cg*8] = o;
        }
        // issue next tile's gathers NOW — they fly across both lgkm barriers
        if (it + 1 < NTPB) prefetch(it + 1);

        lds_barrier();

        // ---- layer 2: K = 128 MFMA ----
        floatx4 acc2[2][2] = {{{0,0,0,0},{0,0,0,0}},{{0,0,0,0},{0,0,0,0}}};
        #pragma unroll
        for (int ks = 0; ks < 4; ++ks) {
            int koff = ks*32 + quad*8;
            short8 bb0 = *(const short8*)&t1[l15*TST + koff];
            short8 bb1 = *(const short8*)&t1[(16 + l15)*TST + koff];
            acc2[0][0] = __builtin_amdgcn_mfma_f32_16x16x32_bf16(aw2[0][ks], bb0, acc2[0][0], 0, 0, 0);
            acc2[0][1] = __builtin_amdgcn_mfma_f32_16x16x32_bf16(aw2[0][ks], bb1, acc2[0][1], 0, 0, 0);
            acc2[1][0] = __builtin_amdgcn_mfma_f32_16x16x32_bf16(aw2[1][ks], bb0, acc2[1][0], 0, 0, 0);
            acc2[1][1] = __builtin_amdgcn_mfma_f32_16x16x32_bf16(aw2[1][ks], bb1, acc2[1][1], 0, 0, 0);
        }

        // ---- epilogue 2: bias + elu -> f32 msg tile ----
        #pragma unroll
        for (int mi = 0; mi < 2; ++mi) {
            int cb = wv*32 + mi*16 + quad*4;
            #pragma unroll
            for (int ni = 0; ni < 2; ++ni) {
                float4 v = { elu_f(acc2[mi][ni][0] + b2v[mi].x), elu_f(acc2[mi][ni][1] + b2v[mi].y),
                             elu_f(acc2[mi][ni][2] + b2v[mi].z), elu_f(acc2[mi][ni][3] + b2v[mi].w) };
                *(float4*)&msgF[(ni*16 + l15)*MST + cb] = v;
            }
        }
        lds_barrier();

        // ---- segmented reduce ----
        {
            int ch = t & 127, half = t >> 7;
            int base = half * 16;
            int prow = srowS[pb][base];
            float run = 0.0f;
            #pragma unroll
            for (int i = 0; i < 16; ++i) {
                int rr = srowS[pb][base + i];
                if (rr != prow) {
                    unsafeAtomicAdd(&agg[(size_t)prow * HID + ch], run);
                    run = 0.0f; prow = rr;
                }
                run += msgF[(base + i)*MST + ch];
            }
            unsafeAtomicAdd(&agg[(size_t)prow * HID + ch], run);
        }
    }
}

// ---------------- node MLP + (l==0) fused a-precompute (bf16 out) + (l==1) fused out head ----
__global__ __launch_bounds__(256, 2) void node_mfma_kernel(
    const short* __restrict__ h_bf, float* __restrict__ agg,
    const short* __restrict__ w1T, const float* __restrict__ b1,
    const short* __restrict__ w2T, const float* __restrict__ b2,
    const short* __restrict__ owT, const float* __restrict__ label,
    const float* __restrict__ eps, float* __restrict__ zout,
    short* __restrict__ hout_bf, const short* __restrict__ awaT1,
    short* __restrict__ aGbout, int zero_agg, int do_out)
{
    __shared__ __align__(16) short featN[32 * NST];   // 16896 B; outB overlays here
    __shared__ __align__(16) short t1[32 * TST];      // 8704 B
    __shared__ __align__(16) short hlB[32 * HLST];    // 10752 B
    float* outB = (float*)featN;
    int t = threadIdx.x;
    int lane = t & 63;
    int wv = t >> 6;
    int l15 = lane & 15;
    int quad = lane >> 4;
    int nl = t >> 3, j = t & 7;

    short8 aw1[2][8], aw2[2][4];
    float4 b1v[2], b2v[2];
    #pragma unroll
    for (int mi = 0; mi < 2; ++mi) {
        #pragma unroll
        for (int ks = 0; ks < 8; ++ks)
            aw1[mi][ks] = *(const short8*)&w1T[(size_t)(wv*32 + mi*16 + l15)*KN + ks*32 + quad*8];
        #pragma unroll
        for (int ks = 0; ks < 4; ++ks)
            aw2[mi][ks] = *(const short8*)&w2T[(size_t)(wv*32 + mi*16 + l15)*128 + ks*32 + quad*8];
        b1v[mi] = *(const float4*)&b1[wv*32 + mi*16 + quad*4];
        b2v[mi] = *(const float4*)&b2[wv*32 + mi*16 + quad*4];
    }

    for (int it = 0; it < NTN; ++it) {
        int n0 = (blockIdx.x * NTN + it) * 32;
        if (n0 >= N_NODES) break;
        __syncthreads();

        int n = n0 + nl;
        int idx = n < N_NODES ? n : N_NODES - 1;
        {
            const short8* hp = (const short8*)(h_bf + (size_t)idx * HID + j*16);
            short8 s0 = hp[0], s1 = hp[1];
            const float4* ap = (const float4*)(agg + (size_t)idx * HID) + j*4;
            float4 u0 = ap[0], u1 = ap[1], u2 = ap[2], u3 = ap[3];
            short2 p0 = f2bf2(u0.x, u0.y), p1 = f2bf2(u0.z, u0.w);
            short2 p2 = f2bf2(u1.x, u1.y), p3 = f2bf2(u1.z, u1.w);
            short2 p4 = f2bf2(u2.x, u2.y), p5 = f2bf2(u2.z, u2.w);
            short2 p6 = f2bf2(u3.x, u3.y), p7 = f2bf2(u3.z, u3.w);
            short8 s2 = { p0.x, p0.y, p1.x, p1.y, p2.x, p2.y, p3.x, p3.y };
            short8 s3 = { p4.x, p4.y, p5.x, p5.y, p6.x, p6.y, p7.x, p7.y };
            *(short8*)&featN[nl*NST + j*16]       = s0;
            *(short8*)&featN[nl*NST + j*16 + 8]   = s1;
            *(short8*)&featN[nl*NST + 128 + j*16]     = s2;
            *(short8*)&featN[nl*NST + 128 + j*16 + 8] = s3;
        }
        __syncthreads();

        if (zero_agg && n < N_NODES) {
            float4 z = {0,0,0,0};
            float4* ap = (float4*)(agg + (size_t)n * HID) + j*4;
            ap[0] = z; ap[1] = z; ap[2] = z; ap[3] = z;
        }

        floatx4 acc[2][2] = {{{0,0,0,0},{0,0,0,0}},{{0,0,0,0},{0,0,0,0}}};
        #pragma unroll
        for (int ks = 0; ks < 8; ++ks) {
            int koff = ks*32 + quad*8;
            short8 bb0 = *(const short8*)&featN[l15*NST + koff];
            short8 bb1 = *(const short8*)&featN[(16 + l15)*NST + koff];
            acc[0][0] = __builtin_amdgcn_mfma_f32_16x16x32_bf16(aw1[0][ks], bb0, acc[0][0], 0, 0, 0);
            acc[0][1] = __builtin_amdgcn_mfma_f32_16x16x32_bf16(aw1[0][ks], bb1, acc[0][1], 0, 0, 0);
            acc[1][0] = __builtin_amdgcn_mfma_f32_16x16x32_bf16(aw1[1][ks], bb0, acc[1][0], 0, 0, 0);
            acc[1][1] = __builtin_amdgcn_mfma_f32_16x16x32_bf16(aw1[1][ks], bb1, acc[1][1], 0, 0, 0);
        }

        #pragma unroll
        for (int mi = 0; mi < 2; ++mi) {
            int cb = wv*32 + mi*16 + quad*4;
            #pragma unroll
            for (int ni = 0; ni < 2; ++ni) {
                short2 p0 = f2bf2(elu_f(acc[mi][ni][0] + b1v[mi].x),
                                  elu_f(acc[mi][ni][1] + b1v[mi].y));
                short2 p1 = f2bf2(elu_f(acc[mi][ni][2] + b1v[mi].z),
                                  elu_f(acc[mi][ni][3] + b1v[mi].w));
                short4v s = { p0.x, p0.y, p1.x, p1.y };
                *(short4v*)&t1[(ni*16 + l15)*TST + cb] = s;
            }
        }
        __syncthreads();

        floatx4 acc2[2][2] = {{{0,0,0,0},{0,0,0,0}},{{0,0,0,0},{0,0,0,0}}};
        #pragma unroll
        for (int ks = 0; ks < 4; ++ks) {
            int koff = ks*32 + quad*8;
            short8 bb0 = *(const short8*)&t1[l15*TST + koff];
            short8 bb1 = *(const short8*)&t1[(16 + l15)*TST + koff];
            acc2[0][0] = __builtin_amdgcn_mfma_f32_16x16x32_bf16(aw2[0][ks], bb0, acc2[0][0], 0, 0, 0);
            acc2[0][1] = __builtin_amdgcn_mfma_f32_16x16x32_bf16(aw2[0][ks], bb1, acc2[0][1], 0, 0, 0);
            acc2[1][0] = __builtin_amdgcn_mfma_f32_16x16x32_bf16(aw2[1][ks], bb0, acc2[1][0], 0, 0, 0);
            acc2[1][1] = __builtin_amdgcn_mfma_f32_16x16x32_bf16(aw2[1][ks], bb1, acc2[1][1], 0, 0, 0);
        }

        if (!do_out) {
            __syncthreads();   // all L2-MFMA t1 reads done before overwrite
            #pragma unroll
            for (int mi = 0; mi < 2; ++mi) {
                int cb = wv*32 + mi*16 + quad*4;
                #pragma unroll
                for (int ni = 0; ni < 2; ++ni) {
                    int nn = n0 + ni*16 + l15;
                    short2 p0 = f2bf2(acc2[mi][ni][0] + b2v[mi].x, acc2[mi][ni][1] + b2v[mi].y);
                    short2 p1 = f2bf2(acc2[mi][ni][2] + b2v[mi].z, acc2[mi][ni][3] + b2v[mi].w);
                    short4v s = { p0.x, p0.y, p1.x, p1.y };
                    if (nn < N_NODES) *(short4v*)&hout_bf[(size_t)nn*HID + cb] = s;
                    *(short4v*)&t1[(ni*16 + l15)*TST + cb] = s;
                }
            }
            __syncthreads();
            // ap MFMA: 256 outputs over 4 waves, K=128; output packed bf16
            floatx4 accA[4][2] = {{{0,0,0,0},{0,0,0,0}},{{0,0,0,0},{0,0,0,0}},
                                  {{0,0,0,0},{0,0,0,0}},{{0,0,0,0},{0,0,0,0}}};
            #pragma unroll
            for (int ks = 0; ks < 4; ++ks) {
                int koff = ks*32 + quad*8;
                short8 bb0 = *(const short8*)&t1[l15*TST + koff];
                short8 bb1 = *(const short8*)&t1[(16 + l15)*TST + koff];
                #pragma unroll
                for (int mi = 0; mi < 4; ++mi) {
                    short8 wf = *(const short8*)&awaT1[(size_t)(wv*64 + mi*16 + l15)*128 + ks*32 + quad*8];
                    accA[mi][0] = __builtin_amdgcn_mfma_f32_16x16x32_bf16(wf, bb0, accA[mi][0], 0, 0, 0);
                    accA[mi][1] = __builtin_amdgcn_mfma_f32_16x16x32_bf16(wf, bb1, accA[mi][1], 0, 0, 0);
                }
            }
            #pragma unroll
            for (int mi = 0; mi < 4; ++mi) {
                int mm = wv*64 + mi*16 + quad*4;
                #pragma unroll
                for (int ni = 0; ni < 2; ++ni) {
                    int nn = n0 + ni*16 + l15;
                    if (nn < N_NODES) {
                        short2 p0 = f2bf2(accA[mi][ni][0], accA[mi][ni][1]);
                        short2 p1 = f2bf2(accA[mi][ni][2], accA[mi][ni][3]);
                        short4v s = { p0.x, p0.y, p1.x, p1.y };
                        *(short4v*)&aGbout[(size_t)nn*256 + mm] = s;
                    }
                }
            }
        } else {
            #pragma unroll
            for (int mi = 0; mi < 2; ++mi) {
                int cb = wv*32 + mi*16 + quad*4;
                #pragma unroll
                for (int ni = 0; ni < 2; ++ni) {
                    short2 p0 = f2bf2(acc2[mi][ni][0] + b2v[mi].x, acc2[mi][ni][1] + b2v[mi].y);
                    short2 p1 = f2bf2(acc2[mi][ni][2] + b2v[mi].z, acc2[mi][ni][3] + b2v[mi].w);
                    short4v s = { p0.x, p0.y, p1.x, p1.y };
                    *(short4v*)&hlB[(ni*16 + l15)*HLST + cb] = s;
                }
            }
            if (t < 32) {
                int nn = n0 + t;
                int ii = nn < N_NODES ? nn : N_NODES - 1;
                const float* lp = label + (size_t)ii * 7;
                short8 s = { f2bf(lp[0]), f2bf(lp[1]), f2bf(lp[2]), f2bf(lp[3]),
                             f2bf(lp[4]), f2bf(lp[5]), f2bf(lp[6]), f2bf(1.0f) };
                short8 z = {0,0,0,0,0,0,0,0};
                *(short8*)&hlB[t*HLST + 128] = s;
                *(short8*)&hlB[t*HLST + 136] = z;
                *(short8*)&hlB[t*HLST + 144] = z;
                *(short8*)&hlB[t*HLST + 152] = z;
            }
            __syncthreads();

            floatx4 accO[2][2] = {{{0,0,0,0},{0,0,0,0}},{{0,0,0,0},{0,0,0,0}}};
            short8 awO[2][5];
            #pragma unroll
            for (int mi = 0; mi < 2; ++mi)
                #pragma unroll
                for (int ks = 0; ks < 5; ++ks)
                    awO[mi][ks] = *(const short8*)&owT[(size_t)(wv*32 + mi*16 + l15)*KO + ks*32 + quad*8];
            #pragma unroll
            for (int ks = 0; ks < 5; ++ks) {
                int koff = ks*32 + quad*8;
                short8 bb0 = *(const short8*)&hlB[l15*HLST + koff];
                short8 bb1 = *(const short8*)&hlB[(16 + l15)*HLST + koff];
                accO[0][0] = __builtin_amdgcn_mfma_f32_16x16x32_bf16(awO[0][ks], bb0, accO[0][0], 0, 0, 0);
                accO[0][1] = __builtin_amdgcn_mfma_f32_16x16x32_bf16(awO[0][ks], bb1, accO[0][1], 0, 0, 0);
                accO[1][0] = __builtin_amdgcn_mfma_f32_16x16x32_bf16(awO[1][ks], bb0, accO[1][0], 0, 0, 0);
                accO[1][1] = __builtin_amdgcn_mfma_f32_16x16x32_bf16(awO[1][ks], bb1, accO[1][1], 0, 0, 0);
            }
            #pragma unroll
            for (int mi = 0; mi < 2; ++mi) {
                int cg2 = wv*32 + mi*16 + quad*4;
                #pragma unroll
                for (int ni = 0; ni < 2; ++ni) {
                    float4 v = { accO[mi][ni][0], accO[mi][ni][1], accO[mi][ni][2], accO[mi][ni][3] };
                    *(float4*)&outB[(ni*16 + l15)*OST + cg2] = v;
                }
            }
            __syncthreads();

            {
                int c = t & 63, g = t >> 6;
                #pragma unroll
                for (int i = 0; i < 8; ++i) {
                    int nloc = g*8 + i;
                    int nn = n0 + nloc;
                    if (nn < N_NODES) {
                        float mu = outB[nloc*OST + c];
                        float va = outB[nloc*OST + 64 + c];
                        zout[(size_t)nn*LAT + c] = mu + 0.01f * eps[(size_t)nn*LAT + c] * __expf(va * 0.5f);
                    }
                }
            }
        }
    }
}

extern "C" void kernel_launch(void* const* d_in, const int* in_sizes, int n_in,
                              void* d_out, int out_size, void* d_ws, size_t ws_size,
                              hipStream_t stream) {
    const float* h0        = (const float*)d_in[0];
    const float* label     = (const float*)d_in[1];
    const float* x         = (const float*)d_in[2];
    const float* edge_attr = (const float*)d_in[3];
    const float* eps       = (const float*)d_in[4];
    const float* emb_w     = (const float*)d_in[5];
    const float* emb_b     = (const float*)d_in[6];
    const float* edge_w1   = (const float*)d_in[7];
    const float* edge_b1   = (const float*)d_in[8];
    const float* edge_w2   = (const float*)d_in[9];
    const float* edge_b2   = (const float*)d_in[10];
    const float* node_w1   = (const float*)d_in[11];
    const float* node_b1   = (const float*)d_in[12];
    const float* node_w2   = (const float*)d_in[13];
    const float* node_b2   = (const float*)d_in[14];
    const float* mu_w      = (const float*)d_in[15];
    const float* mu_b      = (const float*)d_in[16];
    const float* var_w     = (const float*)d_in[17];
    const float* var_b     = (const float*)d_in[18];
    const int*   edges     = (const int*)d_in[19];
    float* out = (float*)d_out;

    float* agg      = (float*)d_ws;                          // N*128 f32
    short* aGb      = (short*)(agg + (size_t)N_NODES * HID); // N*256 bf16
    short* h_bf     = aGb + (size_t)N_NODES * 256;           // N*128 bf16
    short* tail_s   = h_bf + (size_t)N_NODES * HID;          // E*8 bf16 (sorted)
    int*   cnt      = (int*)(tail_s + (size_t)N_EDGES * 8);  // N int
    int*   cursor   = cnt + N_NODES;                         // N int
    int*   blk      = cursor + N_NODES;                      // 256 int
    int*   srow     = blk + 256;                             // E int
    int*   scol     = srow + N_EDGES;                        // E int
    short* ew2T     = (short*)(scol + N_EDGES);              // 2*128*128
    short* nw1T     = ew2T + 2*128*128;                      // 2*128*256
    short* nw2T     = nw1T + 2*128*KN;                       // 2*128*128
    short* owT      = nw2T + 2*128*128;                      // 128*160
    short* awaT     = owT + 128*KO;                          // 2*256*128
    float* cw       = (float*)(awaT + 2*256*128);            // 12*256

    hipMemsetAsync(cnt, 0, N_NODES * sizeof(int), stream);
    compose_k<<<12, 256, 0, stream>>>(emb_w, emb_b, edge_w1, cw);
    prep_all<<<EB + EMB_B + WPB + ZB, 256, 0, stream>>>(
        edges, h0, emb_w, emb_b,
        edge_w1, edge_w2, node_w1, node_w2,
        mu_w, mu_b, var_w, var_b, cw,
        cnt, h_bf, aGb, ew2T, nw1T, nw2T, owT, awaT, agg);
    scan_a<<<NSCAN, 256, 0, stream>>>(cnt, cursor, blk);
    scan_b<<<1, 256, 0, stream>>>(blk);
    csr_place<<<(N_EDGES + 255) / 256, 256, 0, stream>>>(edges, x, edge_attr, cursor, blk,
                                                         srow, scol, tail_s);

    for (int l = 0; l < 2; ++l) {
        edge_mfma_kernel<<<N_EDGES / TE / NTPB, 256, 0, stream>>>(
            aGb, tail_s, srow, scol,
            edge_w1 + (size_t)l * 261 * 128 + 256 * 128, edge_b1 + l * HID,
            ew2T + (size_t)l * 128 * 128, edge_b2 + l * HID, agg);
        node_mfma_kernel<<<(N_NODES/32 + NTN) / NTN, 256, 0, stream>>>(
            h_bf, agg,
            nw1T + (size_t)l * 128 * KN, node_b1 + l * HID,
            nw2T + (size_t)l * 128 * 128, node_b2 + l * HID,
            owT, label, eps, out, h_bf,
            awaT + 256 * 128, aGb,
            (l == 0) ? 1 : 0, (l == 1) ? 1 : 0);
    }
}